// Round 2
// baseline (2629.582 us; speedup 1.0000x reference)
//
#include <hip/hip_runtime.h>
#include <hip/hip_bf16.h>

// Problem constants (match reference)
static constexpr int N_NODES  = 100000;
static constexpr int N_EDGES  = 400000;
static constexpr int DRUG_DIM = 75;
static constexpr int OUT_C    = 256;   // OUT
static constexpr int N_GRAPH  = 2048;  // G
static constexpr int B_CL     = 2048;  // B
static constexpr int CLINE_DIM= 954;

using bf16 = __hip_bfloat16;

// ---------- load/store helpers (fp32 compute, typed storage) ----------
__device__ __forceinline__ float ldf(const float* p) { return *p; }
__device__ __forceinline__ float ldf(const bf16* p)  { return __bfloat162float(*p); }
__device__ __forceinline__ void  stf(float* p, float v) { *p = v; }
__device__ __forceinline__ void  stf(bf16* p, float v)  { *p = __float2bfloat16(v); }

// ---------- orderable float encoding for atomicMax ----------
__device__ __forceinline__ unsigned fenc(float f) {
    unsigned b = __float_as_uint(f);
    return (b & 0x80000000u) ? ~b : (b | 0x80000000u);
}
__device__ __forceinline__ float fdec(unsigned u) {
    return __uint_as_float((u & 0x80000000u) ? (u ^ 0x80000000u) : ~u);
}

// ---------- tiled GEMM: C = act(A@W + bias) (+res) ----------
// A: [M,K] (TA), W: [K,NC] fp32, bias: [NC]. ACT: 0 none, 1 tanh, 2 relu-then-res.
template<int ACT, typename TA, typename TO>
__global__ __launch_bounds__(256)
void gemm_bias_kernel(const TA* __restrict__ A, const float* __restrict__ W,
                      const float* __restrict__ bias, const float* __restrict__ res,
                      TO* __restrict__ C, int M, int K, int NC)
{
    __shared__ float As[16][64];   // [kk][m]
    __shared__ float Ws[16][64];   // [kk][n]
    const int mtile = blockIdx.x;
    const int ntile = blockIdx.y;
    const int tid = threadIdx.x;
    const int tx = tid & 15;
    const int ty = tid >> 4;
    const int row0 = mtile * 64 + ty * 4;
    const int col0 = ntile * 64 + tx * 4;

    float acc[4][4] = {};
    for (int k0 = 0; k0 < K; k0 += 16) {
        #pragma unroll
        for (int l = 0; l < 4; ++l) {
            int lin = tid * 4 + l;
            int m  = lin >> 4;
            int kk = lin & 15;
            int gr = mtile * 64 + m;
            int gk = k0 + kk;
            As[kk][m] = (gr < M && gk < K) ? ldf(&A[(size_t)gr * K + gk]) : 0.f;
        }
        #pragma unroll
        for (int l = 0; l < 4; ++l) {
            int lin = tid * 4 + l;
            int kk = lin >> 6;
            int n  = lin & 63;
            int gk = k0 + kk;
            Ws[kk][n] = (gk < K) ? W[(size_t)gk * NC + ntile * 64 + n] : 0.f;
        }
        __syncthreads();
        #pragma unroll
        for (int kk = 0; kk < 16; ++kk) {
            float a[4], b[4];
            #pragma unroll
            for (int i = 0; i < 4; ++i) a[i] = As[kk][ty * 4 + i];
            #pragma unroll
            for (int j = 0; j < 4; ++j) b[j] = Ws[kk][tx * 4 + j];
            #pragma unroll
            for (int i = 0; i < 4; ++i)
                #pragma unroll
                for (int j = 0; j < 4; ++j)
                    acc[i][j] = fmaf(a[i], b[j], acc[i][j]);
        }
        __syncthreads();
    }
    #pragma unroll
    for (int i = 0; i < 4; ++i) {
        int r = row0 + i;
        if (r >= M) continue;
        #pragma unroll
        for (int j = 0; j < 4; ++j) {
            int c = col0 + j;
            float val = acc[i][j] + bias[c];
            if (ACT == 1) val = tanhf(val);
            if (ACT == 2) val = fmaxf(val, 0.f);
            if (res) val += res[(size_t)r * NC + c];
            stf(&C[(size_t)r * NC + c], val);
        }
    }
}

// ---------- edge pass A: logits + segment max (one wave per edge) ----------
__global__ __launch_bounds__(256)
void edge_logits_kernel(const int* __restrict__ src, const int* __restrict__ dst,
                        const bf16* __restrict__ q, const bf16* __restrict__ k,
                        float* __restrict__ logits, unsigned* __restrict__ m, int E)
{
    int wave = (blockIdx.x * blockDim.x + threadIdx.x) >> 6;
    int lane = threadIdx.x & 63;
    if (wave >= E) return;
    int s = src[wave], d = dst[wave];
    const bf16* qd = q + (size_t)d * OUT_C;
    const bf16* ks = k + (size_t)s * OUT_C;
    float p0 = ldf(&qd[lane])       * ldf(&ks[lane]);
    float p1 = ldf(&qd[64  + lane]) * ldf(&ks[64  + lane]);
    float p2 = ldf(&qd[128 + lane]) * ldf(&ks[128 + lane]);
    float p3 = ldf(&qd[192 + lane]) * ldf(&ks[192 + lane]);
    #pragma unroll
    for (int off = 32; off; off >>= 1) {
        p0 += __shfl_xor(p0, off);
        p1 += __shfl_xor(p1, off);
        p2 += __shfl_xor(p2, off);
        p3 += __shfl_xor(p3, off);
    }
    if (lane == 0) {
        const float sc = 0.125f;  // 1/sqrt(64)
        float l0 = p0 * sc, l1 = p1 * sc, l2 = p2 * sc, l3 = p3 * sc;
        float* lp = logits + (size_t)wave * 4;
        lp[0] = l0; lp[1] = l1; lp[2] = l2; lp[3] = l3;
        unsigned* mp = m + (size_t)d * 4;
        atomicMax(&mp[0], fenc(l0));
        atomicMax(&mp[1], fenc(l1));
        atomicMax(&mp[2], fenc(l2));
        atomicMax(&mp[3], fenc(l3));
    }
}

// ---------- edge pass B: e = exp(l - m); s += e; out[dst] += e * v[src] ----------
__global__ __launch_bounds__(256)
void edge_aggr_kernel(const int* __restrict__ src, const int* __restrict__ dst,
                      const bf16* __restrict__ v, const float* __restrict__ logits,
                      const unsigned* __restrict__ m, float* __restrict__ ssum,
                      float* __restrict__ out, int E)
{
    int wave = (blockIdx.x * blockDim.x + threadIdx.x) >> 6;
    int lane = threadIdx.x & 63;
    if (wave >= E) return;
    int s_ = src[wave], d_ = dst[wave];
    const bf16* vs = v + (size_t)s_ * OUT_C;
    float* od = out + (size_t)d_ * OUT_C;
    #pragma unroll
    for (int h = 0; h < 4; ++h) {
        float l  = logits[(size_t)wave * 4 + h];
        float mm = fdec(m[(size_t)d_ * 4 + h]);
        float e  = __expf(l - mm);
        if (lane == 0) atomicAdd(&ssum[(size_t)d_ * 4 + h], e);
        atomicAdd(&od[h * 64 + lane], e * ldf(&vs[h * 64 + lane]));
    }
}

// ---------- finalize conv (divide by s, relu) + per-channel BN stats ----------
template<bool DIVRELU>
__global__ __launch_bounds__(256)
void finalize_stats_kernel(float* __restrict__ x, const float* __restrict__ s,
                           float* __restrict__ bnsum, float* __restrict__ bnsumsq, int M)
{
    const int c = threadIdx.x;   // channel 0..255
    const int r0 = blockIdx.x * 64;
    const int r1 = min(r0 + 64, M);
    float ls = 0.f, lq = 0.f;
    for (int r = r0; r < r1; ++r) {
        size_t idx = (size_t)r * OUT_C + c;
        float val = x[idx];
        if (DIVRELU) {
            float den = s[(size_t)r * 4 + (c >> 6)] + 1e-16f;
            val = fmaxf(val / den, 0.f);
            x[idx] = val;
        }
        ls += val;
        lq += val * val;
    }
    atomicAdd(&bnsum[c], ls);
    atomicAdd(&bnsumsq[c], lq);
}

// ---------- BN apply: y = (x - mu) * rsqrt(var+eps) * g + be (+add) ----------
template<typename TO>
__global__ __launch_bounds__(256)
void bn_apply_kernel(const float* __restrict__ x, const float* __restrict__ bnsum,
                     const float* __restrict__ bnsumsq, const float* __restrict__ g,
                     const float* __restrict__ be, const bf16* __restrict__ add,
                     TO* __restrict__ y, float invM, size_t total)
{
    size_t idx = (size_t)blockIdx.x * blockDim.x + threadIdx.x;
    if (idx >= total) return;
    int c = (int)(idx & 255);
    float mu  = bnsum[c] * invM;
    float var = bnsumsq[c] * invM - mu * mu;
    float val = (x[idx] - mu) * rsqrtf(var + 1e-5f) * g[c] + be[c];
    if (add) val += ldf(&add[idx]);
    stf(&y[idx], val);
}

// ---------- pooling ----------
__global__ __launch_bounds__(256)
void pool_accum_kernel(const float* __restrict__ h, const int* __restrict__ ibatch,
                       float* __restrict__ pooled, float* __restrict__ counts, int Nn)
{
    int n = blockIdx.x;
    if (n >= Nn) return;
    int g = ibatch[n];
    int c = threadIdx.x;
    atomicAdd(&pooled[(size_t)g * OUT_C + c], h[(size_t)n * OUT_C + c]);
    if (c == 0) atomicAdd(&counts[g], 1.0f);
}

__global__ __launch_bounds__(256)
void pool_div_kernel(float* __restrict__ pooled, const float* __restrict__ counts)
{
    int idx = blockIdx.x * blockDim.x + threadIdx.x;
    if (idx >= N_GRAPH * OUT_C) return;
    int g = idx >> 8;
    pooled[idx] /= fmaxf(counts[g], 1.0f);
}

extern "C" void kernel_launch(void* const* d_in, const int* in_sizes, int n_in,
                              void* d_out, int out_size, void* d_ws, size_t ws_size,
                              hipStream_t stream)
{
    // inputs (setup_inputs order)
    const float* drug_x  = (const float*)d_in[0];
    const int*   adj     = (const int*)  d_in[1];
    const int*   ibatch  = (const int*)  d_in[2];
    const float* cline_x = (const float*)d_in[3];
    const float* Wq1 = (const float*)d_in[4];  const float* bq1 = (const float*)d_in[5];
    const float* Wk1 = (const float*)d_in[6];  const float* bk1 = (const float*)d_in[7];
    const float* Wv1 = (const float*)d_in[8];  const float* bv1 = (const float*)d_in[9];
    const float* g1  = (const float*)d_in[10]; const float* be1 = (const float*)d_in[11];
    const float* Wq2 = (const float*)d_in[12]; const float* bq2 = (const float*)d_in[13];
    const float* Wk2 = (const float*)d_in[14]; const float* bk2 = (const float*)d_in[15];
    const float* Wv2 = (const float*)d_in[16]; const float* bv2 = (const float*)d_in[17];
    const float* g2  = (const float*)d_in[18]; const float* be2 = (const float*)d_in[19];
    const float* Wc1 = (const float*)d_in[20]; const float* bc1 = (const float*)d_in[21];
    const float* gc  = (const float*)d_in[22]; const float* bec = (const float*)d_in[23];
    const float* Wc2 = (const float*)d_in[24]; const float* bc2 = (const float*)d_in[25];

    const int* srcp = adj;            // drug_adj[0]
    const int* dstp = adj + N_EDGES;  // drug_adj[1]

    // ---- workspace arena (~219 MB) with lifetime overlap ----
    // bufA (bf16 N*256): q, then v
    // bufB (fp32 N*256): k (bf16, first half) -> acc (fp32) -> final h (fp32)
    char* p = (char*)d_ws;
    bf16*  bufA  = (bf16*)p;  p += (size_t)N_NODES * OUT_C * sizeof(bf16);
    float* bufB  = (float*)p; p += (size_t)N_NODES * OUT_C * sizeof(float);
    bf16*  h1    = (bf16*)p;  p += (size_t)N_NODES * OUT_C * sizeof(bf16);
    float* logits= (float*)p; p += (size_t)N_EDGES * 4 * sizeof(float);
    unsigned* mbuf = (unsigned*)p; p += (size_t)N_NODES * 4 * sizeof(unsigned);
    float* sbuf  = (float*)p; p += (size_t)N_NODES * 4 * sizeof(float);
    float* bnsum = (float*)p; p += 256 * sizeof(float);
    float* bnsumsq=(float*)p; p += 256 * sizeof(float);
    float* counts= (float*)p; p += N_GRAPH * sizeof(float);
    float* c1    = (float*)p; p += (size_t)B_CL * OUT_C * sizeof(float);
    float* cbn   = (float*)p; p += (size_t)B_CL * OUT_C * sizeof(float);
    size_t needed = (size_t)(p - (char*)d_ws);
    if (ws_size < needed) return;   // graceful fail -> absmax report, not a crash
    bf16* kbuf = (bf16*)bufB;

    float* out_pool = (float*)d_out;                      // [G,256]
    float* out_c    = out_pool + (size_t)N_GRAPH * OUT_C; // [B,256]

    dim3 gemmGridN((N_NODES + 63) / 64, OUT_C / 64);
    dim3 gemmGridB((B_CL + 63) / 64, OUT_C / 64);
    const int edgeBlocks = (N_EDGES + 3) / 4;   // 1 wave/edge, 4 waves/block
    const size_t nTot = (size_t)N_NODES * OUT_C;

    // ===================== drug layer 1 =====================
    gemm_bias_kernel<0, float, bf16><<<gemmGridN, 256, 0, stream>>>(drug_x, Wq1, bq1, nullptr, bufA, N_NODES, DRUG_DIM, OUT_C);
    gemm_bias_kernel<0, float, bf16><<<gemmGridN, 256, 0, stream>>>(drug_x, Wk1, bk1, nullptr, kbuf, N_NODES, DRUG_DIM, OUT_C);
    hipMemsetAsync(mbuf, 0, (size_t)N_NODES * 4 * sizeof(unsigned) * 2, stream); // m + s
    edge_logits_kernel<<<edgeBlocks, 256, 0, stream>>>(srcp, dstp, bufA, kbuf, logits, mbuf, N_EDGES);
    gemm_bias_kernel<0, float, bf16><<<gemmGridN, 256, 0, stream>>>(drug_x, Wv1, bv1, nullptr, bufA, N_NODES, DRUG_DIM, OUT_C);
    hipMemsetAsync(bufB, 0, nTot * sizeof(float), stream);
    edge_aggr_kernel<<<edgeBlocks, 256, 0, stream>>>(srcp, dstp, bufA, logits, mbuf, sbuf, bufB, N_EDGES);
    hipMemsetAsync(bnsum, 0, 512 * sizeof(float), stream);
    finalize_stats_kernel<true><<<(N_NODES + 63) / 64, 256, 0, stream>>>(bufB, sbuf, bnsum, bnsumsq, N_NODES);
    bn_apply_kernel<bf16><<<(nTot + 255) / 256, 256, 0, stream>>>(
        bufB, bnsum, bnsumsq, g1, be1, nullptr, h1, 1.0f / N_NODES, nTot);

    // ===================== drug layer 2 =====================
    gemm_bias_kernel<0, bf16, bf16><<<gemmGridN, 256, 0, stream>>>(h1, Wq2, bq2, nullptr, bufA, N_NODES, OUT_C, OUT_C);
    gemm_bias_kernel<0, bf16, bf16><<<gemmGridN, 256, 0, stream>>>(h1, Wk2, bk2, nullptr, kbuf, N_NODES, OUT_C, OUT_C);
    hipMemsetAsync(mbuf, 0, (size_t)N_NODES * 4 * sizeof(unsigned) * 2, stream);
    edge_logits_kernel<<<edgeBlocks, 256, 0, stream>>>(srcp, dstp, bufA, kbuf, logits, mbuf, N_EDGES);
    gemm_bias_kernel<0, bf16, bf16><<<gemmGridN, 256, 0, stream>>>(h1, Wv2, bv2, nullptr, bufA, N_NODES, OUT_C, OUT_C);
    hipMemsetAsync(bufB, 0, nTot * sizeof(float), stream);
    edge_aggr_kernel<<<edgeBlocks, 256, 0, stream>>>(srcp, dstp, bufA, logits, mbuf, sbuf, bufB, N_EDGES);
    hipMemsetAsync(bnsum, 0, 512 * sizeof(float), stream);
    finalize_stats_kernel<true><<<(N_NODES + 63) / 64, 256, 0, stream>>>(bufB, sbuf, bnsum, bnsumsq, N_NODES);
    // final h = h1 + bn2(y2), fp32 into bufB
    bn_apply_kernel<float><<<(nTot + 255) / 256, 256, 0, stream>>>(
        bufB, bnsum, bnsumsq, g2, be2, h1, bufB, 1.0f / N_NODES, nTot);

    // ===================== pooling =====================
    hipMemsetAsync(out_pool, 0, (size_t)N_GRAPH * OUT_C * sizeof(float), stream);
    hipMemsetAsync(counts, 0, N_GRAPH * sizeof(float), stream);
    pool_accum_kernel<<<N_NODES, 256, 0, stream>>>(bufB, ibatch, out_pool, counts, N_NODES);
    pool_div_kernel<<<(N_GRAPH * OUT_C + 255) / 256, 256, 0, stream>>>(out_pool, counts);

    // ===================== cline branch (all fp32, ~4 MB) =====================
    gemm_bias_kernel<1, float, float><<<gemmGridB, 256, 0, stream>>>(cline_x, Wc1, bc1, nullptr, c1, B_CL, CLINE_DIM, OUT_C);
    hipMemsetAsync(bnsum, 0, 512 * sizeof(float), stream);
    finalize_stats_kernel<false><<<(B_CL + 63) / 64, 256, 0, stream>>>(c1, nullptr, bnsum, bnsumsq, B_CL);
    bn_apply_kernel<float><<<((size_t)B_CL * OUT_C + 255) / 256, 256, 0, stream>>>(
        c1, bnsum, bnsumsq, gc, bec, nullptr, cbn, 1.0f / B_CL, (size_t)B_CL * OUT_C);
    // out_c = c1 + relu(cbn @ Wc2 + bc2)
    gemm_bias_kernel<2, float, float><<<gemmGridB, 256, 0, stream>>>(cbn, Wc2, bc2, c1, out_c, B_CL, OUT_C, OUT_C);
}

// Round 3
// 1760.730 us; speedup vs baseline: 1.4935x; 1.4935x over previous
//
#include <hip/hip_runtime.h>
#include <hip/hip_bf16.h>

// Problem constants (match reference)
static constexpr int N_NODES  = 100000;
static constexpr int N_EDGES  = 400000;
static constexpr int DRUG_DIM = 75;
static constexpr int OUT_C    = 256;   // OUT
static constexpr int N_GRAPH  = 2048;  // G
static constexpr int B_CL     = 2048;  // B
static constexpr int CLINE_DIM= 954;

using bf16 = __hip_bfloat16;

// ---------- load/store helpers ----------
__device__ __forceinline__ float ldf(const float* p) { return *p; }
__device__ __forceinline__ float ldf(const bf16* p)  { return __bfloat162float(*p); }
__device__ __forceinline__ void  stf(float* p, float v) { *p = v; }
__device__ __forceinline__ void  stf(bf16* p, float v)  { *p = __float2bfloat16(v); }
__device__ __forceinline__ float bfu(unsigned short u) { return __uint_as_float(((unsigned)u) << 16); }
__device__ __forceinline__ unsigned short f2bu(float f) {
    bf16 h = __float2bfloat16(f);
    return *reinterpret_cast<unsigned short*>(&h);
}

// ---------- tiled GEMM: C = act(A@W + bias) (+res) ----------
template<int ACT, typename TA, typename TO>
__global__ __launch_bounds__(256)
void gemm_bias_kernel(const TA* __restrict__ A, const float* __restrict__ W,
                      const float* __restrict__ bias, const float* __restrict__ res,
                      TO* __restrict__ C, int M, int K, int NC)
{
    __shared__ float As[16][64];
    __shared__ float Ws[16][64];
    const int mtile = blockIdx.x;
    const int ntile = blockIdx.y;
    const int tid = threadIdx.x;
    const int tx = tid & 15;
    const int ty = tid >> 4;
    const int row0 = mtile * 64 + ty * 4;
    const int col0 = ntile * 64 + tx * 4;

    float acc[4][4] = {};
    for (int k0 = 0; k0 < K; k0 += 16) {
        #pragma unroll
        for (int l = 0; l < 4; ++l) {
            int lin = tid * 4 + l;
            int m  = lin >> 4;
            int kk = lin & 15;
            int gr = mtile * 64 + m;
            int gk = k0 + kk;
            As[kk][m] = (gr < M && gk < K) ? ldf(&A[(size_t)gr * K + gk]) : 0.f;
        }
        #pragma unroll
        for (int l = 0; l < 4; ++l) {
            int lin = tid * 4 + l;
            int kk = lin >> 6;
            int n  = lin & 63;
            int gk = k0 + kk;
            Ws[kk][n] = (gk < K) ? W[(size_t)gk * NC + ntile * 64 + n] : 0.f;
        }
        __syncthreads();
        #pragma unroll
        for (int kk = 0; kk < 16; ++kk) {
            float a[4], b[4];
            #pragma unroll
            for (int i = 0; i < 4; ++i) a[i] = As[kk][ty * 4 + i];
            #pragma unroll
            for (int j = 0; j < 4; ++j) b[j] = Ws[kk][tx * 4 + j];
            #pragma unroll
            for (int i = 0; i < 4; ++i)
                #pragma unroll
                for (int j = 0; j < 4; ++j)
                    acc[i][j] = fmaf(a[i], b[j], acc[i][j]);
        }
        __syncthreads();
    }
    #pragma unroll
    for (int i = 0; i < 4; ++i) {
        int r = row0 + i;
        if (r >= M) continue;
        #pragma unroll
        for (int j = 0; j < 4; ++j) {
            int c = col0 + j;
            float val = acc[i][j] + bias[c];
            if (ACT == 1) val = tanhf(val);
            if (ACT == 2) val = fmaxf(val, 0.f);
            if (res) val += res[(size_t)r * NC + c];
            stf(&C[(size_t)r * NC + c], val);
        }
    }
}

// ================= CSR build =================
__global__ __launch_bounds__(256)
void hist_kernel(const int* __restrict__ dst, int* __restrict__ deg, int E)
{
    int e = blockIdx.x * 256 + threadIdx.x;
    if (e < E) atomicAdd(&deg[dst[e]], 1);
}

// block-local exclusive scan over chunks of 1024 (256 thr x 4 elems)
__global__ __launch_bounds__(256)
void scan1_kernel(const int* __restrict__ deg, int* __restrict__ part,
                  int* __restrict__ bsum, int n)
{
    __shared__ int sh[256];
    const int t = threadIdx.x;
    const int b0 = blockIdx.x * 1024;
    int v[4]; int s = 0;
    #pragma unroll
    for (int j = 0; j < 4; ++j) {
        int idx = b0 + t * 4 + j;
        v[j] = (idx < n) ? deg[idx] : 0;
        s += v[j];
    }
    sh[t] = s; __syncthreads();
    for (int off = 1; off < 256; off <<= 1) {
        int x = (t >= off) ? sh[t - off] : 0;
        __syncthreads();
        sh[t] += x;
        __syncthreads();
    }
    if (t == 255) bsum[blockIdx.x] = sh[255];
    int run = sh[t] - s;   // exclusive prefix of this thread's chunk
    #pragma unroll
    for (int j = 0; j < 4; ++j) {
        int idx = b0 + t * 4 + j;
        if (idx < n) part[idx] = run;
        run += v[j];
    }
}

__global__ __launch_bounds__(256)
void scan2_kernel(const int* __restrict__ bsum, int* __restrict__ bsume, int nb)
{
    __shared__ int sh[256];
    const int t = threadIdx.x;
    int x0 = (t < nb) ? bsum[t] : 0;
    sh[t] = x0; __syncthreads();
    for (int off = 1; off < 256; off <<= 1) {
        int x = (t >= off) ? sh[t - off] : 0;
        __syncthreads();
        sh[t] += x;
        __syncthreads();
    }
    if (t < nb) bsume[t] = sh[t] - x0;
}

__global__ __launch_bounds__(256)
void scan3_kernel(int* __restrict__ rowptr, int* __restrict__ cursor,
                  const int* __restrict__ bsume, int n, int E)
{
    int idx = blockIdx.x * 256 + threadIdx.x;
    if (idx < n) {
        int val = rowptr[idx] + bsume[idx >> 10];
        rowptr[idx] = val;
        cursor[idx] = val;
    }
    if (idx == 0) rowptr[n] = E;
}

__global__ __launch_bounds__(256)
void scatter_kernel(const int* __restrict__ src, const int* __restrict__ dst,
                    int* __restrict__ cursor, int* __restrict__ esrc, int E)
{
    int e = blockIdx.x * 256 + threadIdx.x;
    if (e < E) {
        int slot = atomicAdd(&cursor[dst[e]], 1);
        esrc[slot] = src[e];
    }
}

// ================= fused attention (CSR gather) =================
// wave per dst node; lane = head*16 + sub (head = lane>>4); each lane owns
// 4 consecutive dims of its head via ushort4 loads.
__global__ __launch_bounds__(256)
void attn_logits_kernel(const int* __restrict__ rowptr, const int* __restrict__ esrc,
                        const bf16* __restrict__ q, const bf16* __restrict__ k,
                        float* __restrict__ alpha, float* __restrict__ msbuf, int n)
{
    int node = blockIdx.x * 4 + (threadIdx.x >> 6);
    if (node >= n) return;
    int lane = threadIdx.x & 63;
    int head = lane >> 4;
    int lo = rowptr[node], hi = rowptr[node + 1];

    ushort4 qu = ((const ushort4*)(q + (size_t)node * OUT_C))[lane];
    float q0 = bfu(qu.x), q1 = bfu(qu.y), q2 = bfu(qu.z), q3 = bfu(qu.w);

    float m = -INFINITY, s = 0.f;
    for (int i = lo; i < hi; ++i) {
        int sn = esrc[i];
        ushort4 ku = ((const ushort4*)(k + (size_t)sn * OUT_C))[lane];
        float p = q0 * bfu(ku.x);
        p = fmaf(q1, bfu(ku.y), p);
        p = fmaf(q2, bfu(ku.z), p);
        p = fmaf(q3, bfu(ku.w), p);
        p += __shfl_xor(p, 1);
        p += __shfl_xor(p, 2);
        p += __shfl_xor(p, 4);
        p += __shfl_xor(p, 8);       // 16-lane group sum -> per-head dot
        float l = p * 0.125f;        // 1/sqrt(64)
        if ((lane & 15) == 0) alpha[(size_t)i * 4 + head] = l;
        float mn = fmaxf(m, l);
        s = s * __expf(m - mn) + __expf(l - mn);
        m = mn;
    }
    if ((lane & 15) == 0) {
        msbuf[(size_t)node * 8 + head]     = m;
        msbuf[(size_t)node * 8 + 4 + head] = s;
    }
}

__global__ __launch_bounds__(256)
void attn_aggr_kernel(const int* __restrict__ rowptr, const int* __restrict__ esrc,
                      const bf16* __restrict__ v, const float* __restrict__ alpha,
                      const float* __restrict__ msbuf, bf16* __restrict__ out, int n)
{
    int node = blockIdx.x * 4 + (threadIdx.x >> 6);
    if (node >= n) return;
    int lane = threadIdx.x & 63;
    int head = lane >> 4;
    int lo = rowptr[node], hi = rowptr[node + 1];

    float m   = msbuf[(size_t)node * 8 + head];
    float inv = 1.f / (msbuf[(size_t)node * 8 + 4 + head] + 1e-16f);

    float a0 = 0.f, a1 = 0.f, a2 = 0.f, a3 = 0.f;
    for (int i = lo; i < hi; ++i) {
        int sn = esrc[i];
        float e = __expf(alpha[(size_t)i * 4 + head] - m) * inv;
        ushort4 vu = ((const ushort4*)(v + (size_t)sn * OUT_C))[lane];
        a0 = fmaf(e, bfu(vu.x), a0);
        a1 = fmaf(e, bfu(vu.y), a1);
        a2 = fmaf(e, bfu(vu.z), a2);
        a3 = fmaf(e, bfu(vu.w), a3);
    }
    ushort4 o;
    o.x = f2bu(fmaxf(a0, 0.f));
    o.y = f2bu(fmaxf(a1, 0.f));
    o.z = f2bu(fmaxf(a2, 0.f));
    o.w = f2bu(fmaxf(a3, 0.f));
    ((ushort4*)(out + (size_t)node * OUT_C))[lane] = o;
}

// ---------- per-channel BN stats (pure read) ----------
template<typename TX>
__global__ __launch_bounds__(256)
void col_stats_kernel(const TX* __restrict__ x, float* __restrict__ bnsum,
                      float* __restrict__ bnsumsq, int M)
{
    const int c = threadIdx.x;
    const int r0 = blockIdx.x * 64;
    const int r1 = min(r0 + 64, M);
    float ls = 0.f, lq = 0.f;
    for (int r = r0; r < r1; ++r) {
        float val = ldf(&x[(size_t)r * OUT_C + c]);
        ls += val;
        lq += val * val;
    }
    atomicAdd(&bnsum[c], ls);
    atomicAdd(&bnsumsq[c], lq);
}

// ---------- BN apply: y = (x - mu) * rsqrt(var+eps) * g + be (+add) ----------
template<typename TX, typename TO>
__global__ __launch_bounds__(256)
void bn_apply_kernel(const TX* __restrict__ x, const float* __restrict__ bnsum,
                     const float* __restrict__ bnsumsq, const float* __restrict__ g,
                     const float* __restrict__ be, const bf16* __restrict__ add,
                     TO* __restrict__ y, float invM, size_t total)
{
    size_t idx = (size_t)blockIdx.x * blockDim.x + threadIdx.x;
    if (idx >= total) return;
    int c = (int)(idx & 255);
    float mu  = bnsum[c] * invM;
    float var = bnsumsq[c] * invM - mu * mu;
    float val = (ldf(&x[idx]) - mu) * rsqrtf(var + 1e-5f) * g[c] + be[c];
    if (add) val += ldf(&add[idx]);
    stf(&y[idx], val);
}

// ---------- pooling: block per graph, binary search on sorted ibatch ----------
__global__ __launch_bounds__(256)
void pool_kernel(const bf16* __restrict__ h, const int* __restrict__ ibatch,
                 float* __restrict__ out)
{
    int g = blockIdx.x;
    __shared__ int bounds[2];
    if (threadIdx.x == 0) {
        int lo = 0, hi = N_NODES;
        while (lo < hi) { int mid = (lo + hi) >> 1; if (ibatch[mid] < g) lo = mid + 1; else hi = mid; }
        bounds[0] = lo;
        int lo2 = lo, hi2 = N_NODES;
        while (lo2 < hi2) { int mid = (lo2 + hi2) >> 1; if (ibatch[mid] < g + 1) lo2 = mid + 1; else hi2 = mid; }
        bounds[1] = lo2;
    }
    __syncthreads();
    int lo = bounds[0], hi = bounds[1];
    int c = threadIdx.x;
    float s = 0.f;
    for (int r = lo; r < hi; ++r) s += ldf(&h[(size_t)r * OUT_C + c]);
    out[(size_t)g * OUT_C + c] = s / fmaxf((float)(hi - lo), 1.f);
}

extern "C" void kernel_launch(void* const* d_in, const int* in_sizes, int n_in,
                              void* d_out, int out_size, void* d_ws, size_t ws_size,
                              hipStream_t stream)
{
    const float* drug_x  = (const float*)d_in[0];
    const int*   adj     = (const int*)  d_in[1];
    const int*   ibatch  = (const int*)  d_in[2];
    const float* cline_x = (const float*)d_in[3];
    const float* Wq1 = (const float*)d_in[4];  const float* bq1 = (const float*)d_in[5];
    const float* Wk1 = (const float*)d_in[6];  const float* bk1 = (const float*)d_in[7];
    const float* Wv1 = (const float*)d_in[8];  const float* bv1 = (const float*)d_in[9];
    const float* g1  = (const float*)d_in[10]; const float* be1 = (const float*)d_in[11];
    const float* Wq2 = (const float*)d_in[12]; const float* bq2 = (const float*)d_in[13];
    const float* Wk2 = (const float*)d_in[14]; const float* bk2 = (const float*)d_in[15];
    const float* Wv2 = (const float*)d_in[16]; const float* bv2 = (const float*)d_in[17];
    const float* g2  = (const float*)d_in[18]; const float* be2 = (const float*)d_in[19];
    const float* Wc1 = (const float*)d_in[20]; const float* bc1 = (const float*)d_in[21];
    const float* gc  = (const float*)d_in[22]; const float* bec = (const float*)d_in[23];
    const float* Wc2 = (const float*)d_in[24]; const float* bc2 = (const float*)d_in[25];

    const int* srcp = adj;            // drug_adj[0]
    const int* dstp = adj + N_EDGES;  // drug_adj[1]

    // ---- workspace arena (~217 MB) ----
    char* p = (char*)d_ws;
    bf16*  qv    = (bf16*)p;  p += (size_t)N_NODES * OUT_C * sizeof(bf16);   // q then v
    bf16*  kbuf  = (bf16*)p;  p += (size_t)N_NODES * OUT_C * sizeof(bf16);
    bf16*  conv  = (bf16*)p;  p += (size_t)N_NODES * OUT_C * sizeof(bf16);   // conv out / final h
    bf16*  h1    = (bf16*)p;  p += (size_t)N_NODES * OUT_C * sizeof(bf16);
    float* alpha = (float*)p; p += (size_t)N_EDGES * 4 * sizeof(float);      // raw logits; later cline bufs
    float* msbuf = (float*)p; p += (size_t)N_NODES * 8 * sizeof(float);
    int*   rowptr= (int*)p;   p += (size_t)(N_NODES + 1) * sizeof(int);
    int*   degcur= (int*)p;   p += (size_t)N_NODES * sizeof(int);            // deg, then cursor
    int*   bsum  = (int*)p;   p += 256 * sizeof(int);
    int*   bsume = (int*)p;   p += 256 * sizeof(int);
    int*   esrc  = (int*)p;   p += (size_t)N_EDGES * sizeof(int);
    float* bnsum = (float*)p; p += 256 * sizeof(float);
    float* bnsumsq=(float*)p; p += 256 * sizeof(float);
    size_t needed = (size_t)(p - (char*)d_ws);
    if (ws_size < needed) return;

    // cline buffers alias the (then-dead) alpha region: need 2*2048*256 f32 = 4.2MB <= 6.4MB
    float* c1  = alpha;
    float* cbn = alpha + (size_t)B_CL * OUT_C;

    float* out_pool = (float*)d_out;                      // [G,256]
    float* out_c    = out_pool + (size_t)N_GRAPH * OUT_C; // [B,256]

    dim3 gemmGridN((N_NODES + 63) / 64, OUT_C / 64);
    dim3 gemmGridB((B_CL + 63) / 64, OUT_C / 64);
    const int nodeBlocks = (N_NODES + 3) / 4;   // 1 wave/node
    const size_t nTot = (size_t)N_NODES * OUT_C;

    // ===================== CSR build (shared by both layers) =====================
    hipMemsetAsync(degcur, 0, N_NODES * sizeof(int), stream);
    hist_kernel<<<(N_EDGES + 255) / 256, 256, 0, stream>>>(dstp, degcur, N_EDGES);
    const int NB1 = (N_NODES + 1023) / 1024;   // 98
    scan1_kernel<<<NB1, 256, 0, stream>>>(degcur, rowptr, bsum, N_NODES);
    scan2_kernel<<<1, 256, 0, stream>>>(bsum, bsume, NB1);
    scan3_kernel<<<(N_NODES + 255) / 256, 256, 0, stream>>>(rowptr, degcur, bsume, N_NODES, N_EDGES);
    scatter_kernel<<<(N_EDGES + 255) / 256, 256, 0, stream>>>(srcp, dstp, degcur, esrc, N_EDGES);

    // ===================== drug layer 1 =====================
    gemm_bias_kernel<0, float, bf16><<<gemmGridN, 256, 0, stream>>>(drug_x, Wq1, bq1, nullptr, qv,   N_NODES, DRUG_DIM, OUT_C);
    gemm_bias_kernel<0, float, bf16><<<gemmGridN, 256, 0, stream>>>(drug_x, Wk1, bk1, nullptr, kbuf, N_NODES, DRUG_DIM, OUT_C);
    attn_logits_kernel<<<nodeBlocks, 256, 0, stream>>>(rowptr, esrc, qv, kbuf, alpha, msbuf, N_NODES);
    gemm_bias_kernel<0, float, bf16><<<gemmGridN, 256, 0, stream>>>(drug_x, Wv1, bv1, nullptr, qv,   N_NODES, DRUG_DIM, OUT_C);
    attn_aggr_kernel<<<nodeBlocks, 256, 0, stream>>>(rowptr, esrc, qv, alpha, msbuf, conv, N_NODES);
    hipMemsetAsync(bnsum, 0, 512 * sizeof(float), stream);
    col_stats_kernel<bf16><<<(N_NODES + 63) / 64, 256, 0, stream>>>(conv, bnsum, bnsumsq, N_NODES);
    bn_apply_kernel<bf16, bf16><<<(nTot + 255) / 256, 256, 0, stream>>>(
        conv, bnsum, bnsumsq, g1, be1, nullptr, h1, 1.0f / N_NODES, nTot);

    // ===================== drug layer 2 =====================
    gemm_bias_kernel<0, bf16, bf16><<<gemmGridN, 256, 0, stream>>>(h1, Wq2, bq2, nullptr, qv,   N_NODES, OUT_C, OUT_C);
    gemm_bias_kernel<0, bf16, bf16><<<gemmGridN, 256, 0, stream>>>(h1, Wk2, bk2, nullptr, kbuf, N_NODES, OUT_C, OUT_C);
    attn_logits_kernel<<<nodeBlocks, 256, 0, stream>>>(rowptr, esrc, qv, kbuf, alpha, msbuf, N_NODES);
    gemm_bias_kernel<0, bf16, bf16><<<gemmGridN, 256, 0, stream>>>(h1, Wv2, bv2, nullptr, qv,   N_NODES, OUT_C, OUT_C);
    attn_aggr_kernel<<<nodeBlocks, 256, 0, stream>>>(rowptr, esrc, qv, alpha, msbuf, conv, N_NODES);
    hipMemsetAsync(bnsum, 0, 512 * sizeof(float), stream);
    col_stats_kernel<bf16><<<(N_NODES + 63) / 64, 256, 0, stream>>>(conv, bnsum, bnsumsq, N_NODES);
    // final h = h1 + bn2(conv), bf16 in place
    bn_apply_kernel<bf16, bf16><<<(nTot + 255) / 256, 256, 0, stream>>>(
        conv, bnsum, bnsumsq, g2, be2, h1, conv, 1.0f / N_NODES, nTot);

    // ===================== pooling (no atomics) =====================
    pool_kernel<<<N_GRAPH, 256, 0, stream>>>(conv, ibatch, out_pool);

    // ===================== cline branch =====================
    gemm_bias_kernel<1, float, float><<<gemmGridB, 256, 0, stream>>>(cline_x, Wc1, bc1, nullptr, c1, B_CL, CLINE_DIM, OUT_C);
    hipMemsetAsync(bnsum, 0, 512 * sizeof(float), stream);
    col_stats_kernel<float><<<(B_CL + 63) / 64, 256, 0, stream>>>(c1, bnsum, bnsumsq, B_CL);
    bn_apply_kernel<float, float><<<((size_t)B_CL * OUT_C + 255) / 256, 256, 0, stream>>>(
        c1, bnsum, bnsumsq, gc, bec, nullptr, cbn, 1.0f / B_CL, (size_t)B_CL * OUT_C);
    gemm_bias_kernel<2, float, float><<<gemmGridB, 256, 0, stream>>>(cbn, Wc2, bc2, c1, out_c, B_CL, OUT_C, OUT_C);
}

// Round 4
// 1248.403 us; speedup vs baseline: 2.1064x; 1.4104x over previous
//
#include <hip/hip_runtime.h>
#include <hip/hip_bf16.h>

// Problem constants (match reference)
static constexpr int N_NODES  = 100000;
static constexpr int N_EDGES  = 400000;
static constexpr int DRUG_DIM = 75;
static constexpr int OUT_C    = 256;   // OUT
static constexpr int N_GRAPH  = 2048;  // G
static constexpr int B_CL     = 2048;  // B
static constexpr int CLINE_DIM= 954;

using bf16 = __hip_bfloat16;
using short8 = __attribute__((ext_vector_type(8))) short;
using f32x4  = __attribute__((ext_vector_type(4))) float;

template<class A, class B> struct is_same_t { static constexpr bool v = false; };
template<class A> struct is_same_t<A, A>   { static constexpr bool v = true;  };

// ---------- load/store helpers ----------
__device__ __forceinline__ float ldf(const float* p) { return *p; }
__device__ __forceinline__ float ldf(const bf16* p)  { return __bfloat162float(*p); }
__device__ __forceinline__ void  stf(float* p, float v) { *p = v; }
__device__ __forceinline__ void  stf(bf16* p, float v)  { *p = __float2bfloat16(v); }
__device__ __forceinline__ float bfu(unsigned short u) { return __uint_as_float(((unsigned)u) << 16); }
__device__ __forceinline__ unsigned short f2bu(float f) {
    bf16 h = __float2bfloat16(f);
    return *reinterpret_cast<unsigned short*>(&h);
}

// ================= weight prep =================
// W: [K, NW] fp32 -> Wt rows [n0, n0+NW), each row length Kpad bf16, zero-padded k>=K
__global__ __launch_bounds__(256)
void convert_wt_kernel(const float* __restrict__ W, bf16* __restrict__ Wt,
                       int K, int NW, int n0, int Kpad)
{
    int n = blockIdx.x;
    for (int k = threadIdx.x; k < Kpad; k += 256) {
        float f = (k < K) ? W[(size_t)k * NW + n] : 0.f;
        Wt[(size_t)(n0 + n) * Kpad + k] = __float2bfloat16(f);
    }
}

__global__ __launch_bounds__(256)
void concat_bias_kernel(const float* __restrict__ a, const float* __restrict__ b,
                        float* __restrict__ out)
{
    int i = blockIdx.x * 256 + threadIdx.x;
    if (i < 512) out[i] = (i < 256) ? a[i] : b[i - 256];
}

// ================= MFMA GEMM =================
// C[M x NCOLS] = act(A[M x Kst] @ Wt^T + bias) (+res). Wt: [NCOLS][Kpad] bf16 (B^T).
// C row stride NC. Tile 128x128, BK=64, 4 waves (2x2), 16x16x32 bf16 MFMA.
// LDS XOR swizzle: element_off ^= (row&7)<<3 (16B-chunk granularity).
template<int ACT, typename TA, typename TO>
__global__ __launch_bounds__(256)
void mfma_gemm_kernel(const TA* __restrict__ A, const bf16* __restrict__ Wt,
                      const float* __restrict__ bias, const float* __restrict__ res,
                      TO* __restrict__ C, int M, int Kst, int Kpad, int NC)
{
    __shared__ short As[128 * 64];
    __shared__ short Bs[128 * 64];
    const int mtile = blockIdx.x, ntile = blockIdx.y;
    const int tid = threadIdx.x;
    const int lane = tid & 63, wid = tid >> 6;
    const int wr = wid >> 1, wc = wid & 1;

    const int srow = tid >> 1, sseg = tid & 1;   // staging: 2 threads per row
    const int gr = mtile * 128 + srow;
    const int swz = (srow & 7) << 3;
    const unsigned short* wrow =
        (const unsigned short*)(Wt + (size_t)(ntile * 128 + srow) * Kpad);

    f32x4 acc[4][4] = {};

    for (int k0 = 0; k0 < Kpad; k0 += 64) {
        #pragma unroll
        for (int c = 0; c < 4; ++c) {
            int kloc = sseg * 32 + c * 8;
            short8 av{};
            if constexpr (is_same_t<TA, bf16>::v) {
                if (gr < M)
                    av = *reinterpret_cast<const short8*>(&A[(size_t)gr * Kst + k0 + kloc]);
            } else {
                #pragma unroll
                for (int e = 0; e < 8; ++e) {
                    int gk = k0 + kloc + e;
                    float f = (gr < M && gk < Kst) ? A[(size_t)gr * Kst + gk] : 0.f;
                    av[e] = (short)f2bu(f);
                }
            }
            *reinterpret_cast<short8*>(&As[srow * 64 + (kloc ^ swz)]) = av;
            *reinterpret_cast<short8*>(&Bs[srow * 64 + (kloc ^ swz)]) =
                *reinterpret_cast<const short8*>(&wrow[k0 + kloc]);
        }
        __syncthreads();
        #pragma unroll
        for (int kk = 0; kk < 2; ++kk) {
            const int coff = (kk * 32 + (lane >> 4) * 8) ^ ((lane & 7) << 3);
            short8 a[4], b[4];
            #pragma unroll
            for (int m = 0; m < 4; ++m)
                a[m] = *reinterpret_cast<const short8*>(
                    &As[(wr * 64 + m * 16 + (lane & 15)) * 64 + coff]);
            #pragma unroll
            for (int n = 0; n < 4; ++n)
                b[n] = *reinterpret_cast<const short8*>(
                    &Bs[(wc * 64 + n * 16 + (lane & 15)) * 64 + coff]);
            #pragma unroll
            for (int m = 0; m < 4; ++m)
                #pragma unroll
                for (int n = 0; n < 4; ++n)
                    acc[m][n] = __builtin_amdgcn_mfma_f32_16x16x32_bf16(
                        a[m], b[n], acc[m][n], 0, 0, 0);
        }
        __syncthreads();
    }

    // epilogue: C/D layout col=lane&15, row=(lane>>4)*4+reg
    #pragma unroll
    for (int m = 0; m < 4; ++m) {
        int row0 = mtile * 128 + wr * 64 + m * 16 + ((lane >> 4) << 2);
        #pragma unroll
        for (int n = 0; n < 4; ++n) {
            int col = ntile * 128 + wc * 64 + n * 16 + (lane & 15);
            float bcol = bias[col];
            #pragma unroll
            for (int r = 0; r < 4; ++r) {
                int row = row0 + r;
                if (row < M) {
                    float val = acc[m][n][r] + bcol;
                    if (ACT == 1) val = tanhf(val);
                    if (ACT == 2) val = fmaxf(val, 0.f);
                    if (res) val += res[(size_t)row * NC + col];
                    stf(&C[(size_t)row * NC + col], val);
                }
            }
        }
    }
}

// ================= CSR build =================
__global__ __launch_bounds__(256)
void hist_kernel(const int* __restrict__ dst, int* __restrict__ deg, int E)
{
    int e = blockIdx.x * 256 + threadIdx.x;
    if (e < E) atomicAdd(&deg[dst[e]], 1);
}

__global__ __launch_bounds__(256)
void scan1_kernel(const int* __restrict__ deg, int* __restrict__ part,
                  int* __restrict__ bsum, int n)
{
    __shared__ int sh[256];
    const int t = threadIdx.x;
    const int b0 = blockIdx.x * 1024;
    int v[4]; int s = 0;
    #pragma unroll
    for (int j = 0; j < 4; ++j) {
        int idx = b0 + t * 4 + j;
        v[j] = (idx < n) ? deg[idx] : 0;
        s += v[j];
    }
    sh[t] = s; __syncthreads();
    for (int off = 1; off < 256; off <<= 1) {
        int x = (t >= off) ? sh[t - off] : 0;
        __syncthreads();
        sh[t] += x;
        __syncthreads();
    }
    if (t == 255) bsum[blockIdx.x] = sh[255];
    int run = sh[t] - s;
    #pragma unroll
    for (int j = 0; j < 4; ++j) {
        int idx = b0 + t * 4 + j;
        if (idx < n) part[idx] = run;
        run += v[j];
    }
}

__global__ __launch_bounds__(256)
void scan2_kernel(const int* __restrict__ bsum, int* __restrict__ bsume, int nb)
{
    __shared__ int sh[256];
    const int t = threadIdx.x;
    int x0 = (t < nb) ? bsum[t] : 0;
    sh[t] = x0; __syncthreads();
    for (int off = 1; off < 256; off <<= 1) {
        int x = (t >= off) ? sh[t - off] : 0;
        __syncthreads();
        sh[t] += x;
        __syncthreads();
    }
    if (t < nb) bsume[t] = sh[t] - x0;
}

__global__ __launch_bounds__(256)
void scan3_kernel(int* __restrict__ rowptr, int* __restrict__ cursor,
                  const int* __restrict__ bsume, int n, int E)
{
    int idx = blockIdx.x * 256 + threadIdx.x;
    if (idx < n) {
        int val = rowptr[idx] + bsume[idx >> 10];
        rowptr[idx] = val;
        cursor[idx] = val;
    }
    if (idx == 0) rowptr[n] = E;
}

__global__ __launch_bounds__(256)
void scatter_kernel(const int* __restrict__ src, const int* __restrict__ dst,
                    int* __restrict__ cursor, int* __restrict__ esrc, int E)
{
    int e = blockIdx.x * 256 + threadIdx.x;
    if (e < E) {
        int slot = atomicAdd(&cursor[dst[e]], 1);
        esrc[slot] = src[e];
    }
}

// ================= fused attention (CSR gather) =================
// wave per dst node; lane = head*16 + sub; each lane owns 4 dims of its head.
// q/k/v rows have stride RS (elements).
__global__ __launch_bounds__(256)
void attn_logits_kernel(const int* __restrict__ rowptr, const int* __restrict__ esrc,
                        const bf16* __restrict__ q, const bf16* __restrict__ k, int rs,
                        float* __restrict__ alpha, float* __restrict__ msbuf, int n)
{
    int node = blockIdx.x * 4 + (threadIdx.x >> 6);
    if (node >= n) return;
    int lane = threadIdx.x & 63;
    int head = lane >> 4;
    int lo = rowptr[node], hi = rowptr[node + 1];

    ushort4 qu = ((const ushort4*)(q + (size_t)node * rs))[lane];
    float q0 = bfu(qu.x), q1 = bfu(qu.y), q2 = bfu(qu.z), q3 = bfu(qu.w);

    float m = -INFINITY, s = 0.f;
    for (int i = lo; i < hi; ++i) {
        int sn = esrc[i];
        ushort4 ku = ((const ushort4*)(k + (size_t)sn * rs))[lane];
        float p = q0 * bfu(ku.x);
        p = fmaf(q1, bfu(ku.y), p);
        p = fmaf(q2, bfu(ku.z), p);
        p = fmaf(q3, bfu(ku.w), p);
        p += __shfl_xor(p, 1);
        p += __shfl_xor(p, 2);
        p += __shfl_xor(p, 4);
        p += __shfl_xor(p, 8);
        float l = p * 0.125f;        // 1/sqrt(64)
        if ((lane & 15) == 0) alpha[(size_t)i * 4 + head] = l;
        float mn = fmaxf(m, l);
        s = s * __expf(m - mn) + __expf(l - mn);
        m = mn;
    }
    if ((lane & 15) == 0) {
        msbuf[(size_t)node * 8 + head]     = m;
        msbuf[(size_t)node * 8 + 4 + head] = s;
    }
}

__global__ __launch_bounds__(256)
void attn_aggr_kernel(const int* __restrict__ rowptr, const int* __restrict__ esrc,
                      const bf16* __restrict__ v, int rs, const float* __restrict__ alpha,
                      const float* __restrict__ msbuf, bf16* __restrict__ out, int n)
{
    int node = blockIdx.x * 4 + (threadIdx.x >> 6);
    if (node >= n) return;
    int lane = threadIdx.x & 63;
    int head = lane >> 4;
    int lo = rowptr[node], hi = rowptr[node + 1];

    float m   = msbuf[(size_t)node * 8 + head];
    float inv = 1.f / (msbuf[(size_t)node * 8 + 4 + head] + 1e-16f);

    float a0 = 0.f, a1 = 0.f, a2 = 0.f, a3 = 0.f;
    for (int i = lo; i < hi; ++i) {
        int sn = esrc[i];
        float e = __expf(alpha[(size_t)i * 4 + head] - m) * inv;
        ushort4 vu = ((const ushort4*)(v + (size_t)sn * rs))[lane];
        a0 = fmaf(e, bfu(vu.x), a0);
        a1 = fmaf(e, bfu(vu.y), a1);
        a2 = fmaf(e, bfu(vu.z), a2);
        a3 = fmaf(e, bfu(vu.w), a3);
    }
    ushort4 o;
    o.x = f2bu(fmaxf(a0, 0.f));
    o.y = f2bu(fmaxf(a1, 0.f));
    o.z = f2bu(fmaxf(a2, 0.f));
    o.w = f2bu(fmaxf(a3, 0.f));
    ((ushort4*)(out + (size_t)node * OUT_C))[lane] = o;
}

// ---------- per-channel BN stats ----------
template<typename TX>
__global__ __launch_bounds__(256)
void col_stats_kernel(const TX* __restrict__ x, float* __restrict__ bnsum,
                      float* __restrict__ bnsumsq, int M)
{
    const int c = threadIdx.x;
    const int r0 = blockIdx.x * 64;
    const int r1 = min(r0 + 64, M);
    float ls = 0.f, lq = 0.f;
    for (int r = r0; r < r1; ++r) {
        float val = ldf(&x[(size_t)r * OUT_C + c]);
        ls += val;
        lq += val * val;
    }
    atomicAdd(&bnsum[c], ls);
    atomicAdd(&bnsumsq[c], lq);
}

// ---------- BN apply ----------
template<typename TX, typename TO>
__global__ __launch_bounds__(256)
void bn_apply_kernel(const TX* __restrict__ x, const float* __restrict__ bnsum,
                     const float* __restrict__ bnsumsq, const float* __restrict__ g,
                     const float* __restrict__ be, const bf16* __restrict__ add,
                     TO* __restrict__ y, float invM, size_t total)
{
    size_t idx = (size_t)blockIdx.x * blockDim.x + threadIdx.x;
    if (idx >= total) return;
    int c = (int)(idx & 255);
    float mu  = bnsum[c] * invM;
    float var = bnsumsq[c] * invM - mu * mu;
    float val = (ldf(&x[idx]) - mu) * rsqrtf(var + 1e-5f) * g[c] + be[c];
    if (add) val += ldf(&add[idx]);
    stf(&y[idx], val);
}

// ---------- pooling ----------
__global__ __launch_bounds__(256)
void pool_kernel(const bf16* __restrict__ h, const int* __restrict__ ibatch,
                 float* __restrict__ out)
{
    int g = blockIdx.x;
    __shared__ int bounds[2];
    if (threadIdx.x == 0) {
        int lo = 0, hi = N_NODES;
        while (lo < hi) { int mid = (lo + hi) >> 1; if (ibatch[mid] < g) lo = mid + 1; else hi = mid; }
        bounds[0] = lo;
        int lo2 = lo, hi2 = N_NODES;
        while (lo2 < hi2) { int mid = (lo2 + hi2) >> 1; if (ibatch[mid] < g + 1) lo2 = mid + 1; else hi2 = mid; }
        bounds[1] = lo2;
    }
    __syncthreads();
    int lo = bounds[0], hi = bounds[1];
    int c = threadIdx.x;
    float s = 0.f;
    for (int r = lo; r < hi; ++r) s += ldf(&h[(size_t)r * OUT_C + c]);
    out[(size_t)g * OUT_C + c] = s / fmaxf((float)(hi - lo), 1.f);
}

extern "C" void kernel_launch(void* const* d_in, const int* in_sizes, int n_in,
                              void* d_out, int out_size, void* d_ws, size_t ws_size,
                              hipStream_t stream)
{
    const float* drug_x  = (const float*)d_in[0];
    const int*   adj     = (const int*)  d_in[1];
    const int*   ibatch  = (const int*)  d_in[2];
    const float* cline_x = (const float*)d_in[3];
    const float* Wq1 = (const float*)d_in[4];  const float* bq1 = (const float*)d_in[5];
    const float* Wk1 = (const float*)d_in[6];  const float* bk1 = (const float*)d_in[7];
    const float* Wv1 = (const float*)d_in[8];  const float* bv1 = (const float*)d_in[9];
    const float* g1  = (const float*)d_in[10]; const float* be1 = (const float*)d_in[11];
    const float* Wq2 = (const float*)d_in[12]; const float* bq2 = (const float*)d_in[13];
    const float* Wk2 = (const float*)d_in[14]; const float* bk2 = (const float*)d_in[15];
    const float* Wv2 = (const float*)d_in[16]; const float* bv2 = (const float*)d_in[17];
    const float* g2  = (const float*)d_in[18]; const float* be2 = (const float*)d_in[19];
    const float* Wc1 = (const float*)d_in[20]; const float* bc1 = (const float*)d_in[21];
    const float* gc  = (const float*)d_in[22]; const float* bec = (const float*)d_in[23];
    const float* Wc2 = (const float*)d_in[24]; const float* bc2 = (const float*)d_in[25];

    const int* srcp = adj;
    const int* dstp = adj + N_EDGES;

    // ---- workspace arena (~222 MB) ----
    char* p = (char*)d_ws;
    auto take = [&p](size_t bytes) {
        char* r = p;
        p += (bytes + 15) & ~(size_t)15;
        return r;
    };
    bf16*  qk    = (bf16*)take((size_t)N_NODES * 512 * sizeof(bf16)); // q|k, then v in q half
    bf16*  conv  = (bf16*)take((size_t)N_NODES * OUT_C * sizeof(bf16));
    bf16*  h1    = (bf16*)take((size_t)N_NODES * OUT_C * sizeof(bf16));
    float* alpha = (float*)take((size_t)N_EDGES * 4 * sizeof(float));
    float* msbuf = (float*)take((size_t)N_NODES * 8 * sizeof(float));
    int*   rowptr= (int*)take((size_t)(N_NODES + 1) * sizeof(int));
    int*   degcur= (int*)take((size_t)N_NODES * sizeof(int));
    int*   bsum  = (int*)take(256 * sizeof(int));
    int*   bsume = (int*)take(256 * sizeof(int));
    int*   esrc  = (int*)take((size_t)N_EDGES * sizeof(int));
    float* bnsum = (float*)take(256 * sizeof(float));
    float* bnsumsq=(float*)take(256 * sizeof(float));
    bf16*  Wt1qk = (bf16*)take((size_t)512 * 128 * sizeof(bf16));
    bf16*  Wt1v  = (bf16*)take((size_t)256 * 128 * sizeof(bf16));
    bf16*  Wt2qk = (bf16*)take((size_t)512 * 256 * sizeof(bf16));
    bf16*  Wt2v  = (bf16*)take((size_t)256 * 256 * sizeof(bf16));
    bf16*  Wtc1  = (bf16*)take((size_t)256 * 960 * sizeof(bf16));
    bf16*  Wtc2  = (bf16*)take((size_t)256 * 256 * sizeof(bf16));
    float* bias_qk1 = (float*)take(512 * sizeof(float));
    float* bias_qk2 = (float*)take(512 * sizeof(float));
    float* c1    = (float*)take((size_t)B_CL * OUT_C * sizeof(float));
    bf16*  cbn   = (bf16*)take((size_t)B_CL * OUT_C * sizeof(bf16));
    size_t needed = (size_t)(p - (char*)d_ws);
    if (ws_size < needed) return;

    float* out_pool = (float*)d_out;                      // [G,256]
    float* out_c    = out_pool + (size_t)N_GRAPH * OUT_C; // [B,256]

    const int MT = (N_NODES + 127) / 128;   // 782
    dim3 gN_qk(MT, 4), gN_v(MT, 2);
    dim3 gB(16, 2);
    const int nodeBlocks = (N_NODES + 3) / 4;
    const size_t nTot = (size_t)N_NODES * OUT_C;

    // ===================== weight prep =====================
    convert_wt_kernel<<<256, 256, 0, stream>>>(Wq1, Wt1qk, DRUG_DIM, 256, 0,   128);
    convert_wt_kernel<<<256, 256, 0, stream>>>(Wk1, Wt1qk, DRUG_DIM, 256, 256, 128);
    convert_wt_kernel<<<256, 256, 0, stream>>>(Wv1, Wt1v,  DRUG_DIM, 256, 0,   128);
    convert_wt_kernel<<<256, 256, 0, stream>>>(Wq2, Wt2qk, 256, 256, 0,   256);
    convert_wt_kernel<<<256, 256, 0, stream>>>(Wk2, Wt2qk, 256, 256, 256, 256);
    convert_wt_kernel<<<256, 256, 0, stream>>>(Wv2, Wt2v,  256, 256, 0,   256);
    convert_wt_kernel<<<256, 256, 0, stream>>>(Wc1, Wtc1,  CLINE_DIM, 256, 0, 960);
    convert_wt_kernel<<<256, 256, 0, stream>>>(Wc2, Wtc2,  256, 256, 0, 256);
    concat_bias_kernel<<<2, 256, 0, stream>>>(bq1, bk1, bias_qk1);
    concat_bias_kernel<<<2, 256, 0, stream>>>(bq2, bk2, bias_qk2);

    // ===================== CSR build =====================
    hipMemsetAsync(degcur, 0, N_NODES * sizeof(int), stream);
    hist_kernel<<<(N_EDGES + 255) / 256, 256, 0, stream>>>(dstp, degcur, N_EDGES);
    const int NB1 = (N_NODES + 1023) / 1024;
    scan1_kernel<<<NB1, 256, 0, stream>>>(degcur, rowptr, bsum, N_NODES);
    scan2_kernel<<<1, 256, 0, stream>>>(bsum, bsume, NB1);
    scan3_kernel<<<(N_NODES + 255) / 256, 256, 0, stream>>>(rowptr, degcur, bsume, N_NODES, N_EDGES);
    scatter_kernel<<<(N_EDGES + 255) / 256, 256, 0, stream>>>(srcp, dstp, degcur, esrc, N_EDGES);

    // ===================== drug layer 1 =====================
    mfma_gemm_kernel<0, float, bf16><<<gN_qk, 256, 0, stream>>>(
        drug_x, Wt1qk, bias_qk1, nullptr, qk, N_NODES, DRUG_DIM, 128, 512);
    attn_logits_kernel<<<nodeBlocks, 256, 0, stream>>>(rowptr, esrc, qk, qk + 256, 512, alpha, msbuf, N_NODES);
    mfma_gemm_kernel<0, float, bf16><<<gN_v, 256, 0, stream>>>(
        drug_x, Wt1v, bv1, nullptr, qk, N_NODES, DRUG_DIM, 128, 512);   // v into dead q half
    attn_aggr_kernel<<<nodeBlocks, 256, 0, stream>>>(rowptr, esrc, qk, 512, alpha, msbuf, conv, N_NODES);
    hipMemsetAsync(bnsum, 0, 512 * sizeof(float), stream);
    col_stats_kernel<bf16><<<(N_NODES + 63) / 64, 256, 0, stream>>>(conv, bnsum, bnsumsq, N_NODES);
    bn_apply_kernel<bf16, bf16><<<(nTot + 255) / 256, 256, 0, stream>>>(
        conv, bnsum, bnsumsq, g1, be1, nullptr, h1, 1.0f / N_NODES, nTot);

    // ===================== drug layer 2 =====================
    mfma_gemm_kernel<0, bf16, bf16><<<gN_qk, 256, 0, stream>>>(
        h1, Wt2qk, bias_qk2, nullptr, qk, N_NODES, 256, 256, 512);
    attn_logits_kernel<<<nodeBlocks, 256, 0, stream>>>(rowptr, esrc, qk, qk + 256, 512, alpha, msbuf, N_NODES);
    mfma_gemm_kernel<0, bf16, bf16><<<gN_v, 256, 0, stream>>>(
        h1, Wt2v, bv2, nullptr, qk, N_NODES, 256, 256, 512);
    attn_aggr_kernel<<<nodeBlocks, 256, 0, stream>>>(rowptr, esrc, qk, 512, alpha, msbuf, conv, N_NODES);
    hipMemsetAsync(bnsum, 0, 512 * sizeof(float), stream);
    col_stats_kernel<bf16><<<(N_NODES + 63) / 64, 256, 0, stream>>>(conv, bnsum, bnsumsq, N_NODES);
    bn_apply_kernel<bf16, bf16><<<(nTot + 255) / 256, 256, 0, stream>>>(
        conv, bnsum, bnsumsq, g2, be2, h1, conv, 1.0f / N_NODES, nTot);

    // ===================== pooling =====================
    pool_kernel<<<N_GRAPH, 256, 0, stream>>>(conv, ibatch, out_pool);

    // ===================== cline branch =====================
    mfma_gemm_kernel<1, float, float><<<gB, 256, 0, stream>>>(
        cline_x, Wtc1, bc1, nullptr, c1, B_CL, CLINE_DIM, 960, 256);
    hipMemsetAsync(bnsum, 0, 512 * sizeof(float), stream);
    col_stats_kernel<float><<<(B_CL + 63) / 64, 256, 0, stream>>>(c1, bnsum, bnsumsq, B_CL);
    bn_apply_kernel<float, bf16><<<((size_t)B_CL * OUT_C + 255) / 256, 256, 0, stream>>>(
        c1, bnsum, bnsumsq, gc, bec, nullptr, cbn, 1.0f / B_CL, (size_t)B_CL * OUT_C);
    mfma_gemm_kernel<2, bf16, float><<<gB, 256, 0, stream>>>(
        cbn, Wtc2, bc2, c1, out_c, B_CL, 256, 256, 256);
}

// Round 5
// 964.905 us; speedup vs baseline: 2.7252x; 1.2938x over previous
//
#include <hip/hip_runtime.h>
#include <hip/hip_bf16.h>

// Problem constants (match reference)
static constexpr int N_NODES  = 100000;
static constexpr int N_EDGES  = 400000;
static constexpr int DRUG_DIM = 75;
static constexpr int OUT_C    = 256;   // OUT
static constexpr int N_GRAPH  = 2048;  // G
static constexpr int B_CL     = 2048;  // B
static constexpr int CLINE_DIM= 954;

using bf16 = __hip_bfloat16;
using short8 = __attribute__((ext_vector_type(8))) short;
using f32x4  = __attribute__((ext_vector_type(4))) float;

// ---------- load/store helpers ----------
__device__ __forceinline__ float ldf(const float* p) { return *p; }
__device__ __forceinline__ float ldf(const bf16* p)  { return __bfloat162float(*p); }
__device__ __forceinline__ void  stf(float* p, float v) { *p = v; }
__device__ __forceinline__ void  stf(bf16* p, float v)  { *p = __float2bfloat16(v); }
__device__ __forceinline__ float bfu(unsigned short u) { return __uint_as_float(((unsigned)u) << 16); }
__device__ __forceinline__ unsigned short f2bu(float f) {
    bf16 h = __float2bfloat16(f);
    return *reinterpret_cast<unsigned short*>(&h);
}

// ================= input/weight prep =================
// A: [M,K] fp32 -> Ab: [M,Kpad] bf16, zero-padded k>=K
__global__ __launch_bounds__(256)
void convert_a_kernel(const float* __restrict__ A, bf16* __restrict__ Ab,
                      int K, int Kpad, int total)
{
    int idx = blockIdx.x * 256 + threadIdx.x;
    if (idx >= total) return;
    int r = idx / Kpad, k = idx - r * Kpad;
    float f = (k < K) ? A[(size_t)r * K + k] : 0.f;
    Ab[idx] = __float2bfloat16(f);
}

// W: [K, NW] fp32 -> Wt rows [n0, n0+NW), each row length Kpad bf16, zero-padded
__global__ __launch_bounds__(256)
void convert_wt_kernel(const float* __restrict__ W, bf16* __restrict__ Wt,
                       int K, int NW, int n0, int Kpad)
{
    int n = blockIdx.x;
    for (int k = threadIdx.x; k < Kpad; k += 256) {
        float f = (k < K) ? W[(size_t)k * NW + n] : 0.f;
        Wt[(size_t)(n0 + n) * Kpad + k] = __float2bfloat16(f);
    }
}

__global__ __launch_bounds__(256)
void concat_bias_kernel(const float* __restrict__ a, const float* __restrict__ b,
                        float* __restrict__ out)
{
    int i = blockIdx.x * 256 + threadIdx.x;
    if (i < 512) out[i] = (i < 256) ? a[i] : b[i - 256];
}

// ================= MFMA GEMM =================
// C[M x *] = act(A[M x K] @ Wt^T + bias) (+res). A: bf16 [M][K] (K mult of 64),
// Wt: [NCOLS][K] bf16 (B^T). C row stride NC. Tile 128x128, BK=64, 4 waves (2x2).
// LDS XOR swizzle: element_off ^= (row&7)<<3.
template<int ACT, typename TO>
__global__ __launch_bounds__(256)
void mfma_gemm_kernel(const bf16* __restrict__ A, const bf16* __restrict__ Wt,
                      const float* __restrict__ bias, const float* __restrict__ res,
                      TO* __restrict__ C, int M, int K, int NC)
{
    __shared__ short As[128 * 64];
    __shared__ short Bs[128 * 64];
    const int mtile = blockIdx.x, ntile = blockIdx.y;
    const int tid = threadIdx.x;
    const int lane = tid & 63, wid = tid >> 6;
    const int wr = wid >> 1, wc = wid & 1;

    const int srow = tid >> 1, sseg = tid & 1;   // staging: 2 threads per row
    const int gr = mtile * 128 + srow;
    const int swz = (srow & 7) << 3;
    const unsigned short* arow = (const unsigned short*)(A + (size_t)gr * K);
    const unsigned short* wrow =
        (const unsigned short*)(Wt + (size_t)(ntile * 128 + srow) * K);

    f32x4 acc[4][4] = {};

    for (int k0 = 0; k0 < K; k0 += 64) {
        #pragma unroll
        for (int c = 0; c < 4; ++c) {
            int kloc = sseg * 32 + c * 8;
            short8 av{};
            if (gr < M)
                av = *reinterpret_cast<const short8*>(&arow[k0 + kloc]);
            *reinterpret_cast<short8*>(&As[srow * 64 + (kloc ^ swz)]) = av;
            *reinterpret_cast<short8*>(&Bs[srow * 64 + (kloc ^ swz)]) =
                *reinterpret_cast<const short8*>(&wrow[k0 + kloc]);
        }
        __syncthreads();
        #pragma unroll
        for (int kk = 0; kk < 2; ++kk) {
            const int coff = (kk * 32 + (lane >> 4) * 8) ^ ((lane & 7) << 3);
            short8 a[4], b[4];
            #pragma unroll
            for (int m = 0; m < 4; ++m)
                a[m] = *reinterpret_cast<const short8*>(
                    &As[(wr * 64 + m * 16 + (lane & 15)) * 64 + coff]);
            #pragma unroll
            for (int n = 0; n < 4; ++n)
                b[n] = *reinterpret_cast<const short8*>(
                    &Bs[(wc * 64 + n * 16 + (lane & 15)) * 64 + coff]);
            #pragma unroll
            for (int m = 0; m < 4; ++m)
                #pragma unroll
                for (int n = 0; n < 4; ++n)
                    acc[m][n] = __builtin_amdgcn_mfma_f32_16x16x32_bf16(
                        a[m], b[n], acc[m][n], 0, 0, 0);
        }
        __syncthreads();
    }

    // epilogue: C/D layout col=lane&15, row=(lane>>4)*4+reg
    #pragma unroll
    for (int m = 0; m < 4; ++m) {
        int row0 = mtile * 128 + wr * 64 + m * 16 + ((lane >> 4) << 2);
        #pragma unroll
        for (int n = 0; n < 4; ++n) {
            int col = ntile * 128 + wc * 64 + n * 16 + (lane & 15);
            float bcol = bias[col];
            #pragma unroll
            for (int r = 0; r < 4; ++r) {
                int row = row0 + r;
                if (row < M) {
                    float val = acc[m][n][r] + bcol;
                    if (ACT == 1) val = tanhf(val);
                    if (ACT == 2) val = fmaxf(val, 0.f);
                    if (res) val += res[(size_t)row * NC + col];
                    stf(&C[(size_t)row * NC + col], val);
                }
            }
        }
    }
}

// ================= CSR build =================
__global__ __launch_bounds__(256)
void hist_kernel(const int* __restrict__ dst, int* __restrict__ deg, int E)
{
    int e = blockIdx.x * 256 + threadIdx.x;
    if (e < E) atomicAdd(&deg[dst[e]], 1);
}

__global__ __launch_bounds__(256)
void scan1_kernel(const int* __restrict__ deg, int* __restrict__ part,
                  int* __restrict__ bsum, int n)
{
    __shared__ int sh[256];
    const int t = threadIdx.x;
    const int b0 = blockIdx.x * 1024;
    int v[4]; int s = 0;
    #pragma unroll
    for (int j = 0; j < 4; ++j) {
        int idx = b0 + t * 4 + j;
        v[j] = (idx < n) ? deg[idx] : 0;
        s += v[j];
    }
    sh[t] = s; __syncthreads();
    for (int off = 1; off < 256; off <<= 1) {
        int x = (t >= off) ? sh[t - off] : 0;
        __syncthreads();
        sh[t] += x;
        __syncthreads();
    }
    if (t == 255) bsum[blockIdx.x] = sh[255];
    int run = sh[t] - s;
    #pragma unroll
    for (int j = 0; j < 4; ++j) {
        int idx = b0 + t * 4 + j;
        if (idx < n) part[idx] = run;
        run += v[j];
    }
}

__global__ __launch_bounds__(256)
void scan2_kernel(const int* __restrict__ bsum, int* __restrict__ bsume, int nb)
{
    __shared__ int sh[256];
    const int t = threadIdx.x;
    int x0 = (t < nb) ? bsum[t] : 0;
    sh[t] = x0; __syncthreads();
    for (int off = 1; off < 256; off <<= 1) {
        int x = (t >= off) ? sh[t - off] : 0;
        __syncthreads();
        sh[t] += x;
        __syncthreads();
    }
    if (t < nb) bsume[t] = sh[t] - x0;
}

__global__ __launch_bounds__(256)
void scan3_kernel(int* __restrict__ rowptr, int* __restrict__ cursor,
                  const int* __restrict__ bsume, int n, int E)
{
    int idx = blockIdx.x * 256 + threadIdx.x;
    if (idx < n) {
        int val = rowptr[idx] + bsume[idx >> 10];
        rowptr[idx] = val;
        cursor[idx] = val;
    }
    if (idx == 0) rowptr[n] = E;
}

__global__ __launch_bounds__(256)
void scatter_kernel(const int* __restrict__ src, const int* __restrict__ dst,
                    int* __restrict__ cursor, int* __restrict__ esrc, int E)
{
    int e = blockIdx.x * 256 + threadIdx.x;
    if (e < E) {
        int slot = atomicAdd(&cursor[dst[e]], 1);
        esrc[slot] = src[e];
    }
}

// ================= fused attention (CSR gather) =================
__global__ __launch_bounds__(256)
void attn_logits_kernel(const int* __restrict__ rowptr, const int* __restrict__ esrc,
                        const bf16* __restrict__ q, const bf16* __restrict__ k, int rs,
                        float* __restrict__ alpha, float* __restrict__ msbuf, int n)
{
    int node = blockIdx.x * 4 + (threadIdx.x >> 6);
    if (node >= n) return;
    int lane = threadIdx.x & 63;
    int head = lane >> 4;
    int lo = rowptr[node], hi = rowptr[node + 1];

    ushort4 qu = ((const ushort4*)(q + (size_t)node * rs))[lane];
    float q0 = bfu(qu.x), q1 = bfu(qu.y), q2 = bfu(qu.z), q3 = bfu(qu.w);

    float m = -INFINITY, s = 0.f;
    for (int i = lo; i < hi; ++i) {
        int sn = esrc[i];
        ushort4 ku = ((const ushort4*)(k + (size_t)sn * rs))[lane];
        float p = q0 * bfu(ku.x);
        p = fmaf(q1, bfu(ku.y), p);
        p = fmaf(q2, bfu(ku.z), p);
        p = fmaf(q3, bfu(ku.w), p);
        p += __shfl_xor(p, 1);
        p += __shfl_xor(p, 2);
        p += __shfl_xor(p, 4);
        p += __shfl_xor(p, 8);
        float l = p * 0.125f;        // 1/sqrt(64)
        if ((lane & 15) == 0) alpha[(size_t)i * 4 + head] = l;
        float mn = fmaxf(m, l);
        s = s * __expf(m - mn) + __expf(l - mn);
        m = mn;
    }
    if ((lane & 15) == 0) {
        msbuf[(size_t)node * 8 + head]     = m;
        msbuf[(size_t)node * 8 + 4 + head] = s;
    }
}

__global__ __launch_bounds__(256)
void attn_aggr_kernel(const int* __restrict__ rowptr, const int* __restrict__ esrc,
                      const bf16* __restrict__ v, int rs, const float* __restrict__ alpha,
                      const float* __restrict__ msbuf, bf16* __restrict__ out, int n)
{
    int node = blockIdx.x * 4 + (threadIdx.x >> 6);
    if (node >= n) return;
    int lane = threadIdx.x & 63;
    int head = lane >> 4;
    int lo = rowptr[node], hi = rowptr[node + 1];

    float m   = msbuf[(size_t)node * 8 + head];
    float inv = 1.f / (msbuf[(size_t)node * 8 + 4 + head] + 1e-16f);

    float a0 = 0.f, a1 = 0.f, a2 = 0.f, a3 = 0.f;
    for (int i = lo; i < hi; ++i) {
        int sn = esrc[i];
        float e = __expf(alpha[(size_t)i * 4 + head] - m) * inv;
        ushort4 vu = ((const ushort4*)(v + (size_t)sn * rs))[lane];
        a0 = fmaf(e, bfu(vu.x), a0);
        a1 = fmaf(e, bfu(vu.y), a1);
        a2 = fmaf(e, bfu(vu.z), a2);
        a3 = fmaf(e, bfu(vu.w), a3);
    }
    ushort4 o;
    o.x = f2bu(fmaxf(a0, 0.f));
    o.y = f2bu(fmaxf(a1, 0.f));
    o.z = f2bu(fmaxf(a2, 0.f));
    o.w = f2bu(fmaxf(a3, 0.f));
    ((ushort4*)(out + (size_t)node * OUT_C))[lane] = o;
}

// ---------- per-channel BN stats ----------
template<typename TX>
__global__ __launch_bounds__(256)
void col_stats_kernel(const TX* __restrict__ x, float* __restrict__ bnsum,
                      float* __restrict__ bnsumsq, int M)
{
    const int c = threadIdx.x;
    const int r0 = blockIdx.x * 64;
    const int r1 = min(r0 + 64, M);
    float ls = 0.f, lq = 0.f;
    for (int r = r0; r < r1; ++r) {
        float val = ldf(&x[(size_t)r * OUT_C + c]);
        ls += val;
        lq += val * val;
    }
    atomicAdd(&bnsum[c], ls);
    atomicAdd(&bnsumsq[c], lq);
}

// ---------- BN apply ----------
template<typename TX, typename TO>
__global__ __launch_bounds__(256)
void bn_apply_kernel(const TX* __restrict__ x, const float* __restrict__ bnsum,
                     const float* __restrict__ bnsumsq, const float* __restrict__ g,
                     const float* __restrict__ be, const bf16* __restrict__ add,
                     TO* __restrict__ y, float invM, size_t total)
{
    size_t idx = (size_t)blockIdx.x * blockDim.x + threadIdx.x;
    if (idx >= total) return;
    int c = (int)(idx & 255);
    float mu  = bnsum[c] * invM;
    float var = bnsumsq[c] * invM - mu * mu;
    float val = (ldf(&x[idx]) - mu) * rsqrtf(var + 1e-5f) * g[c] + be[c];
    if (add) val += ldf(&add[idx]);
    stf(&y[idx], val);
}

// ---------- pooling ----------
__global__ __launch_bounds__(256)
void pool_kernel(const bf16* __restrict__ h, const int* __restrict__ ibatch,
                 float* __restrict__ out)
{
    int g = blockIdx.x;
    __shared__ int bounds[2];
    if (threadIdx.x == 0) {
        int lo = 0, hi = N_NODES;
        while (lo < hi) { int mid = (lo + hi) >> 1; if (ibatch[mid] < g) lo = mid + 1; else hi = mid; }
        bounds[0] = lo;
        int lo2 = lo, hi2 = N_NODES;
        while (lo2 < hi2) { int mid = (lo2 + hi2) >> 1; if (ibatch[mid] < g + 1) lo2 = mid + 1; else hi2 = mid; }
        bounds[1] = lo2;
    }
    __syncthreads();
    int lo = bounds[0], hi = bounds[1];
    int c = threadIdx.x;
    float s = 0.f;
    for (int r = lo; r < hi; ++r) s += ldf(&h[(size_t)r * OUT_C + c]);
    out[(size_t)g * OUT_C + c] = s / fmaxf((float)(hi - lo), 1.f);
}

extern "C" void kernel_launch(void* const* d_in, const int* in_sizes, int n_in,
                              void* d_out, int out_size, void* d_ws, size_t ws_size,
                              hipStream_t stream)
{
    const float* drug_x  = (const float*)d_in[0];
    const int*   adj     = (const int*)  d_in[1];
    const int*   ibatch  = (const int*)  d_in[2];
    const float* cline_x = (const float*)d_in[3];
    const float* Wq1 = (const float*)d_in[4];  const float* bq1 = (const float*)d_in[5];
    const float* Wk1 = (const float*)d_in[6];  const float* bk1 = (const float*)d_in[7];
    const float* Wv1 = (const float*)d_in[8];  const float* bv1 = (const float*)d_in[9];
    const float* g1  = (const float*)d_in[10]; const float* be1 = (const float*)d_in[11];
    const float* Wq2 = (const float*)d_in[12]; const float* bq2 = (const float*)d_in[13];
    const float* Wk2 = (const float*)d_in[14]; const float* bk2 = (const float*)d_in[15];
    const float* Wv2 = (const float*)d_in[16]; const float* bv2 = (const float*)d_in[17];
    const float* g2  = (const float*)d_in[18]; const float* be2 = (const float*)d_in[19];
    const float* Wc1 = (const float*)d_in[20]; const float* bc1 = (const float*)d_in[21];
    const float* gc  = (const float*)d_in[22]; const float* bec = (const float*)d_in[23];
    const float* Wc2 = (const float*)d_in[24]; const float* bc2 = (const float*)d_in[25];

    const int* srcp = adj;
    const int* dstp = adj + N_EDGES;

    // ---- workspace arena (~223 MB) ----
    char* p = (char*)d_ws;
    auto take = [&p](size_t bytes) {
        char* r = p;
        p += (bytes + 15) & ~(size_t)15;
        return r;
    };
    bf16*  qk    = (bf16*)take((size_t)N_NODES * 512 * sizeof(bf16)); // q|k, then v; later cline bufs
    bf16*  conv  = (bf16*)take((size_t)N_NODES * OUT_C * sizeof(bf16));
    bf16*  h1    = (bf16*)take((size_t)N_NODES * OUT_C * sizeof(bf16)); // also drug_xb early
    float* alpha = (float*)take((size_t)N_EDGES * 4 * sizeof(float));
    float* msbuf = (float*)take((size_t)N_NODES * 8 * sizeof(float));
    int*   rowptr= (int*)take((size_t)(N_NODES + 1) * sizeof(int));
    int*   degcur= (int*)take((size_t)N_NODES * sizeof(int));
    int*   bsum  = (int*)take(256 * sizeof(int));
    int*   bsume = (int*)take(256 * sizeof(int));
    int*   esrc  = (int*)take((size_t)N_EDGES * sizeof(int));
    float* bnsum = (float*)take(256 * sizeof(float));
    float* bnsumsq=(float*)take(256 * sizeof(float));
    bf16*  Wt1qk = (bf16*)take((size_t)512 * 128 * sizeof(bf16));
    bf16*  Wt1v  = (bf16*)take((size_t)256 * 128 * sizeof(bf16));
    bf16*  Wt2qk = (bf16*)take((size_t)512 * 256 * sizeof(bf16));
    bf16*  Wt2v  = (bf16*)take((size_t)256 * 256 * sizeof(bf16));
    bf16*  Wtc1  = (bf16*)take((size_t)256 * 960 * sizeof(bf16));
    bf16*  Wtc2  = (bf16*)take((size_t)256 * 256 * sizeof(bf16));
    float* bias_qk1 = (float*)take(512 * sizeof(float));
    float* bias_qk2 = (float*)take(512 * sizeof(float));
    size_t needed = (size_t)(p - (char*)d_ws);
    if (ws_size < needed) return;

    // aliases (lifetime-disjoint):
    bf16* drug_xb = h1;                       // [N,128] bf16, dead before h1 written
    bf16* cline_xb = qk;                      // [2048,960] bf16, after qk dead
    float* c1  = (float*)(qk + (size_t)2048 * 960);          // 2 MB
    bf16*  cbn = (bf16*)(c1 + (size_t)B_CL * OUT_C);         // 1 MB

    float* out_pool = (float*)d_out;                      // [G,256]
    float* out_c    = out_pool + (size_t)N_GRAPH * OUT_C; // [B,256]

    const int MT = (N_NODES + 127) / 128;   // 782
    dim3 gN_qk(MT, 4), gN_v(MT, 2);
    dim3 gB(16, 2);
    const int nodeBlocks = (N_NODES + 3) / 4;
    const size_t nTot = (size_t)N_NODES * OUT_C;

    // ===================== prep =====================
    convert_a_kernel<<<(N_NODES * 128 + 255) / 256, 256, 0, stream>>>(
        drug_x, drug_xb, DRUG_DIM, 128, N_NODES * 128);
    convert_wt_kernel<<<256, 256, 0, stream>>>(Wq1, Wt1qk, DRUG_DIM, 256, 0,   128);
    convert_wt_kernel<<<256, 256, 0, stream>>>(Wk1, Wt1qk, DRUG_DIM, 256, 256, 128);
    convert_wt_kernel<<<256, 256, 0, stream>>>(Wv1, Wt1v,  DRUG_DIM, 256, 0,   128);
    convert_wt_kernel<<<256, 256, 0, stream>>>(Wq2, Wt2qk, 256, 256, 0,   256);
    convert_wt_kernel<<<256, 256, 0, stream>>>(Wk2, Wt2qk, 256, 256, 256, 256);
    convert_wt_kernel<<<256, 256, 0, stream>>>(Wv2, Wt2v,  256, 256, 0,   256);
    convert_wt_kernel<<<256, 256, 0, stream>>>(Wc1, Wtc1,  CLINE_DIM, 256, 0, 960);
    convert_wt_kernel<<<256, 256, 0, stream>>>(Wc2, Wtc2,  256, 256, 0, 256);
    concat_bias_kernel<<<2, 256, 0, stream>>>(bq1, bk1, bias_qk1);
    concat_bias_kernel<<<2, 256, 0, stream>>>(bq2, bk2, bias_qk2);

    // ===================== CSR build =====================
    hipMemsetAsync(degcur, 0, N_NODES * sizeof(int), stream);
    hist_kernel<<<(N_EDGES + 255) / 256, 256, 0, stream>>>(dstp, degcur, N_EDGES);
    const int NB1 = (N_NODES + 1023) / 1024;
    scan1_kernel<<<NB1, 256, 0, stream>>>(degcur, rowptr, bsum, N_NODES);
    scan2_kernel<<<1, 256, 0, stream>>>(bsum, bsume, NB1);
    scan3_kernel<<<(N_NODES + 255) / 256, 256, 0, stream>>>(rowptr, degcur, bsume, N_NODES, N_EDGES);
    scatter_kernel<<<(N_EDGES + 255) / 256, 256, 0, stream>>>(srcp, dstp, degcur, esrc, N_EDGES);

    // ===================== drug layer 1 =====================
    mfma_gemm_kernel<0, bf16><<<gN_qk, 256, 0, stream>>>(
        drug_xb, Wt1qk, bias_qk1, nullptr, qk, N_NODES, 128, 512);
    attn_logits_kernel<<<nodeBlocks, 256, 0, stream>>>(rowptr, esrc, qk, qk + 256, 512, alpha, msbuf, N_NODES);
    mfma_gemm_kernel<0, bf16><<<gN_v, 256, 0, stream>>>(
        drug_xb, Wt1v, bv1, nullptr, qk, N_NODES, 128, 512);   // v into dead q half
    attn_aggr_kernel<<<nodeBlocks, 256, 0, stream>>>(rowptr, esrc, qk, 512, alpha, msbuf, conv, N_NODES);
    hipMemsetAsync(bnsum, 0, 512 * sizeof(float), stream);
    col_stats_kernel<bf16><<<(N_NODES + 63) / 64, 256, 0, stream>>>(conv, bnsum, bnsumsq, N_NODES);
    bn_apply_kernel<bf16, bf16><<<(nTot + 255) / 256, 256, 0, stream>>>(
        conv, bnsum, bnsumsq, g1, be1, nullptr, h1, 1.0f / N_NODES, nTot);

    // ===================== drug layer 2 =====================
    mfma_gemm_kernel<0, bf16><<<gN_qk, 256, 0, stream>>>(
        h1, Wt2qk, bias_qk2, nullptr, qk, N_NODES, 256, 512);
    attn_logits_kernel<<<nodeBlocks, 256, 0, stream>>>(rowptr, esrc, qk, qk + 256, 512, alpha, msbuf, N_NODES);
    mfma_gemm_kernel<0, bf16><<<gN_v, 256, 0, stream>>>(
        h1, Wt2v, bv2, nullptr, qk, N_NODES, 256, 512);
    attn_aggr_kernel<<<nodeBlocks, 256, 0, stream>>>(rowptr, esrc, qk, 512, alpha, msbuf, conv, N_NODES);
    hipMemsetAsync(bnsum, 0, 512 * sizeof(float), stream);
    col_stats_kernel<bf16><<<(N_NODES + 63) / 64, 256, 0, stream>>>(conv, bnsum, bnsumsq, N_NODES);
    bn_apply_kernel<bf16, bf16><<<(nTot + 255) / 256, 256, 0, stream>>>(
        conv, bnsum, bnsumsq, g2, be2, h1, conv, 1.0f / N_NODES, nTot);

    // ===================== pooling =====================
    pool_kernel<<<N_GRAPH, 256, 0, stream>>>(conv, ibatch, out_pool);

    // ===================== cline branch (qk region now dead) =====================
    convert_a_kernel<<<(B_CL * 960 + 255) / 256, 256, 0, stream>>>(
        cline_x, cline_xb, CLINE_DIM, 960, B_CL * 960);
    mfma_gemm_kernel<1, float><<<gB, 256, 0, stream>>>(
        cline_xb, Wtc1, bc1, nullptr, c1, B_CL, 960, 256);
    hipMemsetAsync(bnsum, 0, 512 * sizeof(float), stream);
    col_stats_kernel<float><<<(B_CL + 63) / 64, 256, 0, stream>>>(c1, bnsum, bnsumsq, B_CL);
    bn_apply_kernel<float, bf16><<<((size_t)B_CL * OUT_C + 255) / 256, 256, 0, stream>>>(
        c1, bnsum, bnsumsq, gc, bec, nullptr, cbn, 1.0f / B_CL, (size_t)B_CL * OUT_C);
    mfma_gemm_kernel<2, float><<<gB, 256, 0, stream>>>(
        cbn, Wtc2, bc2, c1, out_c, B_CL, 256, 256);
}

// Round 6
// 900.588 us; speedup vs baseline: 2.9199x; 1.0714x over previous
//
#include <hip/hip_runtime.h>
#include <hip/hip_bf16.h>

// Problem constants (match reference)
static constexpr int N_NODES  = 100000;
static constexpr int N_EDGES  = 400000;
static constexpr int DRUG_DIM = 75;
static constexpr int OUT_C    = 256;   // OUT
static constexpr int N_GRAPH  = 2048;  // G
static constexpr int B_CL     = 2048;  // B
static constexpr int CLINE_DIM= 954;

using bf16 = __hip_bfloat16;
using short8 = __attribute__((ext_vector_type(8))) short;
using f32x4  = __attribute__((ext_vector_type(4))) float;

// ---------- load/store helpers ----------
__device__ __forceinline__ float ldf(const float* p) { return *p; }
__device__ __forceinline__ float ldf(const bf16* p)  { return __bfloat162float(*p); }
__device__ __forceinline__ void  stf(float* p, float v) { *p = v; }
__device__ __forceinline__ void  stf(bf16* p, float v)  { *p = __float2bfloat16(v); }
__device__ __forceinline__ float bfu(unsigned short u) { return __uint_as_float(((unsigned)u) << 16); }
__device__ __forceinline__ unsigned short f2bu(float f) {
    bf16 h = __float2bfloat16(f);
    return *reinterpret_cast<unsigned short*>(&h);
}

// async global -> LDS, 16B per lane; LDS dest = uniform base + lane*16
__device__ __forceinline__ void gload_lds16(const void* g, void* l) {
    __builtin_amdgcn_global_load_lds(
        (const __attribute__((address_space(1))) void*)g,
        (__attribute__((address_space(3))) void*)l, 16, 0, 0);
}

// ================= input/weight prep =================
__global__ __launch_bounds__(256)
void convert_a_kernel(const float* __restrict__ A, bf16* __restrict__ Ab,
                      int K, int Kpad, int total)
{
    int idx = blockIdx.x * 256 + threadIdx.x;
    if (idx >= total) return;
    int r = idx / Kpad, k = idx - r * Kpad;
    float f = (k < K) ? A[(size_t)r * K + k] : 0.f;
    Ab[idx] = __float2bfloat16(f);
}

__global__ __launch_bounds__(256)
void convert_wt_kernel(const float* __restrict__ W, bf16* __restrict__ Wt,
                       int K, int NW, int n0, int Kpad)
{
    int n = blockIdx.x;
    for (int k = threadIdx.x; k < Kpad; k += 256) {
        float f = (k < K) ? W[(size_t)k * NW + n] : 0.f;
        Wt[(size_t)(n0 + n) * Kpad + k] = __float2bfloat16(f);
    }
}

__global__ __launch_bounds__(256)
void concat_bias_kernel(const float* __restrict__ a, const float* __restrict__ b,
                        float* __restrict__ out)
{
    int i = blockIdx.x * 256 + threadIdx.x;
    if (i < 512) out[i] = (i < 256) ? a[i] : b[i - 256];
}

// ================= MFMA GEMM (global_load_lds staging) =================
// C[M x *] = act(A[M x K] @ Wt^T + bias) (+res). A bf16 [M][K], K mult of 64,
// M mult of 8. Wt [NCOLS][K] bf16. Tile 128x128, BK=64, 4 waves (2x2).
// LDS relation: LDS[row][y] = data[row][y ^ ((row&7)<<3)], achieved by
// pre-swizzling the per-lane GLOBAL source element while LDS dest stays linear.
// blockIdx.x = ntile (siblings sharing an A-tile dispatch adjacently).
template<int ACT, typename TO>
__global__ __launch_bounds__(256)
void mfma_gemm_kernel(const bf16* __restrict__ A, const bf16* __restrict__ Wt,
                      const float* __restrict__ bias, const float* __restrict__ res,
                      TO* __restrict__ C, int M, int K, int NC)
{
    __shared__ alignas(16) short As[128 * 64];
    __shared__ alignas(16) short Bs[128 * 64];
    const int ntile = blockIdx.x, mtile = blockIdx.y;
    const int tid = threadIdx.x;
    const int lane = tid & 63, wid = tid >> 6;
    const int wr = wid >> 1, wc = wid & 1;

    f32x4 acc[4][4] = {};

    for (int k0 = 0; k0 < K; k0 += 64) {
        // ---- stage: 4 A-issues + 4 B-issues per wave, 8 rows per issue ----
        #pragma unroll
        for (int i = 0; i < 4; ++i) {
            const int chunk = i * 4 + wid;            // wave-uniform
            const int row   = chunk * 8 + (lane >> 3);
            const int e     = ((lane & 7) ^ (row & 7)) << 3;  // pre-swizzled src elem
            if (mtile * 128 + chunk * 8 + 8 <= M)     // wave-uniform guard (M % 8 == 0)
                gload_lds16(A + (size_t)(mtile * 128 + row) * K + k0 + e,
                            &As[chunk * 512]);
            gload_lds16(Wt + (size_t)(ntile * 128 + row) * K + k0 + e,
                        &Bs[chunk * 512]);
        }
        __syncthreads();   // drains vmcnt(0): LDS tiles ready
        #pragma unroll
        for (int kk = 0; kk < 2; ++kk) {
            const int coff = (kk * 32 + (lane >> 4) * 8) ^ ((lane & 7) << 3);
            short8 a[4], b[4];
            #pragma unroll
            for (int m = 0; m < 4; ++m)
                a[m] = *reinterpret_cast<const short8*>(
                    &As[(wr * 64 + m * 16 + (lane & 15)) * 64 + coff]);
            #pragma unroll
            for (int n = 0; n < 4; ++n)
                b[n] = *reinterpret_cast<const short8*>(
                    &Bs[(wc * 64 + n * 16 + (lane & 15)) * 64 + coff]);
            #pragma unroll
            for (int m = 0; m < 4; ++m)
                #pragma unroll
                for (int n = 0; n < 4; ++n)
                    acc[m][n] = __builtin_amdgcn_mfma_f32_16x16x32_bf16(
                        a[m], b[n], acc[m][n], 0, 0, 0);
        }
        __syncthreads();
    }

    // epilogue: C/D layout col=lane&15, row=(lane>>4)*4+reg
    #pragma unroll
    for (int m = 0; m < 4; ++m) {
        int row0 = mtile * 128 + wr * 64 + m * 16 + ((lane >> 4) << 2);
        #pragma unroll
        for (int n = 0; n < 4; ++n) {
            int col = ntile * 128 + wc * 64 + n * 16 + (lane & 15);
            float bcol = bias[col];
            #pragma unroll
            for (int r = 0; r < 4; ++r) {
                int row = row0 + r;
                if (row < M) {
                    float val = acc[m][n][r] + bcol;
                    if (ACT == 1) val = tanhf(val);
                    if (ACT == 2) val = fmaxf(val, 0.f);
                    if (res) val += res[(size_t)row * NC + col];
                    stf(&C[(size_t)row * NC + col], val);
                }
            }
        }
    }
}

// ================= CSR build =================
__global__ __launch_bounds__(256)
void hist_kernel(const int* __restrict__ dst, int* __restrict__ deg, int E)
{
    int e = blockIdx.x * 256 + threadIdx.x;
    if (e < E) atomicAdd(&deg[dst[e]], 1);
}

__global__ __launch_bounds__(256)
void scan1_kernel(const int* __restrict__ deg, int* __restrict__ part,
                  int* __restrict__ bsum, int n)
{
    __shared__ int sh[256];
    const int t = threadIdx.x;
    const int b0 = blockIdx.x * 1024;
    int v[4]; int s = 0;
    #pragma unroll
    for (int j = 0; j < 4; ++j) {
        int idx = b0 + t * 4 + j;
        v[j] = (idx < n) ? deg[idx] : 0;
        s += v[j];
    }
    sh[t] = s; __syncthreads();
    for (int off = 1; off < 256; off <<= 1) {
        int x = (t >= off) ? sh[t - off] : 0;
        __syncthreads();
        sh[t] += x;
        __syncthreads();
    }
    if (t == 255) bsum[blockIdx.x] = sh[255];
    int run = sh[t] - s;
    #pragma unroll
    for (int j = 0; j < 4; ++j) {
        int idx = b0 + t * 4 + j;
        if (idx < n) part[idx] = run;
        run += v[j];
    }
}

__global__ __launch_bounds__(256)
void scan2_kernel(const int* __restrict__ bsum, int* __restrict__ bsume, int nb)
{
    __shared__ int sh[256];
    const int t = threadIdx.x;
    int x0 = (t < nb) ? bsum[t] : 0;
    sh[t] = x0; __syncthreads();
    for (int off = 1; off < 256; off <<= 1) {
        int x = (t >= off) ? sh[t - off] : 0;
        __syncthreads();
        sh[t] += x;
        __syncthreads();
    }
    if (t < nb) bsume[t] = sh[t] - x0;
}

__global__ __launch_bounds__(256)
void scan3_kernel(int* __restrict__ rowptr, int* __restrict__ cursor,
                  const int* __restrict__ bsume, int n, int E)
{
    int idx = blockIdx.x * 256 + threadIdx.x;
    if (idx < n) {
        int val = rowptr[idx] + bsume[idx >> 10];
        rowptr[idx] = val;
        cursor[idx] = val;
    }
    if (idx == 0) rowptr[n] = E;
}

__global__ __launch_bounds__(256)
void scatter_kernel(const int* __restrict__ src, const int* __restrict__ dst,
                    int* __restrict__ cursor, int* __restrict__ esrc, int E)
{
    int e = blockIdx.x * 256 + threadIdx.x;
    if (e < E) {
        int slot = atomicAdd(&cursor[dst[e]], 1);
        esrc[slot] = src[e];
    }
}

// ================= fused attention (CSR gather) =================
__global__ __launch_bounds__(256)
void attn_logits_kernel(const int* __restrict__ rowptr, const int* __restrict__ esrc,
                        const bf16* __restrict__ q, const bf16* __restrict__ k, int rs,
                        float* __restrict__ alpha, float* __restrict__ msbuf, int n)
{
    int node = blockIdx.x * 4 + (threadIdx.x >> 6);
    if (node >= n) return;
    int lane = threadIdx.x & 63;
    int head = lane >> 4;
    int lo = rowptr[node], hi = rowptr[node + 1];

    ushort4 qu = ((const ushort4*)(q + (size_t)node * rs))[lane];
    float q0 = bfu(qu.x), q1 = bfu(qu.y), q2 = bfu(qu.z), q3 = bfu(qu.w);

    float m = -INFINITY, s = 0.f;
    for (int i = lo; i < hi; ++i) {
        int sn = esrc[i];
        ushort4 ku = ((const ushort4*)(k + (size_t)sn * rs))[lane];
        float p = q0 * bfu(ku.x);
        p = fmaf(q1, bfu(ku.y), p);
        p = fmaf(q2, bfu(ku.z), p);
        p = fmaf(q3, bfu(ku.w), p);
        p += __shfl_xor(p, 1);
        p += __shfl_xor(p, 2);
        p += __shfl_xor(p, 4);
        p += __shfl_xor(p, 8);
        float l = p * 0.125f;        // 1/sqrt(64)
        if ((lane & 15) == 0) alpha[(size_t)i * 4 + head] = l;
        float mn = fmaxf(m, l);
        s = s * __expf(m - mn) + __expf(l - mn);
        m = mn;
    }
    if ((lane & 15) == 0) {
        msbuf[(size_t)node * 8 + head]     = m;
        msbuf[(size_t)node * 8 + 4 + head] = s;
    }
}

__global__ __launch_bounds__(256)
void attn_aggr_kernel(const int* __restrict__ rowptr, const int* __restrict__ esrc,
                      const bf16* __restrict__ v, int rs, const float* __restrict__ alpha,
                      const float* __restrict__ msbuf, bf16* __restrict__ out, int n)
{
    int node = blockIdx.x * 4 + (threadIdx.x >> 6);
    if (node >= n) return;
    int lane = threadIdx.x & 63;
    int head = lane >> 4;
    int lo = rowptr[node], hi = rowptr[node + 1];

    float m   = msbuf[(size_t)node * 8 + head];
    float inv = 1.f / (msbuf[(size_t)node * 8 + 4 + head] + 1e-16f);

    float a0 = 0.f, a1 = 0.f, a2 = 0.f, a3 = 0.f;
    for (int i = lo; i < hi; ++i) {
        int sn = esrc[i];
        float e = __expf(alpha[(size_t)i * 4 + head] - m) * inv;
        ushort4 vu = ((const ushort4*)(v + (size_t)sn * rs))[lane];
        a0 = fmaf(e, bfu(vu.x), a0);
        a1 = fmaf(e, bfu(vu.y), a1);
        a2 = fmaf(e, bfu(vu.z), a2);
        a3 = fmaf(e, bfu(vu.w), a3);
    }
    ushort4 o;
    o.x = f2bu(fmaxf(a0, 0.f));
    o.y = f2bu(fmaxf(a1, 0.f));
    o.z = f2bu(fmaxf(a2, 0.f));
    o.w = f2bu(fmaxf(a3, 0.f));
    ((ushort4*)(out + (size_t)node * OUT_C))[lane] = o;
}

// ---------- per-channel BN stats ----------
template<typename TX>
__global__ __launch_bounds__(256)
void col_stats_kernel(const TX* __restrict__ x, float* __restrict__ bnsum,
                      float* __restrict__ bnsumsq, int M)
{
    const int c = threadIdx.x;
    const int r0 = blockIdx.x * 64;
    const int r1 = min(r0 + 64, M);
    float ls = 0.f, lq = 0.f;
    for (int r = r0; r < r1; ++r) {
        float val = ldf(&x[(size_t)r * OUT_C + c]);
        ls += val;
        lq += val * val;
    }
    atomicAdd(&bnsum[c], ls);
    atomicAdd(&bnsumsq[c], lq);
}

// ---------- BN apply ----------
template<typename TX, typename TO>
__global__ __launch_bounds__(256)
void bn_apply_kernel(const TX* __restrict__ x, const float* __restrict__ bnsum,
                     const float* __restrict__ bnsumsq, const float* __restrict__ g,
                     const float* __restrict__ be, const bf16* __restrict__ add,
                     TO* __restrict__ y, float invM, size_t total)
{
    size_t idx = (size_t)blockIdx.x * blockDim.x + threadIdx.x;
    if (idx >= total) return;
    int c = (int)(idx & 255);
    float mu  = bnsum[c] * invM;
    float var = bnsumsq[c] * invM - mu * mu;
    float val = (ldf(&x[idx]) - mu) * rsqrtf(var + 1e-5f) * g[c] + be[c];
    if (add) val += ldf(&add[idx]);
    stf(&y[idx], val);
}

// ---------- pooling ----------
__global__ __launch_bounds__(256)
void pool_kernel(const bf16* __restrict__ h, const int* __restrict__ ibatch,
                 float* __restrict__ out)
{
    int g = blockIdx.x;
    __shared__ int bounds[2];
    if (threadIdx.x == 0) {
        int lo = 0, hi = N_NODES;
        while (lo < hi) { int mid = (lo + hi) >> 1; if (ibatch[mid] < g) lo = mid + 1; else hi = mid; }
        bounds[0] = lo;
        int lo2 = lo, hi2 = N_NODES;
        while (lo2 < hi2) { int mid = (lo2 + hi2) >> 1; if (ibatch[mid] < g + 1) lo2 = mid + 1; else hi2 = mid; }
        bounds[1] = lo2;
    }
    __syncthreads();
    int lo = bounds[0], hi = bounds[1];
    int c = threadIdx.x;
    float s = 0.f;
    for (int r = lo; r < hi; ++r) s += ldf(&h[(size_t)r * OUT_C + c]);
    out[(size_t)g * OUT_C + c] = s / fmaxf((float)(hi - lo), 1.f);
}

extern "C" void kernel_launch(void* const* d_in, const int* in_sizes, int n_in,
                              void* d_out, int out_size, void* d_ws, size_t ws_size,
                              hipStream_t stream)
{
    const float* drug_x  = (const float*)d_in[0];
    const int*   adj     = (const int*)  d_in[1];
    const int*   ibatch  = (const int*)  d_in[2];
    const float* cline_x = (const float*)d_in[3];
    const float* Wq1 = (const float*)d_in[4];  const float* bq1 = (const float*)d_in[5];
    const float* Wk1 = (const float*)d_in[6];  const float* bk1 = (const float*)d_in[7];
    const float* Wv1 = (const float*)d_in[8];  const float* bv1 = (const float*)d_in[9];
    const float* g1  = (const float*)d_in[10]; const float* be1 = (const float*)d_in[11];
    const float* Wq2 = (const float*)d_in[12]; const float* bq2 = (const float*)d_in[13];
    const float* Wk2 = (const float*)d_in[14]; const float* bk2 = (const float*)d_in[15];
    const float* Wv2 = (const float*)d_in[16]; const float* bv2 = (const float*)d_in[17];
    const float* g2  = (const float*)d_in[18]; const float* be2 = (const float*)d_in[19];
    const float* Wc1 = (const float*)d_in[20]; const float* bc1 = (const float*)d_in[21];
    const float* gc  = (const float*)d_in[22]; const float* bec = (const float*)d_in[23];
    const float* Wc2 = (const float*)d_in[24]; const float* bc2 = (const float*)d_in[25];

    const int* srcp = adj;
    const int* dstp = adj + N_EDGES;

    // ---- workspace arena (~223 MB) ----
    char* p = (char*)d_ws;
    auto take = [&p](size_t bytes) {
        char* r = p;
        p += (bytes + 15) & ~(size_t)15;
        return r;
    };
    bf16*  qk    = (bf16*)take((size_t)N_NODES * 512 * sizeof(bf16)); // q|k, then v; later cline bufs
    bf16*  conv  = (bf16*)take((size_t)N_NODES * OUT_C * sizeof(bf16));
    bf16*  h1    = (bf16*)take((size_t)N_NODES * OUT_C * sizeof(bf16)); // also drug_xb early
    float* alpha = (float*)take((size_t)N_EDGES * 4 * sizeof(float));
    float* msbuf = (float*)take((size_t)N_NODES * 8 * sizeof(float));
    int*   rowptr= (int*)take((size_t)(N_NODES + 1) * sizeof(int));
    int*   degcur= (int*)take((size_t)N_NODES * sizeof(int));
    int*   bsum  = (int*)take(256 * sizeof(int));
    int*   bsume = (int*)take(256 * sizeof(int));
    int*   esrc  = (int*)take((size_t)N_EDGES * sizeof(int));
    float* bnsum = (float*)take(256 * sizeof(float));
    float* bnsumsq=(float*)take(256 * sizeof(float));
    bf16*  Wt1qk = (bf16*)take((size_t)512 * 128 * sizeof(bf16));
    bf16*  Wt1v  = (bf16*)take((size_t)256 * 128 * sizeof(bf16));
    bf16*  Wt2qk = (bf16*)take((size_t)512 * 256 * sizeof(bf16));
    bf16*  Wt2v  = (bf16*)take((size_t)256 * 256 * sizeof(bf16));
    bf16*  Wtc1  = (bf16*)take((size_t)256 * 960 * sizeof(bf16));
    bf16*  Wtc2  = (bf16*)take((size_t)256 * 256 * sizeof(bf16));
    float* bias_qk1 = (float*)take(512 * sizeof(float));
    float* bias_qk2 = (float*)take(512 * sizeof(float));
    size_t needed = (size_t)(p - (char*)d_ws);
    if (ws_size < needed) return;

    // aliases (lifetime-disjoint):
    bf16* drug_xb = h1;                       // [N,128] bf16, dead before h1 written
    bf16* cline_xb = qk;                      // [2048,960] bf16, after qk dead
    float* c1  = (float*)(qk + (size_t)2048 * 960);          // 2 MB
    bf16*  cbn = (bf16*)(c1 + (size_t)B_CL * OUT_C);         // 1 MB

    float* out_pool = (float*)d_out;                      // [G,256]
    float* out_c    = out_pool + (size_t)N_GRAPH * OUT_C; // [B,256]

    const int MT = (N_NODES + 127) / 128;   // 782
    dim3 gN_qk(4, MT), gN_v(2, MT);          // x = ntile (A-tile siblings adjacent)
    dim3 gB(2, 16);
    const int nodeBlocks = (N_NODES + 3) / 4;
    const size_t nTot = (size_t)N_NODES * OUT_C;

    // ===================== prep =====================
    convert_a_kernel<<<(N_NODES * 128 + 255) / 256, 256, 0, stream>>>(
        drug_x, drug_xb, DRUG_DIM, 128, N_NODES * 128);
    convert_wt_kernel<<<256, 256, 0, stream>>>(Wq1, Wt1qk, DRUG_DIM, 256, 0,   128);
    convert_wt_kernel<<<256, 256, 0, stream>>>(Wk1, Wt1qk, DRUG_DIM, 256, 256, 128);
    convert_wt_kernel<<<256, 256, 0, stream>>>(Wv1, Wt1v,  DRUG_DIM, 256, 0,   128);
    convert_wt_kernel<<<256, 256, 0, stream>>>(Wq2, Wt2qk, 256, 256, 0,   256);
    convert_wt_kernel<<<256, 256, 0, stream>>>(Wk2, Wt2qk, 256, 256, 256, 256);
    convert_wt_kernel<<<256, 256, 0, stream>>>(Wv2, Wt2v,  256, 256, 0,   256);
    convert_wt_kernel<<<256, 256, 0, stream>>>(Wc1, Wtc1,  CLINE_DIM, 256, 0, 960);
    convert_wt_kernel<<<256, 256, 0, stream>>>(Wc2, Wtc2,  256, 256, 0, 256);
    concat_bias_kernel<<<2, 256, 0, stream>>>(bq1, bk1, bias_qk1);
    concat_bias_kernel<<<2, 256, 0, stream>>>(bq2, bk2, bias_qk2);

    // ===================== CSR build =====================
    hipMemsetAsync(degcur, 0, N_NODES * sizeof(int), stream);
    hist_kernel<<<(N_EDGES + 255) / 256, 256, 0, stream>>>(dstp, degcur, N_EDGES);
    const int NB1 = (N_NODES + 1023) / 1024;
    scan1_kernel<<<NB1, 256, 0, stream>>>(degcur, rowptr, bsum, N_NODES);
    scan2_kernel<<<1, 256, 0, stream>>>(bsum, bsume, NB1);
    scan3_kernel<<<(N_NODES + 255) / 256, 256, 0, stream>>>(rowptr, degcur, bsume, N_NODES, N_EDGES);
    scatter_kernel<<<(N_EDGES + 255) / 256, 256, 0, stream>>>(srcp, dstp, degcur, esrc, N_EDGES);

    // ===================== drug layer 1 =====================
    mfma_gemm_kernel<0, bf16><<<gN_qk, 256, 0, stream>>>(
        drug_xb, Wt1qk, bias_qk1, nullptr, qk, N_NODES, 128, 512);
    attn_logits_kernel<<<nodeBlocks, 256, 0, stream>>>(rowptr, esrc, qk, qk + 256, 512, alpha, msbuf, N_NODES);
    mfma_gemm_kernel<0, bf16><<<gN_v, 256, 0, stream>>>(
        drug_xb, Wt1v, bv1, nullptr, qk, N_NODES, 128, 512);   // v into dead q half
    attn_aggr_kernel<<<nodeBlocks, 256, 0, stream>>>(rowptr, esrc, qk, 512, alpha, msbuf, conv, N_NODES);
    hipMemsetAsync(bnsum, 0, 512 * sizeof(float), stream);
    col_stats_kernel<bf16><<<(N_NODES + 63) / 64, 256, 0, stream>>>(conv, bnsum, bnsumsq, N_NODES);
    bn_apply_kernel<bf16, bf16><<<(nTot + 255) / 256, 256, 0, stream>>>(
        conv, bnsum, bnsumsq, g1, be1, nullptr, h1, 1.0f / N_NODES, nTot);

    // ===================== drug layer 2 =====================
    mfma_gemm_kernel<0, bf16><<<gN_qk, 256, 0, stream>>>(
        h1, Wt2qk, bias_qk2, nullptr, qk, N_NODES, 256, 512);
    attn_logits_kernel<<<nodeBlocks, 256, 0, stream>>>(rowptr, esrc, qk, qk + 256, 512, alpha, msbuf, N_NODES);
    mfma_gemm_kernel<0, bf16><<<gN_v, 256, 0, stream>>>(
        h1, Wt2v, bv2, nullptr, qk, N_NODES, 256, 512);
    attn_aggr_kernel<<<nodeBlocks, 256, 0, stream>>>(rowptr, esrc, qk, 512, alpha, msbuf, conv, N_NODES);
    hipMemsetAsync(bnsum, 0, 512 * sizeof(float), stream);
    col_stats_kernel<bf16><<<(N_NODES + 63) / 64, 256, 0, stream>>>(conv, bnsum, bnsumsq, N_NODES);
    bn_apply_kernel<bf16, bf16><<<(nTot + 255) / 256, 256, 0, stream>>>(
        conv, bnsum, bnsumsq, g2, be2, h1, conv, 1.0f / N_NODES, nTot);

    // ===================== pooling =====================
    pool_kernel<<<N_GRAPH, 256, 0, stream>>>(conv, ibatch, out_pool);

    // ===================== cline branch (qk region now dead) =====================
    convert_a_kernel<<<(B_CL * 960 + 255) / 256, 256, 0, stream>>>(
        cline_x, cline_xb, CLINE_DIM, 960, B_CL * 960);
    mfma_gemm_kernel<1, float><<<gB, 256, 0, stream>>>(
        cline_xb, Wtc1, bc1, nullptr, c1, B_CL, 960, 256);
    hipMemsetAsync(bnsum, 0, 512 * sizeof(float), stream);
    col_stats_kernel<float><<<(B_CL + 63) / 64, 256, 0, stream>>>(c1, bnsum, bnsumsq, B_CL);
    bn_apply_kernel<float, bf16><<<((size_t)B_CL * OUT_C + 255) / 256, 256, 0, stream>>>(
        c1, bnsum, bnsumsq, gc, bec, nullptr, cbn, 1.0f / B_CL, (size_t)B_CL * OUT_C);
    mfma_gemm_kernel<2, float><<<gB, 256, 0, stream>>>(
        cbn, Wtc2, bc2, c1, out_c, B_CL, 256, 256);
}

// Round 7
// 852.056 us; speedup vs baseline: 3.0862x; 1.0570x over previous
//
#include <hip/hip_runtime.h>
#include <hip/hip_bf16.h>

// Problem constants (match reference)
static constexpr int N_NODES  = 100000;
static constexpr int N_EDGES  = 400000;
static constexpr int DRUG_DIM = 75;
static constexpr int OUT_C    = 256;   // OUT
static constexpr int N_GRAPH  = 2048;  // G
static constexpr int B_CL     = 2048;  // B
static constexpr int CLINE_DIM= 954;

using bf16 = __hip_bfloat16;
using short8 = __attribute__((ext_vector_type(8))) short;
using f32x4  = __attribute__((ext_vector_type(4))) float;

// ---------- load/store helpers ----------
__device__ __forceinline__ float ldf(const float* p) { return *p; }
__device__ __forceinline__ float ldf(const bf16* p)  { return __bfloat162float(*p); }
__device__ __forceinline__ void  stf(float* p, float v) { *p = v; }
__device__ __forceinline__ void  stf(bf16* p, float v)  { *p = __float2bfloat16(v); }
__device__ __forceinline__ float bfu(unsigned short u) { return __uint_as_float(((unsigned)u) << 16); }
__device__ __forceinline__ unsigned short f2bu(float f) {
    bf16 h = __float2bfloat16(f);
    return *reinterpret_cast<unsigned short*>(&h);
}

// async global -> LDS, 16B per lane; LDS dest = uniform base + lane*16
__device__ __forceinline__ void gload_lds16(const void* g, void* l) {
    __builtin_amdgcn_global_load_lds(
        (const __attribute__((address_space(1))) void*)g,
        (__attribute__((address_space(3))) void*)l, 16, 0, 0);
}

// ================= input/weight prep =================
__global__ __launch_bounds__(256)
void convert_a_kernel(const float* __restrict__ A, bf16* __restrict__ Ab,
                      int K, int Kpad, int total)
{
    int idx = blockIdx.x * 256 + threadIdx.x;
    if (idx >= total) return;
    int r = idx / Kpad, k = idx - r * Kpad;
    float f = (k < K) ? A[(size_t)r * K + k] : 0.f;
    Ab[idx] = __float2bfloat16(f);
}

__global__ __launch_bounds__(256)
void convert_wt_kernel(const float* __restrict__ W, bf16* __restrict__ Wt,
                       int K, int NW, int n0, int Kpad)
{
    int n = blockIdx.x;
    for (int k = threadIdx.x; k < Kpad; k += 256) {
        float f = (k < K) ? W[(size_t)k * NW + n] : 0.f;
        Wt[(size_t)(n0 + n) * Kpad + k] = __float2bfloat16(f);
    }
}

__global__ __launch_bounds__(256)
void concat_bias_kernel(const float* __restrict__ a, const float* __restrict__ b,
                        float* __restrict__ out)
{
    int i = blockIdx.x * 256 + threadIdx.x;
    if (i < 512) out[i] = (i < 256) ? a[i] : b[i - 256];
}

// ================= MFMA GEMM (2-phase pipelined global_load_lds) =================
// C[M x *] = act(A[M x K] @ Wt^T + bias) (+res). A bf16 [M][K], K mult of 64,
// M mult of 8, NCOLS mult of 128. Tile 128x128, BK=64, 4 waves (2x2), dbuf LDS.
// LDS relation: LDS[row][y] = data[row][y ^ ((row&7)<<3)] via pre-swizzled
// global source element (LDS dest stays linear - rule #21).
// Schedule per K-step: stage(next buf) -> ds_read+MFMA(cur buf) -> barrier
// (barrier's implicit vmcnt(0) drains the stage that overlapped with compute).
template<int ACT, typename TO>
__global__ __launch_bounds__(256)
void mfma_gemm_kernel(const bf16* __restrict__ A, const bf16* __restrict__ Wt,
                      const float* __restrict__ bias, const float* __restrict__ res,
                      TO* __restrict__ C, int M, int K, int NC)
{
    __shared__ alignas(16) short As[2][128 * 64];
    __shared__ alignas(16) short Bs[2][128 * 64];
    const int ntile = blockIdx.x, mtile = blockIdx.y;
    const int tid = threadIdx.x;
    const int lane = tid & 63, wid = tid >> 6;
    const int wr = wid >> 1, wc = wid & 1;

    f32x4 acc[4][4] = {};

    auto stage = [&](int b, int k0) {
        #pragma unroll
        for (int i = 0; i < 4; ++i) {
            const int chunk = i * 4 + wid;            // wave-uniform
            const int row   = chunk * 8 + (lane >> 3);
            const int e     = ((lane & 7) ^ (row & 7)) << 3;  // pre-swizzled src elem
            if (mtile * 128 + chunk * 8 + 8 <= M)     // wave-uniform guard (M % 8 == 0)
                gload_lds16(A + (size_t)(mtile * 128 + row) * K + k0 + e,
                            &As[b][chunk * 512]);
            gload_lds16(Wt + (size_t)(ntile * 128 + row) * K + k0 + e,
                        &Bs[b][chunk * 512]);
        }
    };

    const int NT = K >> 6;
    stage(0, 0);
    __syncthreads();   // drains vmcnt(0): buf0 ready

    for (int t = 0; t < NT; ++t) {
        const int cur = t & 1;
        if (t + 1 < NT) stage(cur ^ 1, (t + 1) << 6);   // overlaps with compute below
        #pragma unroll
        for (int kk = 0; kk < 2; ++kk) {
            const int coff = (kk * 32 + (lane >> 4) * 8) ^ ((lane & 7) << 3);
            short8 a[4], b[4];
            #pragma unroll
            for (int m = 0; m < 4; ++m)
                a[m] = *reinterpret_cast<const short8*>(
                    &As[cur][(wr * 64 + m * 16 + (lane & 15)) * 64 + coff]);
            #pragma unroll
            for (int n = 0; n < 4; ++n)
                b[n] = *reinterpret_cast<const short8*>(
                    &Bs[cur][(wc * 64 + n * 16 + (lane & 15)) * 64 + coff]);
            #pragma unroll
            for (int m = 0; m < 4; ++m)
                #pragma unroll
                for (int n = 0; n < 4; ++n)
                    acc[m][n] = __builtin_amdgcn_mfma_f32_16x16x32_bf16(
                        a[m], b[n], acc[m][n], 0, 0, 0);
        }
        __syncthreads();   // all reads of cur done + next buf drained
    }

    // epilogue: C/D layout col=lane&15, row=(lane>>4)*4+reg
    #pragma unroll
    for (int m = 0; m < 4; ++m) {
        int row0 = mtile * 128 + wr * 64 + m * 16 + ((lane >> 4) << 2);
        #pragma unroll
        for (int n = 0; n < 4; ++n) {
            int col = ntile * 128 + wc * 64 + n * 16 + (lane & 15);
            float bcol = bias[col];
            #pragma unroll
            for (int r = 0; r < 4; ++r) {
                int row = row0 + r;
                if (row < M) {
                    float val = acc[m][n][r] + bcol;
                    if (ACT == 1) val = tanhf(val);
                    if (ACT == 2) val = fmaxf(val, 0.f);
                    if (res) val += res[(size_t)row * NC + col];
                    stf(&C[(size_t)row * NC + col], val);
                }
            }
        }
    }
}

// ================= CSR build =================
__global__ __launch_bounds__(256)
void hist_kernel(const int* __restrict__ dst, int* __restrict__ deg, int E)
{
    int e = blockIdx.x * 256 + threadIdx.x;
    if (e < E) atomicAdd(&deg[dst[e]], 1);
}

__global__ __launch_bounds__(256)
void scan1_kernel(const int* __restrict__ deg, int* __restrict__ part,
                  int* __restrict__ bsum, int n)
{
    __shared__ int sh[256];
    const int t = threadIdx.x;
    const int b0 = blockIdx.x * 1024;
    int v[4]; int s = 0;
    #pragma unroll
    for (int j = 0; j < 4; ++j) {
        int idx = b0 + t * 4 + j;
        v[j] = (idx < n) ? deg[idx] : 0;
        s += v[j];
    }
    sh[t] = s; __syncthreads();
    for (int off = 1; off < 256; off <<= 1) {
        int x = (t >= off) ? sh[t - off] : 0;
        __syncthreads();
        sh[t] += x;
        __syncthreads();
    }
    if (t == 255) bsum[blockIdx.x] = sh[255];
    int run = sh[t] - s;
    #pragma unroll
    for (int j = 0; j < 4; ++j) {
        int idx = b0 + t * 4 + j;
        if (idx < n) part[idx] = run;
        run += v[j];
    }
}

__global__ __launch_bounds__(256)
void scan2_kernel(const int* __restrict__ bsum, int* __restrict__ bsume, int nb)
{
    __shared__ int sh[256];
    const int t = threadIdx.x;
    int x0 = (t < nb) ? bsum[t] : 0;
    sh[t] = x0; __syncthreads();
    for (int off = 1; off < 256; off <<= 1) {
        int x = (t >= off) ? sh[t - off] : 0;
        __syncthreads();
        sh[t] += x;
        __syncthreads();
    }
    if (t < nb) bsume[t] = sh[t] - x0;
}

__global__ __launch_bounds__(256)
void scan3_kernel(int* __restrict__ rowptr, int* __restrict__ cursor,
                  const int* __restrict__ bsume, int n, int E)
{
    int idx = blockIdx.x * 256 + threadIdx.x;
    if (idx < n) {
        int val = rowptr[idx] + bsume[idx >> 10];
        rowptr[idx] = val;
        cursor[idx] = val;
    }
    if (idx == 0) rowptr[n] = E;
}

__global__ __launch_bounds__(256)
void scatter_kernel(const int* __restrict__ src, const int* __restrict__ dst,
                    int* __restrict__ cursor, int* __restrict__ esrc, int E)
{
    int e = blockIdx.x * 256 + threadIdx.x;
    if (e < E) {
        int slot = atomicAdd(&cursor[dst[e]], 1);
        esrc[slot] = src[e];
    }
}

// ================= fused flash-style attention (CSR gather) =================
// wave per dst node; lane = head*16 + sub; each lane owns 4 dims of its head.
// qk: [N,512] rows (q | k). v: [N,256]. Output overwrites the q-half in place:
// q[node] is read only by node's own wave (before the write), and other waves
// only touch the k-half columns -> no race.
__global__ __launch_bounds__(256)
void attn_fused_kernel(const int* __restrict__ rowptr, const int* __restrict__ esrc,
                       bf16* __restrict__ qk, const bf16* __restrict__ v, int n)
{
    int node = blockIdx.x * 4 + (threadIdx.x >> 6);
    if (node >= n) return;
    int lane = threadIdx.x & 63;
    int lo = rowptr[node], hi = rowptr[node + 1];

    ushort4 qu = ((const ushort4*)(qk + (size_t)node * 512))[lane];
    float q0 = bfu(qu.x), q1 = bfu(qu.y), q2 = bfu(qu.z), q3 = bfu(qu.w);

    float m = -INFINITY, s = 0.f;
    float a0 = 0.f, a1 = 0.f, a2 = 0.f, a3 = 0.f;
    for (int i = lo; i < hi; ++i) {
        int sn = esrc[i];
        ushort4 ku = ((const ushort4*)(qk + (size_t)sn * 512 + 256))[lane];
        ushort4 vu = ((const ushort4*)(v  + (size_t)sn * 256))[lane];
        float p = q0 * bfu(ku.x);
        p = fmaf(q1, bfu(ku.y), p);
        p = fmaf(q2, bfu(ku.z), p);
        p = fmaf(q3, bfu(ku.w), p);
        p += __shfl_xor(p, 1);
        p += __shfl_xor(p, 2);
        p += __shfl_xor(p, 4);
        p += __shfl_xor(p, 8);       // 16-lane group sum -> per-head dot
        float l = p * 0.125f;        // 1/sqrt(64)
        float mn = fmaxf(m, l);
        float sc = __expf(m - mn);
        float e  = __expf(l - mn);
        a0 = fmaf(a0, sc, e * bfu(vu.x));
        a1 = fmaf(a1, sc, e * bfu(vu.y));
        a2 = fmaf(a2, sc, e * bfu(vu.z));
        a3 = fmaf(a3, sc, e * bfu(vu.w));
        s  = s * sc + e;
        m  = mn;
    }
    float inv = 1.f / (s + 1e-16f);
    ushort4 o;
    o.x = f2bu(fmaxf(a0 * inv, 0.f));
    o.y = f2bu(fmaxf(a1 * inv, 0.f));
    o.z = f2bu(fmaxf(a2 * inv, 0.f));
    o.w = f2bu(fmaxf(a3 * inv, 0.f));
    ((ushort4*)(qk + (size_t)node * 512))[lane] = o;   // overwrite q-half
}

// ---------- per-channel BN stats (strided input) ----------
template<typename TX>
__global__ __launch_bounds__(256)
void col_stats_kernel(const TX* __restrict__ x, int xs, float* __restrict__ bnsum,
                      float* __restrict__ bnsumsq, int M)
{
    const int c = threadIdx.x;
    const int r0 = blockIdx.x * 64;
    const int r1 = min(r0 + 64, M);
    float ls = 0.f, lq = 0.f;
    for (int r = r0; r < r1; ++r) {
        float val = ldf(&x[(size_t)r * xs + c]);
        ls += val;
        lq += val * val;
    }
    atomicAdd(&bnsum[c], ls);
    atomicAdd(&bnsumsq[c], lq);
}

// ---------- BN apply (strided input, compact [.,256] output) ----------
template<typename TX, typename TO>
__global__ __launch_bounds__(256)
void bn_apply_kernel(const TX* __restrict__ x, int xs, const float* __restrict__ bnsum,
                     const float* __restrict__ bnsumsq, const float* __restrict__ g,
                     const float* __restrict__ be, const bf16* __restrict__ add,
                     TO* __restrict__ y, float invM, size_t total)
{
    size_t idx = (size_t)blockIdx.x * blockDim.x + threadIdx.x;
    if (idx >= total) return;
    int c = (int)(idx & 255);
    size_t r = idx >> 8;
    float mu  = bnsum[c] * invM;
    float var = bnsumsq[c] * invM - mu * mu;
    float val = (ldf(&x[r * xs + c]) - mu) * rsqrtf(var + 1e-5f) * g[c] + be[c];
    if (add) val += ldf(&add[idx]);
    stf(&y[idx], val);
}

// ---------- pooling ----------
__global__ __launch_bounds__(256)
void pool_kernel(const bf16* __restrict__ h, const int* __restrict__ ibatch,
                 float* __restrict__ out)
{
    int g = blockIdx.x;
    __shared__ int bounds[2];
    if (threadIdx.x == 0) {
        int lo = 0, hi = N_NODES;
        while (lo < hi) { int mid = (lo + hi) >> 1; if (ibatch[mid] < g) lo = mid + 1; else hi = mid; }
        bounds[0] = lo;
        int lo2 = lo, hi2 = N_NODES;
        while (lo2 < hi2) { int mid = (lo2 + hi2) >> 1; if (ibatch[mid] < g + 1) lo2 = mid + 1; else hi2 = mid; }
        bounds[1] = lo2;
    }
    __syncthreads();
    int lo = bounds[0], hi = bounds[1];
    int c = threadIdx.x;
    float s = 0.f;
    for (int r = lo; r < hi; ++r) s += ldf(&h[(size_t)r * OUT_C + c]);
    out[(size_t)g * OUT_C + c] = s / fmaxf((float)(hi - lo), 1.f);
}

extern "C" void kernel_launch(void* const* d_in, const int* in_sizes, int n_in,
                              void* d_out, int out_size, void* d_ws, size_t ws_size,
                              hipStream_t stream)
{
    const float* drug_x  = (const float*)d_in[0];
    const int*   adj     = (const int*)  d_in[1];
    const int*   ibatch  = (const int*)  d_in[2];
    const float* cline_x = (const float*)d_in[3];
    const float* Wq1 = (const float*)d_in[4];  const float* bq1 = (const float*)d_in[5];
    const float* Wk1 = (const float*)d_in[6];  const float* bk1 = (const float*)d_in[7];
    const float* Wv1 = (const float*)d_in[8];  const float* bv1 = (const float*)d_in[9];
    const float* g1  = (const float*)d_in[10]; const float* be1 = (const float*)d_in[11];
    const float* Wq2 = (const float*)d_in[12]; const float* bq2 = (const float*)d_in[13];
    const float* Wk2 = (const float*)d_in[14]; const float* bk2 = (const float*)d_in[15];
    const float* Wv2 = (const float*)d_in[16]; const float* bv2 = (const float*)d_in[17];
    const float* g2  = (const float*)d_in[18]; const float* be2 = (const float*)d_in[19];
    const float* Wc1 = (const float*)d_in[20]; const float* bc1 = (const float*)d_in[21];
    const float* gc  = (const float*)d_in[22]; const float* bec = (const float*)d_in[23];
    const float* Wc2 = (const float*)d_in[24]; const float* bc2 = (const float*)d_in[25];

    const int* srcp = adj;
    const int* dstp = adj + N_EDGES;

    // ---- workspace arena (~216 MB) ----
    char* p = (char*)d_ws;
    auto take = [&p](size_t bytes) {
        char* r = p;
        p += (bytes + 15) & ~(size_t)15;
        return r;
    };
    bf16*  qk    = (bf16*)take((size_t)N_NODES * 512 * sizeof(bf16)); // q|k; attn out in q-half; later cline bufs
    bf16*  conv  = (bf16*)take((size_t)N_NODES * OUT_C * sizeof(bf16)); // v (both layers); final h
    bf16*  h1    = (bf16*)take((size_t)N_NODES * OUT_C * sizeof(bf16)); // also drug_xb early
    int*   rowptr= (int*)take((size_t)(N_NODES + 1) * sizeof(int));
    int*   degcur= (int*)take((size_t)N_NODES * sizeof(int));
    int*   bsum  = (int*)take(256 * sizeof(int));
    int*   bsume = (int*)take(256 * sizeof(int));
    int*   esrc  = (int*)take((size_t)N_EDGES * sizeof(int));
    float* bnsum = (float*)take(256 * sizeof(float));
    float* bnsumsq=(float*)take(256 * sizeof(float));
    bf16*  Wt1qk = (bf16*)take((size_t)512 * 128 * sizeof(bf16));
    bf16*  Wt1v  = (bf16*)take((size_t)256 * 128 * sizeof(bf16));
    bf16*  Wt2qk = (bf16*)take((size_t)512 * 256 * sizeof(bf16));
    bf16*  Wt2v  = (bf16*)take((size_t)256 * 256 * sizeof(bf16));
    bf16*  Wtc1  = (bf16*)take((size_t)256 * 960 * sizeof(bf16));
    bf16*  Wtc2  = (bf16*)take((size_t)256 * 256 * sizeof(bf16));
    float* bias_qk1 = (float*)take(512 * sizeof(float));
    float* bias_qk2 = (float*)take(512 * sizeof(float));
    size_t needed = (size_t)(p - (char*)d_ws);
    if (ws_size < needed) return;

    // aliases (lifetime-disjoint):
    bf16* drug_xb = h1;                       // [N,128] bf16, dead before h1 written
    bf16* cline_xb = qk;                      // [2048,960] bf16, after qk dead
    float* c1  = (float*)(qk + (size_t)2048 * 960);          // 2 MB
    bf16*  cbn = (bf16*)(c1 + (size_t)B_CL * OUT_C);         // 1 MB

    float* out_pool = (float*)d_out;                      // [G,256]
    float* out_c    = out_pool + (size_t)N_GRAPH * OUT_C; // [B,256]

    const int MT = (N_NODES + 127) / 128;   // 782
    dim3 gN_qk(4, MT), gN_v(2, MT);          // x = ntile (A-tile siblings adjacent)
    dim3 gB(2, 16);
    const int nodeBlocks = (N_NODES + 3) / 4;
    const size_t nTot = (size_t)N_NODES * OUT_C;

    // ===================== prep =====================
    convert_a_kernel<<<(N_NODES * 128 + 255) / 256, 256, 0, stream>>>(
        drug_x, drug_xb, DRUG_DIM, 128, N_NODES * 128);
    convert_wt_kernel<<<256, 256, 0, stream>>>(Wq1, Wt1qk, DRUG_DIM, 256, 0,   128);
    convert_wt_kernel<<<256, 256, 0, stream>>>(Wk1, Wt1qk, DRUG_DIM, 256, 256, 128);
    convert_wt_kernel<<<256, 256, 0, stream>>>(Wv1, Wt1v,  DRUG_DIM, 256, 0,   128);
    convert_wt_kernel<<<256, 256, 0, stream>>>(Wq2, Wt2qk, 256, 256, 0,   256);
    convert_wt_kernel<<<256, 256, 0, stream>>>(Wk2, Wt2qk, 256, 256, 256, 256);
    convert_wt_kernel<<<256, 256, 0, stream>>>(Wv2, Wt2v,  256, 256, 0,   256);
    convert_wt_kernel<<<256, 256, 0, stream>>>(Wc1, Wtc1,  CLINE_DIM, 256, 0, 960);
    convert_wt_kernel<<<256, 256, 0, stream>>>(Wc2, Wtc2,  256, 256, 0, 256);
    concat_bias_kernel<<<2, 256, 0, stream>>>(bq1, bk1, bias_qk1);
    concat_bias_kernel<<<2, 256, 0, stream>>>(bq2, bk2, bias_qk2);

    // ===================== CSR build =====================
    hipMemsetAsync(degcur, 0, N_NODES * sizeof(int), stream);
    hist_kernel<<<(N_EDGES + 255) / 256, 256, 0, stream>>>(dstp, degcur, N_EDGES);
    const int NB1 = (N_NODES + 1023) / 1024;
    scan1_kernel<<<NB1, 256, 0, stream>>>(degcur, rowptr, bsum, N_NODES);
    scan2_kernel<<<1, 256, 0, stream>>>(bsum, bsume, NB1);
    scan3_kernel<<<(N_NODES + 255) / 256, 256, 0, stream>>>(rowptr, degcur, bsume, N_NODES, N_EDGES);
    scatter_kernel<<<(N_EDGES + 255) / 256, 256, 0, stream>>>(srcp, dstp, degcur, esrc, N_EDGES);

    // ===================== drug layer 1 =====================
    mfma_gemm_kernel<0, bf16><<<gN_qk, 256, 0, stream>>>(
        drug_xb, Wt1qk, bias_qk1, nullptr, qk, N_NODES, 128, 512);
    mfma_gemm_kernel<0, bf16><<<gN_v, 256, 0, stream>>>(
        drug_xb, Wt1v, bv1, nullptr, conv, N_NODES, 128, 256);
    attn_fused_kernel<<<nodeBlocks, 256, 0, stream>>>(rowptr, esrc, qk, conv, N_NODES);
    hipMemsetAsync(bnsum, 0, 512 * sizeof(float), stream);
    col_stats_kernel<bf16><<<(N_NODES + 63) / 64, 256, 0, stream>>>(qk, 512, bnsum, bnsumsq, N_NODES);
    bn_apply_kernel<bf16, bf16><<<(nTot + 255) / 256, 256, 0, stream>>>(
        qk, 512, bnsum, bnsumsq, g1, be1, nullptr, h1, 1.0f / N_NODES, nTot);

    // ===================== drug layer 2 =====================
    mfma_gemm_kernel<0, bf16><<<gN_qk, 256, 0, stream>>>(
        h1, Wt2qk, bias_qk2, nullptr, qk, N_NODES, 256, 512);
    mfma_gemm_kernel<0, bf16><<<gN_v, 256, 0, stream>>>(
        h1, Wt2v, bv2, nullptr, conv, N_NODES, 256, 256);
    attn_fused_kernel<<<nodeBlocks, 256, 0, stream>>>(rowptr, esrc, qk, conv, N_NODES);
    hipMemsetAsync(bnsum, 0, 512 * sizeof(float), stream);
    col_stats_kernel<bf16><<<(N_NODES + 63) / 64, 256, 0, stream>>>(qk, 512, bnsum, bnsumsq, N_NODES);
    // final h = h1 + bn2(attn-out), compact into conv (v2 dead)
    bn_apply_kernel<bf16, bf16><<<(nTot + 255) / 256, 256, 0, stream>>>(
        qk, 512, bnsum, bnsumsq, g2, be2, h1, conv, 1.0f / N_NODES, nTot);

    // ===================== pooling =====================
    pool_kernel<<<N_GRAPH, 256, 0, stream>>>(conv, ibatch, out_pool);

    // ===================== cline branch (qk region now dead) =====================
    convert_a_kernel<<<(B_CL * 960 + 255) / 256, 256, 0, stream>>>(
        cline_x, cline_xb, CLINE_DIM, 960, B_CL * 960);
    mfma_gemm_kernel<1, float><<<gB, 256, 0, stream>>>(
        cline_xb, Wtc1, bc1, nullptr, c1, B_CL, 960, 256);
    hipMemsetAsync(bnsum, 0, 512 * sizeof(float), stream);
    col_stats_kernel<float><<<(B_CL + 63) / 64, 256, 0, stream>>>(c1, 256, bnsum, bnsumsq, B_CL);
    bn_apply_kernel<float, bf16><<<((size_t)B_CL * OUT_C + 255) / 256, 256, 0, stream>>>(
        c1, 256, bnsum, bnsumsq, gc, bec, nullptr, cbn, 1.0f / B_CL, (size_t)B_CL * OUT_C);
    mfma_gemm_kernel<2, float><<<gB, 256, 0, stream>>>(
        cbn, Wtc2, bc2, c1, out_c, B_CL, 256, 256);
}

// Round 8
// 748.321 us; speedup vs baseline: 3.5140x; 1.1386x over previous
//
#include <hip/hip_runtime.h>
#include <hip/hip_bf16.h>

// Problem constants (match reference)
static constexpr int N_NODES  = 100000;
static constexpr int N_EDGES  = 400000;
static constexpr int DRUG_DIM = 75;
static constexpr int OUT_C    = 256;   // OUT
static constexpr int N_GRAPH  = 2048;  // G
static constexpr int B_CL     = 2048;  // B
static constexpr int CLINE_DIM= 954;

using bf16 = __hip_bfloat16;
using short8 = __attribute__((ext_vector_type(8))) short;
using f32x4  = __attribute__((ext_vector_type(4))) float;

template<class A, class B> struct is_same_t { static constexpr bool v = false; };
template<class A> struct is_same_t<A, A>   { static constexpr bool v = true;  };

// ---------- load/store helpers ----------
__device__ __forceinline__ float ldf(const float* p) { return *p; }
__device__ __forceinline__ float ldf(const bf16* p)  { return __bfloat162float(*p); }
__device__ __forceinline__ void  stf(float* p, float v) { *p = v; }
__device__ __forceinline__ void  stf(bf16* p, float v)  { *p = __float2bfloat16(v); }
__device__ __forceinline__ float bfu(unsigned short u) { return __uint_as_float(((unsigned)u) << 16); }
__device__ __forceinline__ unsigned short f2bu(float f) {
    bf16 h = __float2bfloat16(f);
    return *reinterpret_cast<unsigned short*>(&h);
}

// async global -> LDS, 16B per lane; LDS dest = uniform base + lane*16
__device__ __forceinline__ void gload_lds16(const void* g, void* l) {
    __builtin_amdgcn_global_load_lds(
        (const __attribute__((address_space(1))) void*)g,
        (__attribute__((address_space(3))) void*)l, 16, 0, 0);
}

// ================= input/weight prep =================
__global__ __launch_bounds__(256)
void convert_a_kernel(const float* __restrict__ A, bf16* __restrict__ Ab,
                      int K, int Kpad, int total)
{
    int idx = blockIdx.x * 256 + threadIdx.x;
    if (idx >= total) return;
    int r = idx / Kpad, k = idx - r * Kpad;
    float f = (k < K) ? A[(size_t)r * K + k] : 0.f;
    Ab[idx] = __float2bfloat16(f);
}

// all weight transposes in one launch; NW is always 256
struct WtJob  { const float* W; bf16* Wt; int K; int n0; int Kpad; };
struct WtJobs { WtJob j[8]; };
__global__ __launch_bounds__(256)
void convert_wt8_kernel(WtJobs jobs)
{
    WtJob jb = jobs.j[blockIdx.y];
    int n = blockIdx.x;
    for (int k = threadIdx.x; k < jb.Kpad; k += 256) {
        float f = (k < jb.K) ? jb.W[(size_t)k * 256 + n] : 0.f;
        jb.Wt[(size_t)(jb.n0 + n) * jb.Kpad + k] = __float2bfloat16(f);
    }
}

__global__ __launch_bounds__(256)
void concat_bias_kernel(const float* __restrict__ a, const float* __restrict__ b,
                        float* __restrict__ out)
{
    int i = blockIdx.x * 256 + threadIdx.x;
    if (i < 512) out[i] = (i < 256) ? a[i] : b[i - 256];
}

// ================= MFMA GEMM (single-buffer global_load_lds, round-6 proven) ====
// C[M x *] = act(A[M x K] @ Wt^T + bias) (+res). A bf16 [M][K], K mult of 64,
// M mult of 8, NCOLS mult of 128. Tile 128x128, BK=64, 4 waves (2x2).
// LDS relation: LDS[row][y] = data[row][y ^ ((row&7)<<3)] via pre-swizzled
// global source element (LDS dest stays linear - rule #21).
// bf16-output epilogue: per-wave LDS bounce -> short8 (16B/lane) stores.
template<int ACT, typename TO>
__global__ __launch_bounds__(256)
void mfma_gemm_kernel(const bf16* __restrict__ A, const bf16* __restrict__ Wt,
                      const float* __restrict__ bias, const float* __restrict__ res,
                      TO* __restrict__ C, int M, int K, int NC)
{
    __shared__ alignas(16) short As[128 * 64];
    __shared__ alignas(16) short Bs[128 * 64];
    const int ntile = blockIdx.x, mtile = blockIdx.y;
    const int tid = threadIdx.x;
    const int lane = tid & 63, wid = tid >> 6;
    const int wr = wid >> 1, wc = wid & 1;

    f32x4 acc[4][4] = {};

    for (int k0 = 0; k0 < K; k0 += 64) {
        #pragma unroll
        for (int i = 0; i < 4; ++i) {
            const int chunk = i * 4 + wid;            // wave-uniform
            const int row   = chunk * 8 + (lane >> 3);
            const int e     = ((lane & 7) ^ (row & 7)) << 3;  // pre-swizzled src elem
            if (mtile * 128 + chunk * 8 + 8 <= M)     // wave-uniform guard (M % 8 == 0)
                gload_lds16(A + (size_t)(mtile * 128 + row) * K + k0 + e,
                            &As[chunk * 512]);
            gload_lds16(Wt + (size_t)(ntile * 128 + row) * K + k0 + e,
                        &Bs[chunk * 512]);
        }
        __syncthreads();   // drains vmcnt(0): LDS tiles ready
        #pragma unroll
        for (int kk = 0; kk < 2; ++kk) {
            const int coff = (kk * 32 + (lane >> 4) * 8) ^ ((lane & 7) << 3);
            short8 a[4], b[4];
            #pragma unroll
            for (int m = 0; m < 4; ++m)
                a[m] = *reinterpret_cast<const short8*>(
                    &As[(wr * 64 + m * 16 + (lane & 15)) * 64 + coff]);
            #pragma unroll
            for (int n = 0; n < 4; ++n)
                b[n] = *reinterpret_cast<const short8*>(
                    &Bs[(wc * 64 + n * 16 + (lane & 15)) * 64 + coff]);
            #pragma unroll
            for (int m = 0; m < 4; ++m)
                #pragma unroll
                for (int n = 0; n < 4; ++n)
                    acc[m][n] = __builtin_amdgcn_mfma_f32_16x16x32_bf16(
                        a[m], b[n], acc[m][n], 0, 0, 0);
        }
        __syncthreads();
    }

    // epilogue: C/D layout col=lane&15, row=(lane>>4)*4+reg
    if constexpr (is_same_t<TO, bf16>::v) {
        // per-wave private 8KB bounce region in the (now dead) As/Bs
        short* eb = (wid < 2 ? As : Bs) + (wid & 1) * 4096;
        #pragma unroll
        for (int m = 0; m < 4; ++m)
            #pragma unroll
            for (int n = 0; n < 4; ++n) {
                int col_l = n * 16 + (lane & 15);
                float bcol = bias[ntile * 128 + wc * 64 + col_l];
                #pragma unroll
                for (int r = 0; r < 4; ++r) {
                    int row_l = m * 16 + ((lane >> 4) << 2) + r;
                    float val = acc[m][n][r] + bcol;
                    if (ACT == 2) val = fmaxf(val, 0.f);
                    eb[row_l * 64 + (col_l ^ ((row_l & 7) << 3))] = (short)f2bu(val);
                }
            }
        // read back coalesced: 8 lanes per row, 16B per lane
        #pragma unroll
        for (int i = 0; i < 8; ++i) {
            int row_l = i * 8 + (lane >> 3);
            int row_g = mtile * 128 + wr * 64 + row_l;
            short8 vr = *reinterpret_cast<const short8*>(
                &eb[row_l * 64 + ((((lane & 7) << 3)) ^ ((row_l & 7) << 3))]);
            if (row_g < M)
                *reinterpret_cast<short8*>(
                    &C[(size_t)row_g * NC + ntile * 128 + wc * 64 + ((lane & 7) << 3)]) = vr;
        }
    } else {
        #pragma unroll
        for (int m = 0; m < 4; ++m) {
            int row0 = mtile * 128 + wr * 64 + m * 16 + ((lane >> 4) << 2);
            #pragma unroll
            for (int n = 0; n < 4; ++n) {
                int col = ntile * 128 + wc * 64 + n * 16 + (lane & 15);
                float bcol = bias[col];
                #pragma unroll
                for (int r = 0; r < 4; ++r) {
                    int row = row0 + r;
                    if (row < M) {
                        float val = acc[m][n][r] + bcol;
                        if (ACT == 1) val = tanhf(val);
                        if (ACT == 2) val = fmaxf(val, 0.f);
                        if (res) val += res[(size_t)row * NC + col];
                        stf(&C[(size_t)row * NC + col], val);
                    }
                }
            }
        }
    }
}

// ================= CSR build =================
__global__ __launch_bounds__(256)
void hist_kernel(const int* __restrict__ dst, int* __restrict__ deg, int E)
{
    int e = blockIdx.x * 256 + threadIdx.x;
    if (e < E) atomicAdd(&deg[dst[e]], 1);
}

__global__ __launch_bounds__(256)
void scan1_kernel(const int* __restrict__ deg, int* __restrict__ part,
                  int* __restrict__ bsum, int n)
{
    __shared__ int sh[256];
    const int t = threadIdx.x;
    const int b0 = blockIdx.x * 1024;
    int v[4]; int s = 0;
    #pragma unroll
    for (int j = 0; j < 4; ++j) {
        int idx = b0 + t * 4 + j;
        v[j] = (idx < n) ? deg[idx] : 0;
        s += v[j];
    }
    sh[t] = s; __syncthreads();
    for (int off = 1; off < 256; off <<= 1) {
        int x = (t >= off) ? sh[t - off] : 0;
        __syncthreads();
        sh[t] += x;
        __syncthreads();
    }
    if (t == 255) bsum[blockIdx.x] = sh[255];
    int run = sh[t] - s;
    #pragma unroll
    for (int j = 0; j < 4; ++j) {
        int idx = b0 + t * 4 + j;
        if (idx < n) part[idx] = run;
        run += v[j];
    }
}

__global__ __launch_bounds__(256)
void scan2_kernel(const int* __restrict__ bsum, int* __restrict__ bsume, int nb)
{
    __shared__ int sh[256];
    const int t = threadIdx.x;
    int x0 = (t < nb) ? bsum[t] : 0;
    sh[t] = x0; __syncthreads();
    for (int off = 1; off < 256; off <<= 1) {
        int x = (t >= off) ? sh[t - off] : 0;
        __syncthreads();
        sh[t] += x;
        __syncthreads();
    }
    if (t < nb) bsume[t] = sh[t] - x0;
}

__global__ __launch_bounds__(256)
void scan3_kernel(int* __restrict__ rowptr, int* __restrict__ cursor,
                  const int* __restrict__ bsume, int n, int E)
{
    int idx = blockIdx.x * 256 + threadIdx.x;
    if (idx < n) {
        int val = rowptr[idx] + bsume[idx >> 10];
        rowptr[idx] = val;
        cursor[idx] = val;
    }
    if (idx == 0) rowptr[n] = E;
}

__global__ __launch_bounds__(256)
void scatter_kernel(const int* __restrict__ src, const int* __restrict__ dst,
                    int* __restrict__ cursor, int* __restrict__ esrc, int E)
{
    int e = blockIdx.x * 256 + threadIdx.x;
    if (e < E) {
        int slot = atomicAdd(&cursor[dst[e]], 1);
        esrc[slot] = src[e];
    }
}

// ================= fused flash-style attention (CSR gather) =================
// wave per dst node. qk: [N,512] rows (q | k). v: [N,256].
// out: [N, os] (os=512 -> in-place q-half overwrite; os=256 -> compact).
__global__ __launch_bounds__(256)
void attn_fused_kernel(const int* __restrict__ rowptr, const int* __restrict__ esrc,
                       bf16* __restrict__ qk, const bf16* __restrict__ v,
                       bf16* __restrict__ out, int os, int n)
{
    int node = blockIdx.x * 4 + (threadIdx.x >> 6);
    if (node >= n) return;
    int lane = threadIdx.x & 63;
    int lo = rowptr[node], hi = rowptr[node + 1];

    ushort4 qu = ((const ushort4*)(qk + (size_t)node * 512))[lane];
    float q0 = bfu(qu.x), q1 = bfu(qu.y), q2 = bfu(qu.z), q3 = bfu(qu.w);

    float m = -INFINITY, s = 0.f;
    float a0 = 0.f, a1 = 0.f, a2 = 0.f, a3 = 0.f;
    for (int i = lo; i < hi; ++i) {
        int sn = esrc[i];
        ushort4 ku = ((const ushort4*)(qk + (size_t)sn * 512 + 256))[lane];
        ushort4 vu = ((const ushort4*)(v  + (size_t)sn * 256))[lane];
        float p = q0 * bfu(ku.x);
        p = fmaf(q1, bfu(ku.y), p);
        p = fmaf(q2, bfu(ku.z), p);
        p = fmaf(q3, bfu(ku.w), p);
        p += __shfl_xor(p, 1);
        p += __shfl_xor(p, 2);
        p += __shfl_xor(p, 4);
        p += __shfl_xor(p, 8);       // 16-lane group sum -> per-head dot
        float l = p * 0.125f;        // 1/sqrt(64)
        float mn = fmaxf(m, l);
        float sc = __expf(m - mn);
        float e  = __expf(l - mn);
        a0 = fmaf(a0, sc, e * bfu(vu.x));
        a1 = fmaf(a1, sc, e * bfu(vu.y));
        a2 = fmaf(a2, sc, e * bfu(vu.z));
        a3 = fmaf(a3, sc, e * bfu(vu.w));
        s  = s * sc + e;
        m  = mn;
    }
    float inv = 1.f / (s + 1e-16f);
    ushort4 o;
    o.x = f2bu(fmaxf(a0 * inv, 0.f));
    o.y = f2bu(fmaxf(a1 * inv, 0.f));
    o.z = f2bu(fmaxf(a2 * inv, 0.f));
    o.w = f2bu(fmaxf(a3 * inv, 0.f));
    ((ushort4*)(out + (size_t)node * os))[lane] = o;
}

// ---------- per-channel BN stats (strided input) ----------
template<typename TX>
__global__ __launch_bounds__(256)
void col_stats_kernel(const TX* __restrict__ x, int xs, float* __restrict__ bnsum,
                      float* __restrict__ bnsumsq, int M)
{
    const int c = threadIdx.x;
    const int r0 = blockIdx.x * 64;
    const int r1 = min(r0 + 64, M);
    float ls = 0.f, lq = 0.f;
    for (int r = r0; r < r1; ++r) {
        float val = ldf(&x[(size_t)r * xs + c]);
        ls += val;
        lq += val * val;
    }
    atomicAdd(&bnsum[c], ls);
    atomicAdd(&bnsumsq[c], lq);
}

// ---------- BN apply (strided input, compact [.,256] output) ----------
template<typename TX, typename TO>
__global__ __launch_bounds__(256)
void bn_apply_kernel(const TX* __restrict__ x, int xs, const float* __restrict__ bnsum,
                     const float* __restrict__ bnsumsq, const float* __restrict__ g,
                     const float* __restrict__ be, const bf16* __restrict__ add,
                     TO* __restrict__ y, float invM, size_t total)
{
    size_t idx = (size_t)blockIdx.x * blockDim.x + threadIdx.x;
    if (idx >= total) return;
    int c = (int)(idx & 255);
    size_t r = idx >> 8;
    float mu  = bnsum[c] * invM;
    float var = bnsumsq[c] * invM - mu * mu;
    float val = (ldf(&x[r * xs + c]) - mu) * rsqrtf(var + 1e-5f) * g[c] + be[c];
    if (add) val += ldf(&add[idx]);
    stf(&y[idx], val);
}

// ---------- pooling ----------
__global__ __launch_bounds__(256)
void pool_kernel(const bf16* __restrict__ h, const int* __restrict__ ibatch,
                 float* __restrict__ out)
{
    int g = blockIdx.x;
    __shared__ int bounds[2];
    if (threadIdx.x == 0) {
        int lo = 0, hi = N_NODES;
        while (lo < hi) { int mid = (lo + hi) >> 1; if (ibatch[mid] < g) lo = mid + 1; else hi = mid; }
        bounds[0] = lo;
        int lo2 = lo, hi2 = N_NODES;
        while (lo2 < hi2) { int mid = (lo2 + hi2) >> 1; if (ibatch[mid] < g + 1) lo2 = mid + 1; else hi2 = mid; }
        bounds[1] = lo2;
    }
    __syncthreads();
    int lo = bounds[0], hi = bounds[1];
    int c = threadIdx.x;
    float s = 0.f;
    for (int r = lo; r < hi; ++r) s += ldf(&h[(size_t)r * OUT_C + c]);
    out[(size_t)g * OUT_C + c] = s / fmaxf((float)(hi - lo), 1.f);
}

extern "C" void kernel_launch(void* const* d_in, const int* in_sizes, int n_in,
                              void* d_out, int out_size, void* d_ws, size_t ws_size,
                              hipStream_t stream)
{
    const float* drug_x  = (const float*)d_in[0];
    const int*   adj     = (const int*)  d_in[1];
    const int*   ibatch  = (const int*)  d_in[2];
    const float* cline_x = (const float*)d_in[3];
    const float* Wq1 = (const float*)d_in[4];  const float* bq1 = (const float*)d_in[5];
    const float* Wk1 = (const float*)d_in[6];  const float* bk1 = (const float*)d_in[7];
    const float* Wv1 = (const float*)d_in[8];  const float* bv1 = (const float*)d_in[9];
    const float* g1  = (const float*)d_in[10]; const float* be1 = (const float*)d_in[11];
    const float* Wq2 = (const float*)d_in[12]; const float* bq2 = (const float*)d_in[13];
    const float* Wk2 = (const float*)d_in[14]; const float* bk2 = (const float*)d_in[15];
    const float* Wv2 = (const float*)d_in[16]; const float* bv2 = (const float*)d_in[17];
    const float* g2  = (const float*)d_in[18]; const float* be2 = (const float*)d_in[19];
    const float* Wc1 = (const float*)d_in[20]; const float* bc1 = (const float*)d_in[21];
    const float* gc  = (const float*)d_in[22]; const float* bec = (const float*)d_in[23];
    const float* Wc2 = (const float*)d_in[24]; const float* bc2 = (const float*)d_in[25];

    const int* srcp = adj;
    const int* dstp = adj + N_EDGES;

    // ---- workspace arena (~216 MB) ----
    char* p = (char*)d_ws;
    auto take = [&p](size_t bytes) {
        char* r = p;
        p += (bytes + 15) & ~(size_t)15;
        return r;
    };
    bf16*  qk    = (bf16*)take((size_t)N_NODES * 512 * sizeof(bf16)); // q|k; L2 attn out in q-half; later cline bufs
    bf16*  conv  = (bf16*)take((size_t)N_NODES * OUT_C * sizeof(bf16)); // v (both layers); final h
    bf16*  h1    = (bf16*)take((size_t)N_NODES * OUT_C * sizeof(bf16)); // drug_xb -> L1 attn out -> h1 (in place)
    int*   rowptr= (int*)take((size_t)(N_NODES + 1) * sizeof(int));
    int*   degcur= (int*)take((size_t)N_NODES * sizeof(int));
    int*   bsum  = (int*)take(256 * sizeof(int));
    int*   bsume = (int*)take(256 * sizeof(int));
    int*   esrc  = (int*)take((size_t)N_EDGES * sizeof(int));
    float* bnsum = (float*)take(256 * sizeof(float));
    float* bnsumsq=(float*)take(256 * sizeof(float));
    bf16*  Wt1qk = (bf16*)take((size_t)512 * 128 * sizeof(bf16));
    bf16*  Wt1v  = (bf16*)take((size_t)256 * 128 * sizeof(bf16));
    bf16*  Wt2qk = (bf16*)take((size_t)512 * 256 * sizeof(bf16));
    bf16*  Wt2v  = (bf16*)take((size_t)256 * 256 * sizeof(bf16));
    bf16*  Wtc1  = (bf16*)take((size_t)256 * 960 * sizeof(bf16));
    bf16*  Wtc2  = (bf16*)take((size_t)256 * 256 * sizeof(bf16));
    float* bias_qk1 = (float*)take(512 * sizeof(float));
    float* bias_qk2 = (float*)take(512 * sizeof(float));
    size_t needed = (size_t)(p - (char*)d_ws);
    if (ws_size < needed) return;

    // aliases (lifetime-disjoint):
    bf16* drug_xb = h1;                       // [N,128] bf16, dead before L1 attn writes
    bf16* cline_xb = qk;                      // [2048,960] bf16, after qk dead
    float* c1  = (float*)(qk + (size_t)2048 * 960);          // 2 MB
    bf16*  cbn = (bf16*)(c1 + (size_t)B_CL * OUT_C);         // 1 MB

    float* out_pool = (float*)d_out;                      // [G,256]
    float* out_c    = out_pool + (size_t)N_GRAPH * OUT_C; // [B,256]

    const int MT = (N_NODES + 127) / 128;   // 782
    dim3 gN_qk(4, MT), gN_v(2, MT);          // x = ntile
    dim3 gB(2, 16);
    const int nodeBlocks = (N_NODES + 3) / 4;
    const size_t nTot = (size_t)N_NODES * OUT_C;

    // ===================== prep =====================
    convert_a_kernel<<<(N_NODES * 128 + 255) / 256, 256, 0, stream>>>(
        drug_x, drug_xb, DRUG_DIM, 128, N_NODES * 128);
    WtJobs jobs = {{
        { Wq1, Wt1qk, DRUG_DIM,   0, 128 },
        { Wk1, Wt1qk, DRUG_DIM, 256, 128 },
        { Wv1, Wt1v,  DRUG_DIM,   0, 128 },
        { Wq2, Wt2qk, 256,         0, 256 },
        { Wk2, Wt2qk, 256,       256, 256 },
        { Wv2, Wt2v,  256,         0, 256 },
        { Wc1, Wtc1,  CLINE_DIM,   0, 960 },
        { Wc2, Wtc2,  256,         0, 256 },
    }};
    convert_wt8_kernel<<<dim3(256, 8), 256, 0, stream>>>(jobs);
    concat_bias_kernel<<<2, 256, 0, stream>>>(bq1, bk1, bias_qk1);
    concat_bias_kernel<<<2, 256, 0, stream>>>(bq2, bk2, bias_qk2);

    // ===================== CSR build =====================
    hipMemsetAsync(degcur, 0, N_NODES * sizeof(int), stream);
    hist_kernel<<<(N_EDGES + 255) / 256, 256, 0, stream>>>(dstp, degcur, N_EDGES);
    const int NB1 = (N_NODES + 1023) / 1024;
    scan1_kernel<<<NB1, 256, 0, stream>>>(degcur, rowptr, bsum, N_NODES);
    scan2_kernel<<<1, 256, 0, stream>>>(bsum, bsume, NB1);
    scan3_kernel<<<(N_NODES + 255) / 256, 256, 0, stream>>>(rowptr, degcur, bsume, N_NODES, N_EDGES);
    scatter_kernel<<<(N_EDGES + 255) / 256, 256, 0, stream>>>(srcp, dstp, degcur, esrc, N_EDGES);

    // ===================== drug layer 1 =====================
    mfma_gemm_kernel<0, bf16><<<gN_qk, 256, 0, stream>>>(
        drug_xb, Wt1qk, bias_qk1, nullptr, qk, N_NODES, 128, 512);
    mfma_gemm_kernel<0, bf16><<<gN_v, 256, 0, stream>>>(
        drug_xb, Wt1v, bv1, nullptr, conv, N_NODES, 128, 256);
    // attn out -> compact [N,256] into h1 slot (drug_xb dead now)
    attn_fused_kernel<<<nodeBlocks, 256, 0, stream>>>(rowptr, esrc, qk, conv, h1, 256, N_NODES);
    hipMemsetAsync(bnsum, 0, 512 * sizeof(float), stream);
    col_stats_kernel<bf16><<<(N_NODES + 63) / 64, 256, 0, stream>>>(h1, 256, bnsum, bnsumsq, N_NODES);
    bn_apply_kernel<bf16, bf16><<<(nTot + 255) / 256, 256, 0, stream>>>(
        h1, 256, bnsum, bnsumsq, g1, be1, nullptr, h1, 1.0f / N_NODES, nTot);   // in place

    // ===================== drug layer 2 =====================
    mfma_gemm_kernel<0, bf16><<<gN_qk, 256, 0, stream>>>(
        h1, Wt2qk, bias_qk2, nullptr, qk, N_NODES, 256, 512);
    mfma_gemm_kernel<0, bf16><<<gN_v, 256, 0, stream>>>(
        h1, Wt2v, bv2, nullptr, conv, N_NODES, 256, 256);
    // attn out -> in-place q-half (h1 is live residual, conv holds v)
    attn_fused_kernel<<<nodeBlocks, 256, 0, stream>>>(rowptr, esrc, qk, conv, qk, 512, N_NODES);
    hipMemsetAsync(bnsum, 0, 512 * sizeof(float), stream);
    col_stats_kernel<bf16><<<(N_NODES + 63) / 64, 256, 0, stream>>>(qk, 512, bnsum, bnsumsq, N_NODES);
    // final h = h1 + bn2(attn-out), compact into conv (v2 dead)
    bn_apply_kernel<bf16, bf16><<<(nTot + 255) / 256, 256, 0, stream>>>(
        qk, 512, bnsum, bnsumsq, g2, be2, h1, conv, 1.0f / N_NODES, nTot);

    // ===================== pooling =====================
    pool_kernel<<<N_GRAPH, 256, 0, stream>>>(conv, ibatch, out_pool);

    // ===================== cline branch (qk region now dead) =====================
    convert_a_kernel<<<(B_CL * 960 + 255) / 256, 256, 0, stream>>>(
        cline_x, cline_xb, CLINE_DIM, 960, B_CL * 960);
    mfma_gemm_kernel<1, float><<<gB, 256, 0, stream>>>(
        cline_xb, Wtc1, bc1, nullptr, c1, B_CL, 960, 256);
    hipMemsetAsync(bnsum, 0, 512 * sizeof(float), stream);
    col_stats_kernel<float><<<(B_CL + 63) / 64, 256, 0, stream>>>(c1, 256, bnsum, bnsumsq, B_CL);
    bn_apply_kernel<float, bf16><<<((size_t)B_CL * OUT_C + 255) / 256, 256, 0, stream>>>(
        c1, 256, bnsum, bnsumsq, gc, bec, nullptr, cbn, 1.0f / B_CL, (size_t)B_CL * OUT_C);
    mfma_gemm_kernel<2, float><<<gB, 256, 0, stream>>>(
        cbn, Wtc2, bc2, c1, out_c, B_CL, 256, 256);
}

// Round 9
// 726.691 us; speedup vs baseline: 3.6186x; 1.0298x over previous
//
#include <hip/hip_runtime.h>
#include <hip/hip_bf16.h>

// Problem constants (match reference)
static constexpr int N_NODES  = 100000;
static constexpr int N_EDGES  = 400000;
static constexpr int DRUG_DIM = 75;
static constexpr int OUT_C    = 256;   // OUT
static constexpr int N_GRAPH  = 2048;  // G
static constexpr int B_CL     = 2048;  // B
static constexpr int CLINE_DIM= 954;

using bf16 = __hip_bfloat16;
using short8 = __attribute__((ext_vector_type(8))) short;
using f32x4  = __attribute__((ext_vector_type(4))) float;

template<class A, class B> struct is_same_t { static constexpr bool v = false; };
template<class A> struct is_same_t<A, A>   { static constexpr bool v = true;  };

// ---------- load/store helpers ----------
__device__ __forceinline__ float ldf(const float* p) { return *p; }
__device__ __forceinline__ float ldf(const bf16* p)  { return __bfloat162float(*p); }
__device__ __forceinline__ void  stf(float* p, float v) { *p = v; }
__device__ __forceinline__ void  stf(bf16* p, float v)  { *p = __float2bfloat16(v); }
__device__ __forceinline__ float bfu(unsigned short u) { return __uint_as_float(((unsigned)u) << 16); }
__device__ __forceinline__ unsigned short f2bu(float f) {
    bf16 h = __float2bfloat16(f);
    return *reinterpret_cast<unsigned short*>(&h);
}

// async global -> LDS, 16B per lane; LDS dest = uniform base + lane*16
__device__ __forceinline__ void gload_lds16(const void* g, void* l) {
    __builtin_amdgcn_global_load_lds(
        (const __attribute__((address_space(1))) void*)g,
        (__attribute__((address_space(3))) void*)l, 16, 0, 0);
}

// ================= input/weight prep =================
__global__ __launch_bounds__(256)
void convert_a_kernel(const float* __restrict__ A, bf16* __restrict__ Ab,
                      int K, int Kpad, int total)
{
    int idx = blockIdx.x * 256 + threadIdx.x;
    if (idx >= total) return;
    int r = idx / Kpad, k = idx - r * Kpad;
    float f = (k < K) ? A[(size_t)r * K + k] : 0.f;
    Ab[idx] = __float2bfloat16(f);
}

// all weight transposes in one launch; NW is always 256
struct WtJob  { const float* W; bf16* Wt; int K; int n0; int Kpad; };
struct WtJobs { WtJob j[8]; };
__global__ __launch_bounds__(256)
void convert_wt8_kernel(WtJobs jobs)
{
    WtJob jb = jobs.j[blockIdx.y];
    int n = blockIdx.x;
    for (int k = threadIdx.x; k < jb.Kpad; k += 256) {
        float f = (k < jb.K) ? jb.W[(size_t)k * 256 + n] : 0.f;
        jb.Wt[(size_t)(jb.n0 + n) * jb.Kpad + k] = __float2bfloat16(f);
    }
}

__global__ __launch_bounds__(256)
void concat3_kernel(const float* __restrict__ a, const float* __restrict__ b,
                    const float* __restrict__ c, float* __restrict__ out)
{
    int i = blockIdx.x * 256 + threadIdx.x;
    if (i < 256)      out[i] = a[i];
    else if (i < 512) out[i] = b[i - 256];
    else if (i < 768) out[i] = c[i - 512];
}

// ================= MFMA GEMM (single-buffer global_load_lds) =================
// C[M x NC] = act(A[M x K] @ Wt^T + bias) (+res). A bf16 [M][K], K mult of 64,
// M mult of 8, NC mult of 128. Tile 128x128, BK=64, 4 waves (2x2).
// LDS relation: LDS[row][y] = data[row][y ^ ((row&7)<<3)] via pre-swizzled
// global source element (LDS dest stays linear).
// bf16-output epilogue: per-wave LDS bounce -> short8 (16B/lane) stores.
template<int ACT, typename TO>
__global__ __launch_bounds__(256)
void mfma_gemm_kernel(const bf16* __restrict__ A, const bf16* __restrict__ Wt,
                      const float* __restrict__ bias, const bf16* __restrict__ res,
                      TO* __restrict__ C, int M, int K, int NC)
{
    __shared__ alignas(16) short As[128 * 64];
    __shared__ alignas(16) short Bs[128 * 64];
    const int ntile = blockIdx.x, mtile = blockIdx.y;
    const int tid = threadIdx.x;
    const int lane = tid & 63, wid = tid >> 6;
    const int wr = wid >> 1, wc = wid & 1;

    f32x4 acc[4][4] = {};

    for (int k0 = 0; k0 < K; k0 += 64) {
        #pragma unroll
        for (int i = 0; i < 4; ++i) {
            const int chunk = i * 4 + wid;            // wave-uniform
            const int row   = chunk * 8 + (lane >> 3);
            const int e     = ((lane & 7) ^ (row & 7)) << 3;  // pre-swizzled src elem
            if (mtile * 128 + chunk * 8 + 8 <= M)     // wave-uniform guard (M % 8 == 0)
                gload_lds16(A + (size_t)(mtile * 128 + row) * K + k0 + e,
                            &As[chunk * 512]);
            gload_lds16(Wt + (size_t)(ntile * 128 + row) * K + k0 + e,
                        &Bs[chunk * 512]);
        }
        __syncthreads();   // drains vmcnt(0): LDS tiles ready
        #pragma unroll
        for (int kk = 0; kk < 2; ++kk) {
            const int coff = (kk * 32 + (lane >> 4) * 8) ^ ((lane & 7) << 3);
            short8 a[4], b[4];
            #pragma unroll
            for (int m = 0; m < 4; ++m)
                a[m] = *reinterpret_cast<const short8*>(
                    &As[(wr * 64 + m * 16 + (lane & 15)) * 64 + coff]);
            #pragma unroll
            for (int n = 0; n < 4; ++n)
                b[n] = *reinterpret_cast<const short8*>(
                    &Bs[(wc * 64 + n * 16 + (lane & 15)) * 64 + coff]);
            #pragma unroll
            for (int m = 0; m < 4; ++m)
                #pragma unroll
                for (int n = 0; n < 4; ++n)
                    acc[m][n] = __builtin_amdgcn_mfma_f32_16x16x32_bf16(
                        a[m], b[n], acc[m][n], 0, 0, 0);
        }
        __syncthreads();
    }

    // epilogue: C/D layout col=lane&15, row=(lane>>4)*4+reg
    if constexpr (is_same_t<TO, bf16>::v) {
        // per-wave private 8KB bounce region in the (now dead) As/Bs
        short* eb = (wid < 2 ? As : Bs) + (wid & 1) * 4096;
        #pragma unroll
        for (int m = 0; m < 4; ++m)
            #pragma unroll
            for (int n = 0; n < 4; ++n) {
                int col_l = n * 16 + (lane & 15);
                float bcol = bias[ntile * 128 + wc * 64 + col_l];
                #pragma unroll
                for (int r = 0; r < 4; ++r) {
                    int row_l = m * 16 + ((lane >> 4) << 2) + r;
                    float val = acc[m][n][r] + bcol;
                    if (ACT == 1) val = tanhf(val);
                    if (ACT == 2) val = fmaxf(val, 0.f);
                    eb[row_l * 64 + (col_l ^ ((row_l & 7) << 3))] = (short)f2bu(val);
                }
            }
        // read back coalesced: 8 lanes per row, 16B per lane
        #pragma unroll
        for (int i = 0; i < 8; ++i) {
            int row_l = i * 8 + (lane >> 3);
            int row_g = mtile * 128 + wr * 64 + row_l;
            short8 vr = *reinterpret_cast<const short8*>(
                &eb[row_l * 64 + ((((lane & 7) << 3)) ^ ((row_l & 7) << 3))]);
            if (row_g < M)
                *reinterpret_cast<short8*>(
                    &C[(size_t)row_g * NC + ntile * 128 + wc * 64 + ((lane & 7) << 3)]) = vr;
        }
    } else {
        #pragma unroll
        for (int m = 0; m < 4; ++m) {
            int row0 = mtile * 128 + wr * 64 + m * 16 + ((lane >> 4) << 2);
            #pragma unroll
            for (int n = 0; n < 4; ++n) {
                int col = ntile * 128 + wc * 64 + n * 16 + (lane & 15);
                float bcol = bias[col];
                #pragma unroll
                for (int r = 0; r < 4; ++r) {
                    int row = row0 + r;
                    if (row < M) {
                        float val = acc[m][n][r] + bcol;
                        if (ACT == 1) val = tanhf(val);
                        if (ACT == 2) val = fmaxf(val, 0.f);
                        if (res) val += ldf(&res[(size_t)row * NC + col]);
                        stf(&C[(size_t)row * NC + col], val);
                    }
                }
            }
        }
    }
}

// ================= CSR build =================
__global__ __launch_bounds__(256)
void hist_kernel(const int* __restrict__ dst, int* __restrict__ deg, int E)
{
    int e = blockIdx.x * 256 + threadIdx.x;
    if (e < E) atomicAdd(&deg[dst[e]], 1);
}

__global__ __launch_bounds__(256)
void scan1_kernel(const int* __restrict__ deg, int* __restrict__ part,
                  int* __restrict__ bsum, int n)
{
    __shared__ int sh[256];
    const int t = threadIdx.x;
    const int b0 = blockIdx.x * 1024;
    int v[4]; int s = 0;
    #pragma unroll
    for (int j = 0; j < 4; ++j) {
        int idx = b0 + t * 4 + j;
        v[j] = (idx < n) ? deg[idx] : 0;
        s += v[j];
    }
    sh[t] = s; __syncthreads();
    for (int off = 1; off < 256; off <<= 1) {
        int x = (t >= off) ? sh[t - off] : 0;
        __syncthreads();
        sh[t] += x;
        __syncthreads();
    }
    if (t == 255) bsum[blockIdx.x] = sh[255];
    int run = sh[t] - s;
    #pragma unroll
    for (int j = 0; j < 4; ++j) {
        int idx = b0 + t * 4 + j;
        if (idx < n) part[idx] = run;
        run += v[j];
    }
}

__global__ __launch_bounds__(256)
void scan2_kernel(const int* __restrict__ bsum, int* __restrict__ bsume, int nb)
{
    __shared__ int sh[256];
    const int t = threadIdx.x;
    int x0 = (t < nb) ? bsum[t] : 0;
    sh[t] = x0; __syncthreads();
    for (int off = 1; off < 256; off <<= 1) {
        int x = (t >= off) ? sh[t - off] : 0;
        __syncthreads();
        sh[t] += x;
        __syncthreads();
    }
    if (t < nb) bsume[t] = sh[t] - x0;
}

__global__ __launch_bounds__(256)
void scan3_kernel(int* __restrict__ rowptr, int* __restrict__ cursor,
                  const int* __restrict__ bsume, int n, int E)
{
    int idx = blockIdx.x * 256 + threadIdx.x;
    if (idx < n) {
        int val = rowptr[idx] + bsume[idx >> 10];
        rowptr[idx] = val;
        cursor[idx] = val;
    }
    if (idx == 0) rowptr[n] = E;
}

__global__ __launch_bounds__(256)
void scatter_kernel(const int* __restrict__ src, const int* __restrict__ dst,
                    int* __restrict__ cursor, int* __restrict__ esrc, int E)
{
    int e = blockIdx.x * 256 + threadIdx.x;
    if (e < E) {
        int slot = atomicAdd(&cursor[dst[e]], 1);
        esrc[slot] = src[e];
    }
}

// ================= fused flash-style attention (CSR gather) =================
// wave per dst node. qkv: [N,768] rows (q | k | v), rs = 768.
// out: [N, os] (out==qkv row start -> in-place q-part overwrite; or compact 256).
__global__ __launch_bounds__(256)
void attn_fused_kernel(const int* __restrict__ rowptr, const int* __restrict__ esrc,
                       const bf16* __restrict__ qkv, bf16* __restrict__ out,
                       int os, int n)
{
    int node = blockIdx.x * 4 + (threadIdx.x >> 6);
    if (node >= n) return;
    int lane = threadIdx.x & 63;
    int lo = rowptr[node], hi = rowptr[node + 1];

    ushort4 qu = ((const ushort4*)(qkv + (size_t)node * 768))[lane];
    float q0 = bfu(qu.x), q1 = bfu(qu.y), q2 = bfu(qu.z), q3 = bfu(qu.w);

    float m = -INFINITY, s = 0.f;
    float a0 = 0.f, a1 = 0.f, a2 = 0.f, a3 = 0.f;
    for (int i = lo; i < hi; ++i) {
        int sn = esrc[i];
        const bf16* row = qkv + (size_t)sn * 768;
        ushort4 ku = ((const ushort4*)(row + 256))[lane];
        ushort4 vu = ((const ushort4*)(row + 512))[lane];
        float p = q0 * bfu(ku.x);
        p = fmaf(q1, bfu(ku.y), p);
        p = fmaf(q2, bfu(ku.z), p);
        p = fmaf(q3, bfu(ku.w), p);
        p += __shfl_xor(p, 1);
        p += __shfl_xor(p, 2);
        p += __shfl_xor(p, 4);
        p += __shfl_xor(p, 8);       // 16-lane group sum -> per-head dot
        float l = p * 0.125f;        // 1/sqrt(64)
        float mn = fmaxf(m, l);
        float sc = __expf(m - mn);
        float e  = __expf(l - mn);
        a0 = fmaf(a0, sc, e * bfu(vu.x));
        a1 = fmaf(a1, sc, e * bfu(vu.y));
        a2 = fmaf(a2, sc, e * bfu(vu.z));
        a3 = fmaf(a3, sc, e * bfu(vu.w));
        s  = s * sc + e;
        m  = mn;
    }
    float inv = 1.f / (s + 1e-16f);
    ushort4 o;
    o.x = f2bu(fmaxf(a0 * inv, 0.f));
    o.y = f2bu(fmaxf(a1 * inv, 0.f));
    o.z = f2bu(fmaxf(a2 * inv, 0.f));
    o.w = f2bu(fmaxf(a3 * inv, 0.f));
    ((ushort4*)(out + (size_t)node * os))[lane] = o;
}

// ---------- per-channel BN stats (strided input) ----------
template<typename TX>
__global__ __launch_bounds__(256)
void col_stats_kernel(const TX* __restrict__ x, int xs, float* __restrict__ bnsum,
                      float* __restrict__ bnsumsq, int M)
{
    const int c = threadIdx.x;
    const int r0 = blockIdx.x * 64;
    const int r1 = min(r0 + 64, M);
    float ls = 0.f, lq = 0.f;
    for (int r = r0; r < r1; ++r) {
        float val = ldf(&x[(size_t)r * xs + c]);
        ls += val;
        lq += val * val;
    }
    atomicAdd(&bnsum[c], ls);
    atomicAdd(&bnsumsq[c], lq);
}

// ---------- BN apply (strided in/out) ----------
template<typename TX, typename TO>
__global__ __launch_bounds__(256)
void bn_apply_kernel(const TX* __restrict__ x, int xs, const float* __restrict__ bnsum,
                     const float* __restrict__ bnsumsq, const float* __restrict__ g,
                     const float* __restrict__ be, const bf16* __restrict__ add,
                     TO* __restrict__ y, int ys, float invM, size_t total)
{
    size_t idx = (size_t)blockIdx.x * blockDim.x + threadIdx.x;
    if (idx >= total) return;
    int c = (int)(idx & 255);
    size_t r = idx >> 8;
    float mu  = bnsum[c] * invM;
    float var = bnsumsq[c] * invM - mu * mu;
    float val = (ldf(&x[r * xs + c]) - mu) * rsqrtf(var + 1e-5f) * g[c] + be[c];
    if (add) val += ldf(&add[idx]);
    stf(&y[r * ys + c], val);
}

// ---------- cline BN fold: Wc2'[n][k] = Wc2[n][k]*scale[k]; bc2'[n] = bc2[n]+sum shift[k]*W ----------
__global__ __launch_bounds__(256)
void bn_fold_kernel(const bf16* __restrict__ Wt, const float* __restrict__ b,
                    const float* __restrict__ bnsum, const float* __restrict__ bnsumsq,
                    const float* __restrict__ g, const float* __restrict__ be,
                    bf16* __restrict__ Wtf, float* __restrict__ bf, float invM)
{
    __shared__ float sh[256];
    const int n = blockIdx.x, k = threadIdx.x;
    float mu  = bnsum[k] * invM;
    float var = bnsumsq[k] * invM - mu * mu;
    float scale = g[k] * rsqrtf(var + 1e-5f);
    float shift = be[k] - mu * scale;
    float w = ldf(&Wt[(size_t)n * 256 + k]);
    Wtf[(size_t)n * 256 + k] = __float2bfloat16(w * scale);
    sh[k] = shift * w;
    __syncthreads();
    for (int off = 128; off; off >>= 1) {
        if (k < off) sh[k] += sh[k + off];
        __syncthreads();
    }
    if (k == 0) bf[n] = b[n] + sh[0];
}

// ---------- pooling (strided) ----------
__global__ __launch_bounds__(256)
void pool_kernel(const bf16* __restrict__ h, int xs, const int* __restrict__ ibatch,
                 float* __restrict__ out)
{
    int g = blockIdx.x;
    __shared__ int bounds[2];
    if (threadIdx.x == 0) {
        int lo = 0, hi = N_NODES;
        while (lo < hi) { int mid = (lo + hi) >> 1; if (ibatch[mid] < g) lo = mid + 1; else hi = mid; }
        bounds[0] = lo;
        int lo2 = lo, hi2 = N_NODES;
        while (lo2 < hi2) { int mid = (lo2 + hi2) >> 1; if (ibatch[mid] < g + 1) lo2 = mid + 1; else hi2 = mid; }
        bounds[1] = lo2;
    }
    __syncthreads();
    int lo = bounds[0], hi = bounds[1];
    int c = threadIdx.x;
    float s = 0.f;
    for (int r = lo; r < hi; ++r) s += ldf(&h[(size_t)r * xs + c]);
    out[(size_t)g * OUT_C + c] = s / fmaxf((float)(hi - lo), 1.f);
}

extern "C" void kernel_launch(void* const* d_in, const int* in_sizes, int n_in,
                              void* d_out, int out_size, void* d_ws, size_t ws_size,
                              hipStream_t stream)
{
    const float* drug_x  = (const float*)d_in[0];
    const int*   adj     = (const int*)  d_in[1];
    const int*   ibatch  = (const int*)  d_in[2];
    const float* cline_x = (const float*)d_in[3];
    const float* Wq1 = (const float*)d_in[4];  const float* bq1 = (const float*)d_in[5];
    const float* Wk1 = (const float*)d_in[6];  const float* bk1 = (const float*)d_in[7];
    const float* Wv1 = (const float*)d_in[8];  const float* bv1 = (const float*)d_in[9];
    const float* g1  = (const float*)d_in[10]; const float* be1 = (const float*)d_in[11];
    const float* Wq2 = (const float*)d_in[12]; const float* bq2 = (const float*)d_in[13];
    const float* Wk2 = (const float*)d_in[14]; const float* bk2 = (const float*)d_in[15];
    const float* Wv2 = (const float*)d_in[16]; const float* bv2 = (const float*)d_in[17];
    const float* g2  = (const float*)d_in[18]; const float* be2 = (const float*)d_in[19];
    const float* Wc1 = (const float*)d_in[20]; const float* bc1 = (const float*)d_in[21];
    const float* gc  = (const float*)d_in[22]; const float* bec = (const float*)d_in[23];
    const float* Wc2 = (const float*)d_in[24]; const float* bc2 = (const float*)d_in[25];

    const int* srcp = adj;
    const int* dstp = adj + N_EDGES;

    // ---- workspace arena (~209 MB) ----
    char* p = (char*)d_ws;
    auto take = [&p](size_t bytes) {
        char* r = p;
        p += (bytes + 15) & ~(size_t)15;
        return r;
    };
    bf16*  qkv   = (bf16*)take((size_t)N_NODES * 768 * sizeof(bf16)); // q|k|v; L2 out in q; final h in v
    bf16*  h1    = (bf16*)take((size_t)N_NODES * OUT_C * sizeof(bf16)); // drug_xb -> L1 attn out -> h1
    int*   rowptr= (int*)take((size_t)(N_NODES + 1) * sizeof(int));
    int*   degcur= (int*)take((size_t)N_NODES * sizeof(int));
    int*   bsum  = (int*)take(256 * sizeof(int));
    int*   bsume = (int*)take(256 * sizeof(int));
    int*   esrc  = (int*)take((size_t)N_EDGES * sizeof(int));
    float* bnsum = (float*)take(256 * sizeof(float));
    float* bnsumsq=(float*)take(256 * sizeof(float));
    bf16*  Wt1   = (bf16*)take((size_t)768 * 128 * sizeof(bf16));
    bf16*  Wt2   = (bf16*)take((size_t)768 * 256 * sizeof(bf16));
    bf16*  Wtc1  = (bf16*)take((size_t)256 * 960 * sizeof(bf16));
    bf16*  Wtc2  = (bf16*)take((size_t)256 * 256 * sizeof(bf16));
    bf16*  Wtc2f = (bf16*)take((size_t)256 * 256 * sizeof(bf16));
    float* bc2f  = (float*)take(256 * sizeof(float));
    float* bias1 = (float*)take(768 * sizeof(float));
    float* bias2 = (float*)take(768 * sizeof(float));
    size_t needed = (size_t)(p - (char*)d_ws);
    if (ws_size < needed) return;

    // aliases (lifetime-disjoint):
    bf16* drug_xb  = h1;                      // [N,128] bf16, dead before L1 attn writes
    bf16* cline_xb = qkv;                     // [2048,960] bf16 (qkv dead after pool)
    bf16* c1b      = qkv + (size_t)2048 * 960; // [2048,256] bf16 tanh output

    float* out_pool = (float*)d_out;                      // [G,256]
    float* out_c    = out_pool + (size_t)N_GRAPH * OUT_C; // [B,256]

    const int MT = (N_NODES + 127) / 128;   // 782
    dim3 gN(6, MT);                          // x = ntile (768/128)
    dim3 gB1(2, 16), gB2(2, 16);
    const int nodeBlocks = (N_NODES + 3) / 4;
    const size_t nTot = (size_t)N_NODES * OUT_C;

    // ===================== prep =====================
    convert_a_kernel<<<(N_NODES * 128 + 255) / 256, 256, 0, stream>>>(
        drug_x, drug_xb, DRUG_DIM, 128, N_NODES * 128);
    WtJobs jobs = {{
        { Wq1, Wt1, DRUG_DIM,   0, 128 },
        { Wk1, Wt1, DRUG_DIM, 256, 128 },
        { Wv1, Wt1, DRUG_DIM, 512, 128 },
        { Wq2, Wt2, 256,        0, 256 },
        { Wk2, Wt2, 256,      256, 256 },
        { Wv2, Wt2, 256,      512, 256 },
        { Wc1, Wtc1, CLINE_DIM, 0, 960 },
        { Wc2, Wtc2, 256,       0, 256 },
    }};
    convert_wt8_kernel<<<dim3(256, 8), 256, 0, stream>>>(jobs);
    concat3_kernel<<<3, 256, 0, stream>>>(bq1, bk1, bv1, bias1);
    concat3_kernel<<<3, 256, 0, stream>>>(bq2, bk2, bv2, bias2);

    // ===================== CSR build =====================
    hipMemsetAsync(degcur, 0, N_NODES * sizeof(int), stream);
    hist_kernel<<<(N_EDGES + 255) / 256, 256, 0, stream>>>(dstp, degcur, N_EDGES);
    const int NB1 = (N_NODES + 1023) / 1024;
    scan1_kernel<<<NB1, 256, 0, stream>>>(degcur, rowptr, bsum, N_NODES);
    scan2_kernel<<<1, 256, 0, stream>>>(bsum, bsume, NB1);
    scan3_kernel<<<(N_NODES + 255) / 256, 256, 0, stream>>>(rowptr, degcur, bsume, N_NODES, N_EDGES);
    scatter_kernel<<<(N_EDGES + 255) / 256, 256, 0, stream>>>(srcp, dstp, degcur, esrc, N_EDGES);

    // ===================== drug layer 1 =====================
    mfma_gemm_kernel<0, bf16><<<gN, 256, 0, stream>>>(
        drug_xb, Wt1, bias1, nullptr, qkv, N_NODES, 128, 768);
    // attn out -> compact [N,256] into h1 slot (drug_xb dead now)
    attn_fused_kernel<<<nodeBlocks, 256, 0, stream>>>(rowptr, esrc, qkv, h1, 256, N_NODES);
    hipMemsetAsync(bnsum, 0, 512 * sizeof(float), stream);
    col_stats_kernel<bf16><<<(N_NODES + 63) / 64, 256, 0, stream>>>(h1, 256, bnsum, bnsumsq, N_NODES);
    bn_apply_kernel<bf16, bf16><<<(nTot + 255) / 256, 256, 0, stream>>>(
        h1, 256, bnsum, bnsumsq, g1, be1, nullptr, h1, 256, 1.0f / N_NODES, nTot);   // in place

    // ===================== drug layer 2 =====================
    mfma_gemm_kernel<0, bf16><<<gN, 256, 0, stream>>>(
        h1, Wt2, bias2, nullptr, qkv, N_NODES, 256, 768);
    // attn out -> in-place q-part (h1 live residual)
    attn_fused_kernel<<<nodeBlocks, 256, 0, stream>>>(rowptr, esrc, qkv, qkv, 768, N_NODES);
    hipMemsetAsync(bnsum, 0, 512 * sizeof(float), stream);
    col_stats_kernel<bf16><<<(N_NODES + 63) / 64, 256, 0, stream>>>(qkv, 768, bnsum, bnsumsq, N_NODES);
    // final h = h1 + bn2(attn-out) -> v-part of qkv (dead)
    bn_apply_kernel<bf16, bf16><<<(nTot + 255) / 256, 256, 0, stream>>>(
        qkv, 768, bnsum, bnsumsq, g2, be2, h1, qkv + 512, 768, 1.0f / N_NODES, nTot);

    // ===================== pooling =====================
    pool_kernel<<<N_GRAPH, 256, 0, stream>>>(qkv + 512, 768, ibatch, out_pool);

    // ===================== cline branch (qkv region now dead) =====================
    convert_a_kernel<<<(B_CL * 960 + 255) / 256, 256, 0, stream>>>(
        cline_x, cline_xb, CLINE_DIM, 960, B_CL * 960);
    mfma_gemm_kernel<1, bf16><<<gB1, 256, 0, stream>>>(
        cline_xb, Wtc1, bc1, nullptr, c1b, B_CL, 960, 256);        // tanh, bf16
    hipMemsetAsync(bnsum, 0, 512 * sizeof(float), stream);
    col_stats_kernel<bf16><<<(B_CL + 63) / 64, 256, 0, stream>>>(c1b, 256, bnsum, bnsumsq, B_CL);
    bn_fold_kernel<<<256, 256, 0, stream>>>(Wtc2, bc2, bnsum, bnsumsq, gc, bec,
                                            Wtc2f, bc2f, 1.0f / B_CL);
    // out_c = c1 + relu(c1 @ Wc2f^T + bc2f)
    mfma_gemm_kernel<2, float><<<gB2, 256, 0, stream>>>(
        c1b, Wtc2f, bc2f, c1b, out_c, B_CL, 256, 256);
}

// Round 10
// 669.730 us; speedup vs baseline: 3.9263x; 1.0851x over previous
//
#include <hip/hip_runtime.h>
#include <hip/hip_bf16.h>

// Problem constants (match reference)
static constexpr int N_NODES  = 100000;
static constexpr int N_EDGES  = 400000;
static constexpr int DRUG_DIM = 75;
static constexpr int OUT_C    = 256;   // OUT
static constexpr int N_GRAPH  = 2048;  // G
static constexpr int B_CL     = 2048;  // B
static constexpr int CLINE_DIM= 954;

using bf16 = __hip_bfloat16;
using short8 = __attribute__((ext_vector_type(8))) short;
using f32x4  = __attribute__((ext_vector_type(4))) float;

template<class A, class B> struct is_same_t { static constexpr bool v = false; };
template<class A> struct is_same_t<A, A>   { static constexpr bool v = true;  };

// ---------- load/store helpers ----------
__device__ __forceinline__ float ldf(const float* p) { return *p; }
__device__ __forceinline__ float ldf(const bf16* p)  { return __bfloat162float(*p); }
__device__ __forceinline__ void  stf(float* p, float v) { *p = v; }
__device__ __forceinline__ void  stf(bf16* p, float v)  { *p = __float2bfloat16(v); }
__device__ __forceinline__ float bfu(unsigned short u) { return __uint_as_float(((unsigned)u) << 16); }
__device__ __forceinline__ unsigned short f2bu(float f) {
    bf16 h = __float2bfloat16(f);
    return *reinterpret_cast<unsigned short*>(&h);
}

// async global -> LDS, 16B per lane; LDS dest = uniform base + lane*16
__device__ __forceinline__ void gload_lds16(const void* g, void* l) {
    __builtin_amdgcn_global_load_lds(
        (const __attribute__((address_space(1))) void*)g,
        (__attribute__((address_space(3))) void*)l, 16, 0, 0);
}

// ================= input/weight prep =================
__global__ __launch_bounds__(256)
void convert_a_kernel(const float* __restrict__ A, bf16* __restrict__ Ab,
                      int K, int Kpad, int total)
{
    int idx = blockIdx.x * 256 + threadIdx.x;
    if (idx >= total) return;
    int r = idx / Kpad, k = idx - r * Kpad;
    float f = (k < K) ? A[(size_t)r * K + k] : 0.f;
    Ab[idx] = __float2bfloat16(f);
}

// all weight transposes in one launch; NW is always 256
struct WtJob  { const float* W; bf16* Wt; int K; int n0; int Kpad; };
struct WtJobs { WtJob j[8]; };
__global__ __launch_bounds__(256)
void convert_wt8_kernel(WtJobs jobs)
{
    WtJob jb = jobs.j[blockIdx.y];
    int n = blockIdx.x;
    for (int k = threadIdx.x; k < jb.Kpad; k += 256) {
        float f = (k < jb.K) ? jb.W[(size_t)k * 256 + n] : 0.f;
        jb.Wt[(size_t)(jb.n0 + n) * jb.Kpad + k] = __float2bfloat16(f);
    }
}

__global__ __launch_bounds__(256)
void concat3_kernel(const float* __restrict__ a, const float* __restrict__ b,
                    const float* __restrict__ c, float* __restrict__ out)
{
    int i = blockIdx.x * 256 + threadIdx.x;
    if (i < 256)      out[i] = a[i];
    else if (i < 512) out[i] = b[i - 256];
    else if (i < 768) out[i] = c[i - 512];
}

// ================= MFMA GEMM (single-buffer global_load_lds, 64x256 tile) =====
// C[M x NC] = act(A[M x K] @ Wt^T + bias) (+res). A bf16 [M][K], K mult of 64,
// M mult of 8, NC mult of 256. Tile 64x256, BK=64, 4 waves (1x4).
// LDS relation: LDS[row][y] = data[row][y ^ ((row&7)<<3)] via pre-swizzled
// global source element (LDS dest stays linear).
// bf16-output epilogue: per-wave LDS bounce (in Bs) -> short8 stores.
template<int ACT, typename TO>
__global__ __launch_bounds__(256)
void mfma_gemm_kernel(const bf16* __restrict__ A, const bf16* __restrict__ Wt,
                      const float* __restrict__ bias, const bf16* __restrict__ res,
                      TO* __restrict__ C, int M, int K, int NC)
{
    __shared__ alignas(16) short As[64 * 64];    // 8 KB
    __shared__ alignas(16) short Bs[256 * 64];   // 32 KB
    const int ntile = blockIdx.x, mtile = blockIdx.y;
    const int tid = threadIdx.x;
    const int lane = tid & 63, wid = tid >> 6;   // wave col = wid (0..3)

    f32x4 acc[4][4] = {};

    for (int k0 = 0; k0 < K; k0 += 64) {
        // 40 staging issues (A: 8 chunks of 8 rows, B: 32 chunks), 10 per wave
        #pragma unroll
        for (int i = 0; i < 10; ++i) {
            const int ci = wid * 10 + i;               // wave-uniform
            if (ci < 8) {
                const int row = ci * 8 + (lane >> 3);
                const int e   = ((lane & 7) ^ (row & 7)) << 3;
                if (mtile * 64 + ci * 8 + 8 <= M)      // wave-uniform guard (M%8==0)
                    gload_lds16(A + (size_t)(mtile * 64 + row) * K + k0 + e,
                                &As[ci * 512]);
            } else {
                const int cb  = ci - 8;
                const int row = cb * 8 + (lane >> 3);
                const int e   = ((lane & 7) ^ (row & 7)) << 3;
                gload_lds16(Wt + (size_t)(ntile * 256 + row) * K + k0 + e,
                            &Bs[cb * 512]);
            }
        }
        __syncthreads();   // drains vmcnt(0): LDS tiles ready
        #pragma unroll
        for (int kk = 0; kk < 2; ++kk) {
            const int coff = (kk * 32 + (lane >> 4) * 8) ^ ((lane & 7) << 3);
            short8 a[4], b[4];
            #pragma unroll
            for (int m = 0; m < 4; ++m)
                a[m] = *reinterpret_cast<const short8*>(
                    &As[(m * 16 + (lane & 15)) * 64 + coff]);
            #pragma unroll
            for (int n = 0; n < 4; ++n)
                b[n] = *reinterpret_cast<const short8*>(
                    &Bs[(wid * 64 + n * 16 + (lane & 15)) * 64 + coff]);
            #pragma unroll
            for (int m = 0; m < 4; ++m)
                #pragma unroll
                for (int n = 0; n < 4; ++n)
                    acc[m][n] = __builtin_amdgcn_mfma_f32_16x16x32_bf16(
                        a[m], b[n], acc[m][n], 0, 0, 0);
        }
        __syncthreads();
    }

    // epilogue: C/D layout col=lane&15, row=(lane>>4)*4+reg
    if constexpr (is_same_t<TO, bf16>::v) {
        // per-wave private 8KB bounce region in the (now dead) Bs
        short* eb = Bs + wid * 4096;
        #pragma unroll
        for (int m = 0; m < 4; ++m)
            #pragma unroll
            for (int n = 0; n < 4; ++n) {
                int col_l = n * 16 + (lane & 15);
                float bcol = bias[ntile * 256 + wid * 64 + col_l];
                #pragma unroll
                for (int r = 0; r < 4; ++r) {
                    int row_l = m * 16 + ((lane >> 4) << 2) + r;
                    float val = acc[m][n][r] + bcol;
                    if (ACT == 1) val = tanhf(val);
                    if (ACT == 2) val = fmaxf(val, 0.f);
                    eb[row_l * 64 + (col_l ^ ((row_l & 7) << 3))] = (short)f2bu(val);
                }
            }
        // read back coalesced: 8 lanes per row, 16B per lane (wave-private, no barrier)
        #pragma unroll
        for (int i = 0; i < 8; ++i) {
            int row_l = i * 8 + (lane >> 3);
            int row_g = mtile * 64 + row_l;
            short8 vr = *reinterpret_cast<const short8*>(
                &eb[row_l * 64 + ((((lane & 7) << 3)) ^ ((row_l & 7) << 3))]);
            if (row_g < M)
                *reinterpret_cast<short8*>(
                    &C[(size_t)row_g * NC + ntile * 256 + wid * 64 + ((lane & 7) << 3)]) = vr;
        }
    } else {
        #pragma unroll
        for (int m = 0; m < 4; ++m) {
            int row0 = mtile * 64 + m * 16 + ((lane >> 4) << 2);
            #pragma unroll
            for (int n = 0; n < 4; ++n) {
                int col = ntile * 256 + wid * 64 + n * 16 + (lane & 15);
                float bcol = bias[col];
                #pragma unroll
                for (int r = 0; r < 4; ++r) {
                    int row = row0 + r;
                    if (row < M) {
                        float val = acc[m][n][r] + bcol;
                        if (ACT == 1) val = tanhf(val);
                        if (ACT == 2) val = fmaxf(val, 0.f);
                        if (res) val += ldf(&res[(size_t)row * NC + col]);
                        stf(&C[(size_t)row * NC + col], val);
                    }
                }
            }
        }
    }
}

// ================= CSR build =================
__global__ __launch_bounds__(256)
void hist_kernel(const int* __restrict__ dst, int* __restrict__ deg, int E)
{
    int e = blockIdx.x * 256 + threadIdx.x;
    if (e < E) atomicAdd(&deg[dst[e]], 1);
}

__global__ __launch_bounds__(256)
void scan1_kernel(const int* __restrict__ deg, int* __restrict__ part,
                  int* __restrict__ bsum, int n)
{
    __shared__ int sh[256];
    const int t = threadIdx.x;
    const int b0 = blockIdx.x * 1024;
    int v[4]; int s = 0;
    #pragma unroll
    for (int j = 0; j < 4; ++j) {
        int idx = b0 + t * 4 + j;
        v[j] = (idx < n) ? deg[idx] : 0;
        s += v[j];
    }
    sh[t] = s; __syncthreads();
    for (int off = 1; off < 256; off <<= 1) {
        int x = (t >= off) ? sh[t - off] : 0;
        __syncthreads();
        sh[t] += x;
        __syncthreads();
    }
    if (t == 255) bsum[blockIdx.x] = sh[255];
    int run = sh[t] - s;
    #pragma unroll
    for (int j = 0; j < 4; ++j) {
        int idx = b0 + t * 4 + j;
        if (idx < n) part[idx] = run;
        run += v[j];
    }
}

__global__ __launch_bounds__(256)
void scan2_kernel(const int* __restrict__ bsum, int* __restrict__ bsume, int nb)
{
    __shared__ int sh[256];
    const int t = threadIdx.x;
    int x0 = (t < nb) ? bsum[t] : 0;
    sh[t] = x0; __syncthreads();
    for (int off = 1; off < 256; off <<= 1) {
        int x = (t >= off) ? sh[t - off] : 0;
        __syncthreads();
        sh[t] += x;
        __syncthreads();
    }
    if (t < nb) bsume[t] = sh[t] - x0;
}

__global__ __launch_bounds__(256)
void scan3_kernel(int* __restrict__ rowptr, int* __restrict__ cursor,
                  const int* __restrict__ bsume, int n, int E)
{
    int idx = blockIdx.x * 256 + threadIdx.x;
    if (idx < n) {
        int val = rowptr[idx] + bsume[idx >> 10];
        rowptr[idx] = val;
        cursor[idx] = val;
    }
    if (idx == 0) rowptr[n] = E;
}

__global__ __launch_bounds__(256)
void scatter_kernel(const int* __restrict__ src, const int* __restrict__ dst,
                    int* __restrict__ cursor, int* __restrict__ esrc, int E)
{
    int e = blockIdx.x * 256 + threadIdx.x;
    if (e < E) {
        int slot = atomicAdd(&cursor[dst[e]], 1);
        esrc[slot] = src[e];
    }
}

// ================= fused flash-style attention (CSR gather) =================
// wave per dst node. qkv: [N,768] rows (q | k | v).
// out: [N, os] (out==qkv -> in-place q-part overwrite; or compact 256).
__global__ __launch_bounds__(256)
void attn_fused_kernel(const int* __restrict__ rowptr, const int* __restrict__ esrc,
                       const bf16* __restrict__ qkv, bf16* __restrict__ out,
                       int os, int n)
{
    int node = blockIdx.x * 4 + (threadIdx.x >> 6);
    if (node >= n) return;
    int lane = threadIdx.x & 63;
    int lo = rowptr[node], hi = rowptr[node + 1];

    ushort4 qu = ((const ushort4*)(qkv + (size_t)node * 768))[lane];
    float q0 = bfu(qu.x), q1 = bfu(qu.y), q2 = bfu(qu.z), q3 = bfu(qu.w);

    float m = -INFINITY, s = 0.f;
    float a0 = 0.f, a1 = 0.f, a2 = 0.f, a3 = 0.f;
    for (int i = lo; i < hi; ++i) {
        int sn = esrc[i];
        const bf16* row = qkv + (size_t)sn * 768;
        ushort4 ku = ((const ushort4*)(row + 256))[lane];
        ushort4 vu = ((const ushort4*)(row + 512))[lane];
        float p = q0 * bfu(ku.x);
        p = fmaf(q1, bfu(ku.y), p);
        p = fmaf(q2, bfu(ku.z), p);
        p = fmaf(q3, bfu(ku.w), p);
        p += __shfl_xor(p, 1);
        p += __shfl_xor(p, 2);
        p += __shfl_xor(p, 4);
        p += __shfl_xor(p, 8);       // 16-lane group sum -> per-head dot
        float l = p * 0.125f;        // 1/sqrt(64)
        float mn = fmaxf(m, l);
        float sc = __expf(m - mn);
        float e  = __expf(l - mn);
        a0 = fmaf(a0, sc, e * bfu(vu.x));
        a1 = fmaf(a1, sc, e * bfu(vu.y));
        a2 = fmaf(a2, sc, e * bfu(vu.z));
        a3 = fmaf(a3, sc, e * bfu(vu.w));
        s  = s * sc + e;
        m  = mn;
    }
    float inv = 1.f / (s + 1e-16f);
    ushort4 o;
    o.x = f2bu(fmaxf(a0 * inv, 0.f));
    o.y = f2bu(fmaxf(a1 * inv, 0.f));
    o.z = f2bu(fmaxf(a2 * inv, 0.f));
    o.w = f2bu(fmaxf(a3 * inv, 0.f));
    ((ushort4*)(out + (size_t)node * os))[lane] = o;
}

// ---------- per-channel BN stats (strided input) ----------
template<typename TX>
__global__ __launch_bounds__(256)
void col_stats_kernel(const TX* __restrict__ x, int xs, float* __restrict__ bnsum,
                      float* __restrict__ bnsumsq, int M)
{
    const int c = threadIdx.x;
    const int r0 = blockIdx.x * 64;
    const int r1 = min(r0 + 64, M);
    float ls = 0.f, lq = 0.f;
    for (int r = r0; r < r1; ++r) {
        float val = ldf(&x[(size_t)r * xs + c]);
        ls += val;
        lq += val * val;
    }
    atomicAdd(&bnsum[c], ls);
    atomicAdd(&bnsumsq[c], lq);
}

// ---------- BN fold into following weights: Wt[n][k] *= scale[k] (in place),
// bout[n] = bin[n] + sum_k shift[k]*W; optionally export scale/shift ----------
__global__ __launch_bounds__(256)
void bn_fold_kernel(bf16* __restrict__ Wt, const float* __restrict__ bin,
                    float* __restrict__ bout,
                    const float* __restrict__ bnsum, const float* __restrict__ bnsumsq,
                    const float* __restrict__ g, const float* __restrict__ be,
                    float* __restrict__ s_out, float* __restrict__ t_out, float invM)
{
    __shared__ float sh[256];
    const int n = blockIdx.x, k = threadIdx.x;
    float mu  = bnsum[k] * invM;
    float var = bnsumsq[k] * invM - mu * mu;
    float scale = g[k] * rsqrtf(var + 1e-5f);
    float shift = be[k] - mu * scale;
    float w = ldf(&Wt[(size_t)n * 256 + k]);
    Wt[(size_t)n * 256 + k] = __float2bfloat16(w * scale);
    sh[k] = shift * w;
    __syncthreads();
    for (int off = 128; off; off >>= 1) {
        if (k < off) sh[k] += sh[k + off];
        __syncthreads();
    }
    if (k == 0) bout[n] = bin[n] + sh[0];
    if (s_out && n == 0) { s_out[k] = scale; t_out[k] = shift; }
}

// ---------- final: y = bn2(x) + (s1*res + t1)  (strided in/out) ----------
__global__ __launch_bounds__(256)
void bn_final_kernel(const bf16* __restrict__ x, int xs,
                     const float* __restrict__ bnsum, const float* __restrict__ bnsumsq,
                     const float* __restrict__ g, const float* __restrict__ be,
                     const bf16* __restrict__ res, const float* __restrict__ s1,
                     const float* __restrict__ t1,
                     bf16* __restrict__ y, int ys, float invM, size_t total)
{
    size_t idx = (size_t)blockIdx.x * blockDim.x + threadIdx.x;
    if (idx >= total) return;
    int c = (int)(idx & 255);
    size_t r = idx >> 8;
    float mu  = bnsum[c] * invM;
    float var = bnsumsq[c] * invM - mu * mu;
    float val = (ldf(&x[r * xs + c]) - mu) * rsqrtf(var + 1e-5f) * g[c] + be[c];
    val += s1[c] * ldf(&res[r * 256 + c]) + t1[c];
    stf(&y[r * ys + c], val);
}

// ---------- pooling (strided) ----------
__global__ __launch_bounds__(256)
void pool_kernel(const bf16* __restrict__ h, int xs, const int* __restrict__ ibatch,
                 float* __restrict__ out)
{
    int g = blockIdx.x;
    __shared__ int bounds[2];
    if (threadIdx.x == 0) {
        int lo = 0, hi = N_NODES;
        while (lo < hi) { int mid = (lo + hi) >> 1; if (ibatch[mid] < g) lo = mid + 1; else hi = mid; }
        bounds[0] = lo;
        int lo2 = lo, hi2 = N_NODES;
        while (lo2 < hi2) { int mid = (lo2 + hi2) >> 1; if (ibatch[mid] < g + 1) lo2 = mid + 1; else hi2 = mid; }
        bounds[1] = lo2;
    }
    __syncthreads();
    int lo = bounds[0], hi = bounds[1];
    int c = threadIdx.x;
    float s = 0.f;
    for (int r = lo; r < hi; ++r) s += ldf(&h[(size_t)r * xs + c]);
    out[(size_t)g * OUT_C + c] = s / fmaxf((float)(hi - lo), 1.f);
}

extern "C" void kernel_launch(void* const* d_in, const int* in_sizes, int n_in,
                              void* d_out, int out_size, void* d_ws, size_t ws_size,
                              hipStream_t stream)
{
    const float* drug_x  = (const float*)d_in[0];
    const int*   adj     = (const int*)  d_in[1];
    const int*   ibatch  = (const int*)  d_in[2];
    const float* cline_x = (const float*)d_in[3];
    const float* Wq1 = (const float*)d_in[4];  const float* bq1 = (const float*)d_in[5];
    const float* Wk1 = (const float*)d_in[6];  const float* bk1 = (const float*)d_in[7];
    const float* Wv1 = (const float*)d_in[8];  const float* bv1 = (const float*)d_in[9];
    const float* g1  = (const float*)d_in[10]; const float* be1 = (const float*)d_in[11];
    const float* Wq2 = (const float*)d_in[12]; const float* bq2 = (const float*)d_in[13];
    const float* Wk2 = (const float*)d_in[14]; const float* bk2 = (const float*)d_in[15];
    const float* Wv2 = (const float*)d_in[16]; const float* bv2 = (const float*)d_in[17];
    const float* g2  = (const float*)d_in[18]; const float* be2 = (const float*)d_in[19];
    const float* Wc1 = (const float*)d_in[20]; const float* bc1 = (const float*)d_in[21];
    const float* gc  = (const float*)d_in[22]; const float* bec = (const float*)d_in[23];
    const float* Wc2 = (const float*)d_in[24]; const float* bc2 = (const float*)d_in[25];

    const int* srcp = adj;
    const int* dstp = adj + N_EDGES;

    // ---- workspace arena (~209 MB) ----
    char* p = (char*)d_ws;
    auto take = [&p](size_t bytes) {
        char* r = p;
        p += (bytes + 15) & ~(size_t)15;
        return r;
    };
    bf16*  qkv   = (bf16*)take((size_t)N_NODES * 768 * sizeof(bf16)); // q|k|v; L2 out in q; final h in v
    bf16*  h1    = (bf16*)take((size_t)N_NODES * OUT_C * sizeof(bf16)); // drug_xb -> attnout1
    int*   rowptr= (int*)take((size_t)(N_NODES + 1) * sizeof(int));
    int*   degcur= (int*)take((size_t)N_NODES * sizeof(int));
    int*   bsum  = (int*)take(256 * sizeof(int));
    int*   bsume = (int*)take(256 * sizeof(int));
    int*   esrc  = (int*)take((size_t)N_EDGES * sizeof(int));
    float* bnsum = (float*)take(256 * sizeof(float));
    float* bnsumsq=(float*)take(256 * sizeof(float));
    float* s1buf = (float*)take(256 * sizeof(float));
    float* t1buf = (float*)take(256 * sizeof(float));
    bf16*  Wt1   = (bf16*)take((size_t)768 * 128 * sizeof(bf16));
    bf16*  Wt2   = (bf16*)take((size_t)768 * 256 * sizeof(bf16));
    bf16*  Wtc1  = (bf16*)take((size_t)256 * 960 * sizeof(bf16));
    bf16*  Wtc2  = (bf16*)take((size_t)256 * 256 * sizeof(bf16));
    float* bc2f  = (float*)take(256 * sizeof(float));
    float* bias1 = (float*)take(768 * sizeof(float));
    float* bias2 = (float*)take(768 * sizeof(float));
    size_t needed = (size_t)(p - (char*)d_ws);
    if (ws_size < needed) return;

    // aliases (lifetime-disjoint):
    bf16* drug_xb  = h1;                      // [N,128] bf16, dead before L1 attn writes
    bf16* cline_xb = qkv;                     // [2048,960] bf16 (qkv dead after pool)
    bf16* c1b      = qkv + (size_t)2048 * 960; // [2048,256] bf16 tanh output

    float* out_pool = (float*)d_out;                      // [G,256]
    float* out_c    = out_pool + (size_t)N_GRAPH * OUT_C; // [B,256]

    dim3 gN(3, (N_NODES + 63) / 64);         // x = ntile (768/256)
    dim3 gB(1, B_CL / 64);
    const int nodeBlocks = (N_NODES + 3) / 4;
    const size_t nTot = (size_t)N_NODES * OUT_C;

    // ===================== prep =====================
    convert_a_kernel<<<(N_NODES * 128 + 255) / 256, 256, 0, stream>>>(
        drug_x, drug_xb, DRUG_DIM, 128, N_NODES * 128);
    WtJobs jobs = {{
        { Wq1, Wt1, DRUG_DIM,   0, 128 },
        { Wk1, Wt1, DRUG_DIM, 256, 128 },
        { Wv1, Wt1, DRUG_DIM, 512, 128 },
        { Wq2, Wt2, 256,        0, 256 },
        { Wk2, Wt2, 256,      256, 256 },
        { Wv2, Wt2, 256,      512, 256 },
        { Wc1, Wtc1, CLINE_DIM, 0, 960 },
        { Wc2, Wtc2, 256,       0, 256 },
    }};
    convert_wt8_kernel<<<dim3(256, 8), 256, 0, stream>>>(jobs);
    concat3_kernel<<<3, 256, 0, stream>>>(bq1, bk1, bv1, bias1);
    concat3_kernel<<<3, 256, 0, stream>>>(bq2, bk2, bv2, bias2);

    // ===================== CSR build =====================
    hipMemsetAsync(degcur, 0, N_NODES * sizeof(int), stream);
    hist_kernel<<<(N_EDGES + 255) / 256, 256, 0, stream>>>(dstp, degcur, N_EDGES);
    const int NB1 = (N_NODES + 1023) / 1024;
    scan1_kernel<<<NB1, 256, 0, stream>>>(degcur, rowptr, bsum, N_NODES);
    scan2_kernel<<<1, 256, 0, stream>>>(bsum, bsume, NB1);
    scan3_kernel<<<(N_NODES + 255) / 256, 256, 0, stream>>>(rowptr, degcur, bsume, N_NODES, N_EDGES);
    scatter_kernel<<<(N_EDGES + 255) / 256, 256, 0, stream>>>(srcp, dstp, degcur, esrc, N_EDGES);

    // ===================== drug layer 1 =====================
    mfma_gemm_kernel<0, bf16><<<gN, 256, 0, stream>>>(
        drug_xb, Wt1, bias1, nullptr, qkv, N_NODES, 128, 768);
    // attnout1 (relu'd) -> compact [N,256] into h1 slot (drug_xb dead now)
    attn_fused_kernel<<<nodeBlocks, 256, 0, stream>>>(rowptr, esrc, qkv, h1, 256, N_NODES);
    hipMemsetAsync(bnsum, 0, 512 * sizeof(float), stream);
    col_stats_kernel<bf16><<<(N_NODES + 63) / 64, 256, 0, stream>>>(h1, 256, bnsum, bnsumsq, N_NODES);
    // fold BN1 into Wt2/bias2 (in place), export s1/t1 for the residual path
    bn_fold_kernel<<<768, 256, 0, stream>>>(Wt2, bias2, bias2, bnsum, bnsumsq,
                                            g1, be1, s1buf, t1buf, 1.0f / N_NODES);

    // ===================== drug layer 2 =====================
    mfma_gemm_kernel<0, bf16><<<gN, 256, 0, stream>>>(
        h1, Wt2, bias2, nullptr, qkv, N_NODES, 256, 768);
    // attnout2 -> in-place q-part
    attn_fused_kernel<<<nodeBlocks, 256, 0, stream>>>(rowptr, esrc, qkv, qkv, 768, N_NODES);
    hipMemsetAsync(bnsum, 0, 512 * sizeof(float), stream);
    col_stats_kernel<bf16><<<(N_NODES + 63) / 64, 256, 0, stream>>>(qkv, 768, bnsum, bnsumsq, N_NODES);
    // final h = (s1*attnout1 + t1) + bn2(attnout2) -> v-part of qkv (dead)
    bn_final_kernel<<<(nTot + 255) / 256, 256, 0, stream>>>(
        qkv, 768, bnsum, bnsumsq, g2, be2, h1, s1buf, t1buf,
        qkv + 512, 768, 1.0f / N_NODES, nTot);

    // ===================== pooling =====================
    pool_kernel<<<N_GRAPH, 256, 0, stream>>>(qkv + 512, 768, ibatch, out_pool);

    // ===================== cline branch (qkv region now dead) =====================
    convert_a_kernel<<<(B_CL * 960 + 255) / 256, 256, 0, stream>>>(
        cline_x, cline_xb, CLINE_DIM, 960, B_CL * 960);
    mfma_gemm_kernel<1, bf16><<<gB, 256, 0, stream>>>(
        cline_xb, Wtc1, bc1, nullptr, c1b, B_CL, 960, 256);        // tanh, bf16
    hipMemsetAsync(bnsum, 0, 512 * sizeof(float), stream);
    col_stats_kernel<bf16><<<(B_CL + 63) / 64, 256, 0, stream>>>(c1b, 256, bnsum, bnsumsq, B_CL);
    bn_fold_kernel<<<256, 256, 0, stream>>>(Wtc2, bc2, bc2f, bnsum, bnsumsq,
                                            gc, bec, nullptr, nullptr, 1.0f / B_CL);
    // out_c = c1 + relu(c1 @ Wc2f^T + bc2f)
    mfma_gemm_kernel<2, float><<<gB, 256, 0, stream>>>(
        c1b, Wtc2, bc2f, c1b, out_c, B_CL, 256, 256);
}

// Round 11
// 636.273 us; speedup vs baseline: 4.1328x; 1.0526x over previous
//
#include <hip/hip_runtime.h>
#include <hip/hip_bf16.h>

// Problem constants (match reference)
static constexpr int N_NODES  = 100000;
static constexpr int N_EDGES  = 400000;
static constexpr int DRUG_DIM = 75;
static constexpr int OUT_C    = 256;   // OUT
static constexpr int N_GRAPH  = 2048;  // G
static constexpr int B_CL     = 2048;  // B
static constexpr int CLINE_DIM= 954;

using bf16 = __hip_bfloat16;
using short8 = __attribute__((ext_vector_type(8))) short;
using f32x4  = __attribute__((ext_vector_type(4))) float;

template<class A, class B> struct is_same_t { static constexpr bool v = false; };
template<class A> struct is_same_t<A, A>   { static constexpr bool v = true;  };

// ---------- load/store helpers ----------
__device__ __forceinline__ float ldf(const float* p) { return *p; }
__device__ __forceinline__ float ldf(const bf16* p)  { return __bfloat162float(*p); }
__device__ __forceinline__ void  stf(float* p, float v) { *p = v; }
__device__ __forceinline__ void  stf(bf16* p, float v)  { *p = __float2bfloat16(v); }
__device__ __forceinline__ float bfu(unsigned short u) { return __uint_as_float(((unsigned)u) << 16); }
__device__ __forceinline__ unsigned short f2bu(float f) {
    bf16 h = __float2bfloat16(f);
    return *reinterpret_cast<unsigned short*>(&h);
}

// async global -> LDS, 16B per lane; LDS dest = uniform base + lane*16
__device__ __forceinline__ void gload_lds16(const void* g, void* l) {
    __builtin_amdgcn_global_load_lds(
        (const __attribute__((address_space(1))) void*)g,
        (__attribute__((address_space(3))) void*)l, 16, 0, 0);
}

// ================= input/weight prep =================
__global__ __launch_bounds__(256)
void convert_a_kernel(const float* __restrict__ A, bf16* __restrict__ Ab,
                      int K, int Kpad, int total)
{
    int idx = blockIdx.x * 256 + threadIdx.x;
    if (idx >= total) return;
    int r = idx / Kpad, k = idx - r * Kpad;
    float f = (k < K) ? A[(size_t)r * K + k] : 0.f;
    Ab[idx] = __float2bfloat16(f);
}

// all weight transposes in one launch; NW is always 256
struct WtJob  { const float* W; bf16* Wt; int K; int n0; int Kpad; };
struct WtJobs { WtJob j[8]; };
__global__ __launch_bounds__(256)
void convert_wt8_kernel(WtJobs jobs)
{
    WtJob jb = jobs.j[blockIdx.y];
    int n = blockIdx.x;
    for (int k = threadIdx.x; k < jb.Kpad; k += 256) {
        float f = (k < jb.K) ? jb.W[(size_t)k * 256 + n] : 0.f;
        jb.Wt[(size_t)(jb.n0 + n) * jb.Kpad + k] = __float2bfloat16(f);
    }
}

__global__ __launch_bounds__(256)
void concat3_kernel(const float* __restrict__ a, const float* __restrict__ b,
                    const float* __restrict__ c, float* __restrict__ out)
{
    int i = blockIdx.x * 256 + threadIdx.x;
    if (i < 256)      out[i] = a[i];
    else if (i < 512) out[i] = b[i - 256];
    else if (i < 768) out[i] = c[i - 512];
}

// ================= MFMA GEMM (single-buffer global_load_lds, 64x256 tile) =====
// Plane-split output: column slab [ntile*256, ntile*256+256) is written to
// plane `ntile` of C as a compact [M,256] array: C + ntile*PS + row*256 + col.
// A bf16 [M][K], K mult of 64, M mult of 8. Tile 64x256, BK=64, 4 waves (1x4).
// LDS relation: LDS[row][y] = data[row][y ^ ((row&7)<<3)] via pre-swizzled
// global source element (LDS dest stays linear).
template<int ACT, typename TO>
__global__ __launch_bounds__(256)
void mfma_gemm_kernel(const bf16* __restrict__ A, const bf16* __restrict__ Wt,
                      const float* __restrict__ bias, const bf16* __restrict__ res,
                      TO* __restrict__ C, int M, int K, size_t PS)
{
    __shared__ alignas(16) short As[64 * 64];    // 8 KB
    __shared__ alignas(16) short Bs[256 * 64];   // 32 KB
    const int ntile = blockIdx.x, mtile = blockIdx.y;
    const int tid = threadIdx.x;
    const int lane = tid & 63, wid = tid >> 6;   // wave col = wid (0..3)

    f32x4 acc[4][4] = {};

    for (int k0 = 0; k0 < K; k0 += 64) {
        // 40 staging issues (A: 8 chunks of 8 rows, B: 32 chunks), 10 per wave
        #pragma unroll
        for (int i = 0; i < 10; ++i) {
            const int ci = wid * 10 + i;               // wave-uniform
            if (ci < 8) {
                const int row = ci * 8 + (lane >> 3);
                const int e   = ((lane & 7) ^ (row & 7)) << 3;
                if (mtile * 64 + ci * 8 + 8 <= M)      // wave-uniform guard (M%8==0)
                    gload_lds16(A + (size_t)(mtile * 64 + row) * K + k0 + e,
                                &As[ci * 512]);
            } else {
                const int cb  = ci - 8;
                const int row = cb * 8 + (lane >> 3);
                const int e   = ((lane & 7) ^ (row & 7)) << 3;
                gload_lds16(Wt + (size_t)(ntile * 256 + row) * K + k0 + e,
                            &Bs[cb * 512]);
            }
        }
        __syncthreads();   // drains vmcnt(0): LDS tiles ready
        #pragma unroll
        for (int kk = 0; kk < 2; ++kk) {
            const int coff = (kk * 32 + (lane >> 4) * 8) ^ ((lane & 7) << 3);
            short8 a[4], b[4];
            #pragma unroll
            for (int m = 0; m < 4; ++m)
                a[m] = *reinterpret_cast<const short8*>(
                    &As[(m * 16 + (lane & 15)) * 64 + coff]);
            #pragma unroll
            for (int n = 0; n < 4; ++n)
                b[n] = *reinterpret_cast<const short8*>(
                    &Bs[(wid * 64 + n * 16 + (lane & 15)) * 64 + coff]);
            #pragma unroll
            for (int m = 0; m < 4; ++m)
                #pragma unroll
                for (int n = 0; n < 4; ++n)
                    acc[m][n] = __builtin_amdgcn_mfma_f32_16x16x32_bf16(
                        a[m], b[n], acc[m][n], 0, 0, 0);
        }
        __syncthreads();
    }

    // epilogue: C/D layout col=lane&15, row=(lane>>4)*4+reg
    TO* Cp = C + (size_t)ntile * PS;   // plane base (ntile==0 when single-plane)
    if constexpr (is_same_t<TO, bf16>::v) {
        // per-wave private 8KB bounce region in the (now dead) Bs
        short* eb = Bs + wid * 4096;
        #pragma unroll
        for (int m = 0; m < 4; ++m)
            #pragma unroll
            for (int n = 0; n < 4; ++n) {
                int col_l = n * 16 + (lane & 15);
                float bcol = bias[ntile * 256 + wid * 64 + col_l];
                #pragma unroll
                for (int r = 0; r < 4; ++r) {
                    int row_l = m * 16 + ((lane >> 4) << 2) + r;
                    float val = acc[m][n][r] + bcol;
                    if (ACT == 1) val = tanhf(val);
                    if (ACT == 2) val = fmaxf(val, 0.f);
                    eb[row_l * 64 + (col_l ^ ((row_l & 7) << 3))] = (short)f2bu(val);
                }
            }
        // read back coalesced: 8 lanes per row, 16B per lane (wave-private, no barrier)
        #pragma unroll
        for (int i = 0; i < 8; ++i) {
            int row_l = i * 8 + (lane >> 3);
            int row_g = mtile * 64 + row_l;
            short8 vr = *reinterpret_cast<const short8*>(
                &eb[row_l * 64 + ((((lane & 7) << 3)) ^ ((row_l & 7) << 3))]);
            if (row_g < M)
                *reinterpret_cast<short8*>(
                    &Cp[(size_t)row_g * 256 + wid * 64 + ((lane & 7) << 3)]) = vr;
        }
    } else {
        #pragma unroll
        for (int m = 0; m < 4; ++m) {
            int row0 = mtile * 64 + m * 16 + ((lane >> 4) << 2);
            #pragma unroll
            for (int n = 0; n < 4; ++n) {
                int col_l = wid * 64 + n * 16 + (lane & 15);
                float bcol = bias[ntile * 256 + col_l];
                #pragma unroll
                for (int r = 0; r < 4; ++r) {
                    int row = row0 + r;
                    if (row < M) {
                        float val = acc[m][n][r] + bcol;
                        if (ACT == 1) val = tanhf(val);
                        if (ACT == 2) val = fmaxf(val, 0.f);
                        if (res) val += ldf(&res[(size_t)row * 256 + col_l]);
                        stf(&Cp[(size_t)row * 256 + col_l], val);
                    }
                }
            }
        }
    }
}

// ================= CSR build =================
__global__ __launch_bounds__(256)
void hist_kernel(const int* __restrict__ dst, int* __restrict__ deg, int E)
{
    int e = blockIdx.x * 256 + threadIdx.x;
    if (e < E) atomicAdd(&deg[dst[e]], 1);
}

__global__ __launch_bounds__(256)
void scan1_kernel(const int* __restrict__ deg, int* __restrict__ part,
                  int* __restrict__ bsum, int n)
{
    __shared__ int sh[256];
    const int t = threadIdx.x;
    const int b0 = blockIdx.x * 1024;
    int v[4]; int s = 0;
    #pragma unroll
    for (int j = 0; j < 4; ++j) {
        int idx = b0 + t * 4 + j;
        v[j] = (idx < n) ? deg[idx] : 0;
        s += v[j];
    }
    sh[t] = s; __syncthreads();
    for (int off = 1; off < 256; off <<= 1) {
        int x = (t >= off) ? sh[t - off] : 0;
        __syncthreads();
        sh[t] += x;
        __syncthreads();
    }
    if (t == 255) bsum[blockIdx.x] = sh[255];
    int run = sh[t] - s;
    #pragma unroll
    for (int j = 0; j < 4; ++j) {
        int idx = b0 + t * 4 + j;
        if (idx < n) part[idx] = run;
        run += v[j];
    }
}

__global__ __launch_bounds__(256)
void scan2_kernel(const int* __restrict__ bsum, int* __restrict__ bsume, int nb)
{
    __shared__ int sh[256];
    const int t = threadIdx.x;
    int x0 = (t < nb) ? bsum[t] : 0;
    sh[t] = x0; __syncthreads();
    for (int off = 1; off < 256; off <<= 1) {
        int x = (t >= off) ? sh[t - off] : 0;
        __syncthreads();
        sh[t] += x;
        __syncthreads();
    }
    if (t < nb) bsume[t] = sh[t] - x0;
}

__global__ __launch_bounds__(256)
void scan3_kernel(int* __restrict__ rowptr, int* __restrict__ cursor,
                  const int* __restrict__ bsume, int n, int E)
{
    int idx = blockIdx.x * 256 + threadIdx.x;
    if (idx < n) {
        int val = rowptr[idx] + bsume[idx >> 10];
        rowptr[idx] = val;
        cursor[idx] = val;
    }
    if (idx == 0) rowptr[n] = E;
}

__global__ __launch_bounds__(256)
void scatter_kernel(const int* __restrict__ src, const int* __restrict__ dst,
                    int* __restrict__ cursor, int* __restrict__ esrc, int E)
{
    int e = blockIdx.x * 256 + threadIdx.x;
    if (e < E) {
        int slot = atomicAdd(&cursor[dst[e]], 1);
        esrc[slot] = src[e];
    }
}

// ================= fused flash-style attention (CSR gather, planes) ==========
// wave per dst node. q/k/v: compact [N,256] planes. out: [N,256] (out may == q:
// q[node] is read only by node's own wave before the write -> no race).
__global__ __launch_bounds__(256)
void attn_fused_kernel(const int* __restrict__ rowptr, const int* __restrict__ esrc,
                       const bf16* __restrict__ q, const bf16* __restrict__ k,
                       const bf16* __restrict__ v, bf16* __restrict__ out, int n)
{
    int node = blockIdx.x * 4 + (threadIdx.x >> 6);
    if (node >= n) return;
    int lane = threadIdx.x & 63;
    int lo = rowptr[node], hi = rowptr[node + 1];

    ushort4 qu = ((const ushort4*)(q + (size_t)node * 256))[lane];
    float q0 = bfu(qu.x), q1 = bfu(qu.y), q2 = bfu(qu.z), q3 = bfu(qu.w);

    float m = -INFINITY, s = 0.f;
    float a0 = 0.f, a1 = 0.f, a2 = 0.f, a3 = 0.f;
    for (int i = lo; i < hi; ++i) {
        int sn = esrc[i];
        ushort4 ku = ((const ushort4*)(k + (size_t)sn * 256))[lane];
        ushort4 vu = ((const ushort4*)(v + (size_t)sn * 256))[lane];
        float p = q0 * bfu(ku.x);
        p = fmaf(q1, bfu(ku.y), p);
        p = fmaf(q2, bfu(ku.z), p);
        p = fmaf(q3, bfu(ku.w), p);
        p += __shfl_xor(p, 1);
        p += __shfl_xor(p, 2);
        p += __shfl_xor(p, 4);
        p += __shfl_xor(p, 8);       // 16-lane group sum -> per-head dot
        float l = p * 0.125f;        // 1/sqrt(64)
        float mn = fmaxf(m, l);
        float sc = __expf(m - mn);
        float e  = __expf(l - mn);
        a0 = fmaf(a0, sc, e * bfu(vu.x));
        a1 = fmaf(a1, sc, e * bfu(vu.y));
        a2 = fmaf(a2, sc, e * bfu(vu.z));
        a3 = fmaf(a3, sc, e * bfu(vu.w));
        s  = s * sc + e;
        m  = mn;
    }
    float inv = 1.f / (s + 1e-16f);
    ushort4 o;
    o.x = f2bu(fmaxf(a0 * inv, 0.f));
    o.y = f2bu(fmaxf(a1 * inv, 0.f));
    o.z = f2bu(fmaxf(a2 * inv, 0.f));
    o.w = f2bu(fmaxf(a3 * inv, 0.f));
    ((ushort4*)(out + (size_t)node * 256))[lane] = o;
}

// ---------- per-channel BN stats (compact [M,256]) ----------
template<typename TX>
__global__ __launch_bounds__(256)
void col_stats_kernel(const TX* __restrict__ x, float* __restrict__ bnsum,
                      float* __restrict__ bnsumsq, int M)
{
    const int c = threadIdx.x;
    const int r0 = blockIdx.x * 64;
    const int r1 = min(r0 + 64, M);
    float ls = 0.f, lq = 0.f;
    for (int r = r0; r < r1; ++r) {
        float val = ldf(&x[(size_t)r * 256 + c]);
        ls += val;
        lq += val * val;
    }
    atomicAdd(&bnsum[c], ls);
    atomicAdd(&bnsumsq[c], lq);
}

// ---------- BN fold into following weights: Wt[n][k] *= scale[k] (in place),
// bout[n] = bin[n] + sum_k shift[k]*W; optionally export scale/shift ----------
__global__ __launch_bounds__(256)
void bn_fold_kernel(bf16* __restrict__ Wt, const float* __restrict__ bin,
                    float* __restrict__ bout,
                    const float* __restrict__ bnsum, const float* __restrict__ bnsumsq,
                    const float* __restrict__ g, const float* __restrict__ be,
                    float* __restrict__ s_out, float* __restrict__ t_out, float invM)
{
    __shared__ float sh[256];
    const int n = blockIdx.x, k = threadIdx.x;
    float mu  = bnsum[k] * invM;
    float var = bnsumsq[k] * invM - mu * mu;
    float scale = g[k] * rsqrtf(var + 1e-5f);
    float shift = be[k] - mu * scale;
    float w = ldf(&Wt[(size_t)n * 256 + k]);
    Wt[(size_t)n * 256 + k] = __float2bfloat16(w * scale);
    sh[k] = shift * w;
    __syncthreads();
    for (int off = 128; off; off >>= 1) {
        if (k < off) sh[k] += sh[k + off];
        __syncthreads();
    }
    if (k == 0) bout[n] = bin[n] + sh[0];
    if (s_out && n == 0) { s_out[k] = scale; t_out[k] = shift; }
}

// ---------- fused bn2 + residual + segment-mean pool ----------
// pooled[g][c] = cnt>0 ? (sc2*sum(a2) + s1*sum(h1))/cnt + sh2 + t1 : 0
// (per-channel affines commute with the segment mean). Deterministic.
__global__ __launch_bounds__(256)
void pool_bn_kernel(const bf16* __restrict__ a2, const bf16* __restrict__ h1,
                    const int* __restrict__ ibatch,
                    const float* __restrict__ bnsum, const float* __restrict__ bnsumsq,
                    const float* __restrict__ g2, const float* __restrict__ be2,
                    const float* __restrict__ s1, const float* __restrict__ t1,
                    float* __restrict__ out, float invM)
{
    int g = blockIdx.x;
    __shared__ int bounds[2];
    if (threadIdx.x == 0) {
        int lo = 0, hi = N_NODES;
        while (lo < hi) { int mid = (lo + hi) >> 1; if (ibatch[mid] < g) lo = mid + 1; else hi = mid; }
        bounds[0] = lo;
        int lo2 = lo, hi2 = N_NODES;
        while (lo2 < hi2) { int mid = (lo2 + hi2) >> 1; if (ibatch[mid] < g + 1) lo2 = mid + 1; else hi2 = mid; }
        bounds[1] = lo2;
    }
    __syncthreads();
    int lo = bounds[0], hi = bounds[1];
    int c = threadIdx.x;
    float sa = 0.f, sh = 0.f;
    for (int r = lo; r < hi; ++r) {
        sa += ldf(&a2[(size_t)r * 256 + c]);
        sh += ldf(&h1[(size_t)r * 256 + c]);
    }
    float mu  = bnsum[c] * invM;
    float var = bnsumsq[c] * invM - mu * mu;
    float sc2 = g2[c] * rsqrtf(var + 1e-5f);
    float sh2 = be2[c] - mu * sc2;
    int cnt = hi - lo;
    out[(size_t)g * 256 + c] =
        (cnt > 0) ? (sc2 * sa + s1[c] * sh) / cnt + sh2 + t1[c] : 0.f;
}

extern "C" void kernel_launch(void* const* d_in, const int* in_sizes, int n_in,
                              void* d_out, int out_size, void* d_ws, size_t ws_size,
                              hipStream_t stream)
{
    const float* drug_x  = (const float*)d_in[0];
    const int*   adj     = (const int*)  d_in[1];
    const int*   ibatch  = (const int*)  d_in[2];
    const float* cline_x = (const float*)d_in[3];
    const float* Wq1 = (const float*)d_in[4];  const float* bq1 = (const float*)d_in[5];
    const float* Wk1 = (const float*)d_in[6];  const float* bk1 = (const float*)d_in[7];
    const float* Wv1 = (const float*)d_in[8];  const float* bv1 = (const float*)d_in[9];
    const float* g1  = (const float*)d_in[10]; const float* be1 = (const float*)d_in[11];
    const float* Wq2 = (const float*)d_in[12]; const float* bq2 = (const float*)d_in[13];
    const float* Wk2 = (const float*)d_in[14]; const float* bk2 = (const float*)d_in[15];
    const float* Wv2 = (const float*)d_in[16]; const float* bv2 = (const float*)d_in[17];
    const float* g2  = (const float*)d_in[18]; const float* be2 = (const float*)d_in[19];
    const float* Wc1 = (const float*)d_in[20]; const float* bc1 = (const float*)d_in[21];
    const float* gc  = (const float*)d_in[22]; const float* bec = (const float*)d_in[23];
    const float* Wc2 = (const float*)d_in[24]; const float* bc2 = (const float*)d_in[25];

    const int* srcp = adj;
    const int* dstp = adj + N_EDGES;

    // ---- workspace arena (~209 MB) ----
    char* p = (char*)d_ws;
    auto take = [&p](size_t bytes) {
        char* r = p;
        p += (bytes + 15) & ~(size_t)15;
        return r;
    };
    const size_t PS = (size_t)N_NODES * 256;   // plane stride (elements)
    bf16*  qkv   = (bf16*)take(PS * 3 * sizeof(bf16));   // planes q|k|v; attn2 out in q-plane
    bf16*  h1    = (bf16*)take(PS * sizeof(bf16));       // drug_xb -> attnout1
    int*   rowptr= (int*)take((size_t)(N_NODES + 1) * sizeof(int));
    int*   degcur= (int*)take((size_t)N_NODES * sizeof(int));
    int*   bsum  = (int*)take(256 * sizeof(int));
    int*   bsume = (int*)take(256 * sizeof(int));
    int*   esrc  = (int*)take((size_t)N_EDGES * sizeof(int));
    float* bnsum = (float*)take(256 * sizeof(float));
    float* bnsumsq=(float*)take(256 * sizeof(float));
    float* s1buf = (float*)take(256 * sizeof(float));
    float* t1buf = (float*)take(256 * sizeof(float));
    bf16*  Wt1   = (bf16*)take((size_t)768 * 128 * sizeof(bf16));
    bf16*  Wt2   = (bf16*)take((size_t)768 * 256 * sizeof(bf16));
    bf16*  Wtc1  = (bf16*)take((size_t)256 * 960 * sizeof(bf16));
    bf16*  Wtc2  = (bf16*)take((size_t)256 * 256 * sizeof(bf16));
    float* bc2f  = (float*)take(256 * sizeof(float));
    float* bias1 = (float*)take(768 * sizeof(float));
    float* bias2 = (float*)take(768 * sizeof(float));
    size_t needed = (size_t)(p - (char*)d_ws);
    if (ws_size < needed) return;

    // aliases (lifetime-disjoint):
    bf16* drug_xb  = h1;                       // [N,128] bf16, dead before L1 attn writes
    bf16* cline_xb = qkv;                      // [2048,960] bf16 (qkv dead after pool)
    bf16* c1b      = qkv + (size_t)2048 * 960; // [2048,256] bf16 tanh output

    bf16* qpl = qkv;            // q plane
    bf16* kpl = qkv + PS;       // k plane
    bf16* vpl = qkv + 2 * PS;   // v plane

    float* out_pool = (float*)d_out;                      // [G,256]
    float* out_c    = out_pool + (size_t)N_GRAPH * OUT_C; // [B,256]

    dim3 gN(3, (N_NODES + 63) / 64);         // x = ntile (= plane)
    dim3 gB(1, B_CL / 64);
    const int nodeBlocks = (N_NODES + 3) / 4;
    const size_t nTot = (size_t)N_NODES * OUT_C;

    // ===================== prep =====================
    convert_a_kernel<<<(N_NODES * 128 + 255) / 256, 256, 0, stream>>>(
        drug_x, drug_xb, DRUG_DIM, 128, N_NODES * 128);
    WtJobs jobs = {{
        { Wq1, Wt1, DRUG_DIM,   0, 128 },
        { Wk1, Wt1, DRUG_DIM, 256, 128 },
        { Wv1, Wt1, DRUG_DIM, 512, 128 },
        { Wq2, Wt2, 256,        0, 256 },
        { Wk2, Wt2, 256,      256, 256 },
        { Wv2, Wt2, 256,      512, 256 },
        { Wc1, Wtc1, CLINE_DIM, 0, 960 },
        { Wc2, Wtc2, 256,       0, 256 },
    }};
    convert_wt8_kernel<<<dim3(256, 8), 256, 0, stream>>>(jobs);
    concat3_kernel<<<3, 256, 0, stream>>>(bq1, bk1, bv1, bias1);
    concat3_kernel<<<3, 256, 0, stream>>>(bq2, bk2, bv2, bias2);

    // ===================== CSR build =====================
    hipMemsetAsync(degcur, 0, N_NODES * sizeof(int), stream);
    hist_kernel<<<(N_EDGES + 255) / 256, 256, 0, stream>>>(dstp, degcur, N_EDGES);
    const int NB1 = (N_NODES + 1023) / 1024;
    scan1_kernel<<<NB1, 256, 0, stream>>>(degcur, rowptr, bsum, N_NODES);
    scan2_kernel<<<1, 256, 0, stream>>>(bsum, bsume, NB1);
    scan3_kernel<<<(N_NODES + 255) / 256, 256, 0, stream>>>(rowptr, degcur, bsume, N_NODES, N_EDGES);
    scatter_kernel<<<(N_EDGES + 255) / 256, 256, 0, stream>>>(srcp, dstp, degcur, esrc, N_EDGES);

    // ===================== drug layer 1 =====================
    mfma_gemm_kernel<0, bf16><<<gN, 256, 0, stream>>>(
        drug_xb, Wt1, bias1, nullptr, qkv, N_NODES, 128, PS);
    // attnout1 (relu'd) -> compact [N,256] into h1 slot (drug_xb dead now)
    attn_fused_kernel<<<nodeBlocks, 256, 0, stream>>>(rowptr, esrc, qpl, kpl, vpl, h1, N_NODES);
    hipMemsetAsync(bnsum, 0, 512 * sizeof(float), stream);
    col_stats_kernel<bf16><<<(N_NODES + 63) / 64, 256, 0, stream>>>(h1, bnsum, bnsumsq, N_NODES);
    // fold BN1 into Wt2/bias2 (in place), export s1/t1 for the residual path
    bn_fold_kernel<<<768, 256, 0, stream>>>(Wt2, bias2, bias2, bnsum, bnsumsq,
                                            g1, be1, s1buf, t1buf, 1.0f / N_NODES);

    // ===================== drug layer 2 =====================
    mfma_gemm_kernel<0, bf16><<<gN, 256, 0, stream>>>(
        h1, Wt2, bias2, nullptr, qkv, N_NODES, 256, PS);
    // attnout2 -> in-place q-plane (compact)
    attn_fused_kernel<<<nodeBlocks, 256, 0, stream>>>(rowptr, esrc, qpl, kpl, vpl, qpl, N_NODES);
    hipMemsetAsync(bnsum, 0, 512 * sizeof(float), stream);
    col_stats_kernel<bf16><<<(N_NODES + 63) / 64, 256, 0, stream>>>(qpl, bnsum, bnsumsq, N_NODES);
    // fused: pooled = sc2*mean(attnout2) + s1*mean(attnout1) + sh2 + t1
    pool_bn_kernel<<<N_GRAPH, 256, 0, stream>>>(qpl, h1, ibatch, bnsum, bnsumsq,
                                                g2, be2, s1buf, t1buf, out_pool,
                                                1.0f / N_NODES);

    // ===================== cline branch (qkv region now dead) =====================
    convert_a_kernel<<<(B_CL * 960 + 255) / 256, 256, 0, stream>>>(
        cline_x, cline_xb, CLINE_DIM, 960, B_CL * 960);
    mfma_gemm_kernel<1, bf16><<<gB, 256, 0, stream>>>(
        cline_xb, Wtc1, bc1, nullptr, c1b, B_CL, 960, 0);          // tanh, bf16, plane0
    hipMemsetAsync(bnsum, 0, 512 * sizeof(float), stream);
    col_stats_kernel<bf16><<<(B_CL + 63) / 64, 256, 0, stream>>>(c1b, bnsum, bnsumsq, B_CL);
    bn_fold_kernel<<<256, 256, 0, stream>>>(Wtc2, bc2, bc2f, bnsum, bnsumsq,
                                            gc, bec, nullptr, nullptr, 1.0f / B_CL);
    // out_c = c1 + relu(c1 @ Wc2f^T + bc2f)
    mfma_gemm_kernel<2, float><<<gB, 256, 0, stream>>>(
        c1b, Wtc2, bc2f, c1b, out_c, B_CL, 256, 0);
}